// Round 2
// baseline (4926.955 us; speedup 1.0000x reference)
//
#include <hip/hip_runtime.h>
#include <hip/hip_bf16.h>
#include <math.h>

#define D_DIM 256
#define NHEAD 8
#define HDIM 32
#define PATCH 256
#define NCLOUD 4
#define LPC 32768
#define NTOT (NCLOUD * LPC)
#define MLPD 512
#define PEHID 64
#define LN_EPS 1e-5f
#define NCHUNK 8
#define CROWS (NTOT / NCHUNK)   // 16384 rows per chunk

typedef unsigned long long u64;

// ---------------- block-wide sum over 256 threads ----------------
__device__ __forceinline__ float block_sum256(float v, float* red) {
#pragma unroll
  for (int o = 32; o > 0; o >>= 1) v += __shfl_down(v, o);
  __syncthreads();  // protect red from previous use
  if ((threadIdx.x & 63) == 0) red[threadIdx.x >> 6] = v;
  __syncthreads();
  return red[0] + red[1] + red[2] + red[3];
}

// ---------------- per-cloud coordinate stats ----------------
// stats[c*16 + {0..2 mean, 3..5 pescale, 6..8 kmin, 9..11 kscale}]
__global__ __launch_bounds__(256) void stats_kernel(const float* __restrict__ coord,
                                                    float* __restrict__ stats) {
  const int c = blockIdx.x, t = threadIdx.x;
  float sm[3] = {0.f, 0.f, 0.f};
  float mn[3] = {1e30f, 1e30f, 1e30f};
  float mx[3] = {-1e30f, -1e30f, -1e30f};
  const float* cp = coord + (size_t)c * LPC * 3;
  for (int i = t; i < LPC; i += 256) {
#pragma unroll
    for (int a = 0; a < 3; a++) {
      float v = cp[(size_t)i * 3 + a];
      sm[a] += v;
      mn[a] = fminf(mn[a], v);
      mx[a] = fmaxf(mx[a], v);
    }
  }
  __shared__ float sb[256];
  float rsum[3], rmn[3], rmx[3];
#pragma unroll
  for (int a = 0; a < 3; a++) {
    sb[t] = sm[a]; __syncthreads();
    for (int s = 128; s > 0; s >>= 1) { if (t < s) sb[t] += sb[t + s]; __syncthreads(); }
    rsum[a] = sb[0]; __syncthreads();
    sb[t] = mn[a]; __syncthreads();
    for (int s = 128; s > 0; s >>= 1) { if (t < s) sb[t] = fminf(sb[t], sb[t + s]); __syncthreads(); }
    rmn[a] = sb[0]; __syncthreads();
    sb[t] = mx[a]; __syncthreads();
    for (int s = 128; s > 0; s >>= 1) { if (t < s) sb[t] = fmaxf(sb[t], sb[t + s]); __syncthreads(); }
    rmx[a] = sb[0]; __syncthreads();
  }
  if (t == 0) {
    float* st = stats + c * 16;
#pragma unroll
    for (int a = 0; a < 3; a++) {
      float mean = rsum[a] / (float)LPC;
      st[a] = mean;
      st[3 + a] = fmaxf(fmaxf(rmx[a] - mean, mean - rmn[a]), 1e-6f);
      st[6 + a] = rmn[a];
      st[9 + a] = fmaxf(rmx[a] - rmn[a], 1e-6f);
    }
  }
}

// ---------------- serialization keys (bit-exact vs numpy; stable tie-break) ----------------
__global__ __launch_bounds__(256) void key_kernel(const float* __restrict__ coord,
                                                  const float* __restrict__ stats,
                                                  u64* __restrict__ keys) {
#pragma clang fp contract(off)
  const int g = blockIdx.x * 256 + threadIdx.x;
  const int c = g >> 15;
  const float* st = stats + c * 16;
  float k0 = (coord[(size_t)g * 3 + 0] - st[6]) / st[9];
  float k1 = (coord[(size_t)g * 3 + 1] - st[7]) / st[10];
  float k2 = (coord[(size_t)g * 3 + 2] - st[8]) / st[11];
  float key = k0 + 2.17f * k1;
  key = key + 3.31f * k2;
  keys[g] = ((u64)__float_as_uint(key) << 32) | (unsigned)(g & (LPC - 1));
}

// ---------------- bitonic sort (per-cloud, u64 packed key|idx) ----------------
__global__ __launch_bounds__(256) void sort_local_kernel(u64* __restrict__ keys) {
  __shared__ u64 s[4096];
  const int base = blockIdx.x * 4096;
  const int t = threadIdx.x;
  for (int i = t; i < 4096; i += 256) s[i] = keys[base + i];
  __syncthreads();
  for (int k = 2; k <= 4096; k <<= 1) {
    for (int j = k >> 1; j > 0; j >>= 1) {
      for (int p = t; p < 2048; p += 256) {
        int i = ((p & ~(j - 1)) << 1) | (p & (j - 1));
        int l = i | j;
        bool asc = (((base + i) & (LPC - 1)) & k) == 0;
        u64 a = s[i], bb = s[l];
        if (asc ? (a > bb) : (a < bb)) { s[i] = bb; s[l] = a; }
      }
      __syncthreads();
    }
  }
  for (int i = t; i < 4096; i += 256) keys[base + i] = s[i];
}

__global__ __launch_bounds__(256) void sort_global_kernel(u64* __restrict__ keys, int k, int j) {
  int p = blockIdx.x * 256 + threadIdx.x;
  int i = ((p & ~(j - 1)) << 1) | (p & (j - 1));
  int l = i | j;
  bool asc = ((i & (LPC - 1)) & k) == 0;
  u64 a = keys[i], b = keys[l];
  if (asc ? (a > b) : (a < b)) { keys[i] = b; keys[l] = a; }
}

__global__ __launch_bounds__(256) void sort_finish_kernel(u64* __restrict__ keys, int k) {
  __shared__ u64 s[4096];
  const int base = blockIdx.x * 4096;
  const int t = threadIdx.x;
  for (int i = t; i < 4096; i += 256) s[i] = keys[base + i];
  __syncthreads();
  for (int j = 2048; j > 0; j >>= 1) {
    for (int p = t; p < 2048; p += 256) {
      int i = ((p & ~(j - 1)) << 1) | (p & (j - 1));
      int l = i | j;
      bool asc = (((base + i) & (LPC - 1)) & k) == 0;
      u64 a = s[i], bb = s[l];
      if (asc ? (a > bb) : (a < bb)) { s[i] = bb; s[l] = a; }
    }
    __syncthreads();
  }
  for (int i = t; i < 4096; i += 256) keys[base + i] = s[i];
}

// ---------------- order + rank from sorted keys ----------------
__global__ __launch_bounds__(256) void rank_kernel(const u64* __restrict__ keys,
                                                   int* __restrict__ order,
                                                   int* __restrict__ rank) {
  const int g = blockIdx.x * 256 + threadIdx.x;
  const int src = (int)(unsigned)(keys[g] & 0xffffffffULL) + (g & ~(LPC - 1));
  order[g] = src;
  rank[src] = g;
}

// ---------------- PE + pre-LN, written directly into serialized position ----------------
__global__ __launch_bounds__(256) void pe_ln_kernel(
    const float* __restrict__ feats, const float* __restrict__ coord,
    const float* __restrict__ stats, const int* __restrict__ rank,
    const float* __restrict__ pw1, const float* __restrict__ pb1,
    const float* __restrict__ pw2, const float* __restrict__ pb2,
    const float* __restrict__ g, const float* __restrict__ b,
    float* __restrict__ xs) {
  const int row = blockIdx.x, t = threadIdx.x;
  const int c = row >> 15;
  const float* st = stats + c * 16;
  __shared__ float h[PEHID];
  __shared__ float scs[3];
  __shared__ float red[4];
  if (t < 3) {
    float cc = coord[(size_t)row * 3 + t] - st[t];
    scs[t] = cc / st[3 + t];
  }
  __syncthreads();
  if (t < PEHID)
    h[t] = fmaxf(pb1[t] + scs[0] * pw1[t] + scs[1] * pw1[64 + t] + scs[2] * pw1[128 + t], 0.f);
  __syncthreads();
  float pv = pb2[t];
#pragma unroll 8
  for (int k = 0; k < PEHID; k++) pv += h[k] * pw2[k * D_DIM + t];
  float v = feats[(size_t)row * D_DIM + t] + pv;
  float mean = block_sum256(v, red) * (1.f / 256.f);
  float d = v - mean;
  float var = block_sum256(d * d, red) * (1.f / 256.f);
  xs[(size_t)rank[row] * D_DIM + t] = d * (1.f / sqrtf(var + LN_EPS)) * g[t] + b[t];
}

// ---------------- scatter back to original order ----------------
__global__ __launch_bounds__(256) void scatter_kernel(const int* __restrict__ order,
                                                      const float* __restrict__ xs,
                                                      float* __restrict__ xo) {
  const int gr = blockIdx.x;
  const int t = threadIdx.x;
  const int dst = order[gr];
  xo[(size_t)dst * D_DIM + t] = xs[(size_t)gr * D_DIM + t];
}

// ---------------- layernorm (row per block) ----------------
__global__ __launch_bounds__(256) void ln_kernel(const float* __restrict__ in,
                                                 const float* __restrict__ g,
                                                 const float* __restrict__ b,
                                                 float* __restrict__ out) {
  __shared__ float red[4];
  const size_t row = blockIdx.x;
  const int t = threadIdx.x;
  float v = in[row * D_DIM + t];
  float mean = block_sum256(v, red) * (1.f / 256.f);
  float d = v - mean;
  float var = block_sum256(d * d, red) * (1.f / 256.f);
  out[row * D_DIM + t] = d * (1.f / sqrtf(var + LN_EPS)) * g[t] + b[t];
}

// ---------------- tiled fp32 GEMM: C[N x Ko] = act(A[N x K] @ W[K x Ko] + bias (+extra)) ----------------
// ACT: 0 none, 1 relu, 2 gelu(exact), 3 sigmoid. RESID: C += v. EXTRA: + extra[cloud*Ko+col].
template <int ACT, bool RESID, bool EXTRA>
__global__ __launch_bounds__(256) void gemm_kernel(const float* __restrict__ A,
                                                   const float* __restrict__ W,
                                                   const float* __restrict__ bias,
                                                   const float* __restrict__ extra,
                                                   float* __restrict__ C, int K, int Ko,
                                                   int cloud0) {
  __shared__ float As[64][16];
  __shared__ float Ws[16][64];
  const int tid = threadIdx.x;
  const int tx = tid & 15, ty = tid >> 4;
  const size_t row0 = (size_t)blockIdx.y * 64;
  const int col0 = blockIdx.x * 64;
  float acc[4][4] = {};
  const int am = tid >> 2, ak = (tid & 3) * 4;
  const int wk = tid >> 4, wc = (tid & 15) * 4;
  for (int k0 = 0; k0 < K; k0 += 16) {
    float4 av = *(const float4*)(A + (row0 + am) * K + k0 + ak);
    *(float4*)&As[am][ak] = av;
    float4 wv0 = *(const float4*)(W + (size_t)(k0 + wk) * Ko + col0 + wc);
    *(float4*)&Ws[wk][wc] = wv0;
    __syncthreads();
#pragma unroll
    for (int kk4 = 0; kk4 < 4; kk4++) {
      float4 a0 = *(const float4*)&As[ty * 4 + 0][kk4 * 4];
      float4 a1 = *(const float4*)&As[ty * 4 + 1][kk4 * 4];
      float4 a2 = *(const float4*)&As[ty * 4 + 2][kk4 * 4];
      float4 a3 = *(const float4*)&As[ty * 4 + 3][kk4 * 4];
#define STEP(E, COMP)                                                         \
  {                                                                           \
    float4 wv = *(const float4*)&Ws[kk4 * 4 + E][tx * 4];                     \
    acc[0][0] += a0.COMP * wv.x; acc[0][1] += a0.COMP * wv.y;                 \
    acc[0][2] += a0.COMP * wv.z; acc[0][3] += a0.COMP * wv.w;                 \
    acc[1][0] += a1.COMP * wv.x; acc[1][1] += a1.COMP * wv.y;                 \
    acc[1][2] += a1.COMP * wv.z; acc[1][3] += a1.COMP * wv.w;                 \
    acc[2][0] += a2.COMP * wv.x; acc[2][1] += a2.COMP * wv.y;                 \
    acc[2][2] += a2.COMP * wv.z; acc[2][3] += a2.COMP * wv.w;                 \
    acc[3][0] += a3.COMP * wv.x; acc[3][1] += a3.COMP * wv.y;                 \
    acc[3][2] += a3.COMP * wv.z; acc[3][3] += a3.COMP * wv.w;                 \
  }
      STEP(0, x) STEP(1, y) STEP(2, z) STEP(3, w)
#undef STEP
    }
    __syncthreads();
  }
#pragma unroll
  for (int i = 0; i < 4; i++) {
    size_t row = row0 + ty * 4 + i;
    int cloud = cloud0 + (int)(row >> 15);
#pragma unroll
    for (int j = 0; j < 4; j++) {
      int col = col0 + tx * 4 + j;
      float v = acc[i][j] + bias[col];
      if (EXTRA) v += extra[cloud * Ko + col];
      if (ACT == 1) v = fmaxf(v, 0.f);
      else if (ACT == 2) v = 0.5f * v * (1.f + erff(v * 0.70710678118654752440f));
      else if (ACT == 3) v = 1.f / (1.f + __expf(-v));
      size_t o = row * Ko + col;
      if (RESID) C[o] += v; else C[o] = v;
    }
  }
}

// ---------------- attention: one (window, head) per block; LDS = 64 KiB ----------------
__global__ __launch_bounds__(256) void attn_kernel(const float* __restrict__ qkv,
                                                   float* __restrict__ ao) {
  __shared__ float ks[PATCH][HDIM];
  __shared__ float vs[PATCH][HDIM];
  const int w = blockIdx.x, hh = blockIdx.y;
  const int t = threadIdx.x;
  const size_t base = (size_t)w * PATCH;
  const float* rowp = qkv + (base + t) * 768 + hh * HDIM;
  float q[HDIM];
#pragma unroll
  for (int d4 = 0; d4 < 8; d4++) {
    float4 v = *(const float4*)(rowp + d4 * 4);
    q[d4 * 4 + 0] = v.x; q[d4 * 4 + 1] = v.y; q[d4 * 4 + 2] = v.z; q[d4 * 4 + 3] = v.w;
  }
#pragma unroll
  for (int d4 = 0; d4 < 8; d4++) {
    *(float4*)&ks[t][d4 * 4] = *(const float4*)(rowp + 256 + d4 * 4);
    *(float4*)&vs[t][d4 * 4] = *(const float4*)(rowp + 512 + d4 * 4);
  }
  __syncthreads();
  const float scale = 0.17677669529663687f;  // 1/sqrt(32)
  float m = -1e30f, l = 0.f;
  float o[HDIM];
#pragma unroll
  for (int d = 0; d < HDIM; d++) o[d] = 0.f;
  for (int j = 0; j < PATCH; j++) {
    float s = 0.f;
#pragma unroll
    for (int d = 0; d < HDIM; d++) s += q[d] * ks[j][d];
    s *= scale;
    float mn = fmaxf(m, s);
    float corr = __expf(m - mn);
    float p = __expf(s - mn);
    l = l * corr + p;
#pragma unroll
    for (int d = 0; d < HDIM; d++) o[d] = o[d] * corr + p * vs[j][d];
    m = mn;
  }
  float inv = 1.f / l;
  float* op = ao + (base + t) * D_DIM + hh * HDIM;
#pragma unroll
  for (int d4 = 0; d4 < 8; d4++) {
    float4 v;
    v.x = o[d4 * 4 + 0] * inv; v.y = o[d4 * 4 + 1] * inv;
    v.z = o[d4 * 4 + 2] * inv; v.w = o[d4 * 4 + 3] * inv;
    *(float4*)(op + d4 * 4) = v;
  }
}

// ---------------- global-token mean (two-stage, deterministic) ----------------
__global__ __launch_bounds__(256) void gt_partial_kernel(const float* __restrict__ xo,
                                                         float* __restrict__ part) {
  const int s = blockIdx.x, c = blockIdx.y;
  const int t = threadIdx.x;
  float acc = 0.f;
  const size_t base = (size_t)c * LPC + (size_t)s * 1024;
  for (int r = 0; r < 1024; r++) acc += xo[(base + r) * D_DIM + t];
  part[(size_t)(c * 32 + s) * D_DIM + t] = acc;
}

__global__ __launch_bounds__(256) void gt_reduce_kernel(const float* __restrict__ part,
                                                        float* __restrict__ gt) {
  const int c = blockIdx.x, t = threadIdx.x;
  float s = 0.f;
  for (int i = 0; i < 32; i++) s += part[(size_t)(c * 32 + i) * D_DIM + t];
  gt[c * D_DIM + t] = s * (1.f / (float)LPC);
}

// ---------------- per-cloud gt @ bottom-half weights ----------------
__global__ __launch_bounds__(256) void pervec_kernel(const float* __restrict__ gt,
                                                     const float* __restrict__ ggw1,
                                                     const float* __restrict__ fw1,
                                                     float* __restrict__ ggt,
                                                     float* __restrict__ fgt) {
  const int c = blockIdx.x, which = blockIdx.y;
  const int t = threadIdx.x;
  const float* W = which ? fw1 : ggw1;
  float* o = which ? fgt : ggt;
  __shared__ float g[D_DIM];
  g[t] = gt[c * D_DIM + t];
  __syncthreads();
  float acc = 0.f;
#pragma unroll 8
  for (int k = 0; k < D_DIM; k++) acc += g[k] * W[(size_t)(256 + k) * D_DIM + t];
  o[c * D_DIM + t] = acc;
}

// ---------------- out = f + gate * fused ----------------
__global__ __launch_bounds__(256) void final_kernel(const float* __restrict__ f,
                                                    const float* __restrict__ gate,
                                                    const float* __restrict__ fused,
                                                    float* __restrict__ out) {
  size_t i = ((size_t)blockIdx.x * 256 + threadIdx.x) * 4;
  float4 fv = *(const float4*)(f + i);
  float4 gv = *(const float4*)(gate + i);
  float4 uv = *(const float4*)(fused + i);
  float4 o;
  o.x = fv.x + gv.x * uv.x; o.y = fv.y + gv.y * uv.y;
  o.z = fv.z + gv.z * uv.z; o.w = fv.w + gv.w * uv.w;
  *(float4*)(out + i) = o;
}

extern "C" void kernel_launch(void* const* d_in, const int* in_sizes, int n_in,
                              void* d_out, int out_size, void* d_ws, size_t ws_size,
                              hipStream_t stream) {
  const float* feats = (const float*)d_in[0];
  const float* coord = (const float*)d_in[1];
  // d_in[2] = lengths (unused; all clouds equal length)
  const float* pe_w1 = (const float*)d_in[3];
  const float* pe_b1 = (const float*)d_in[4];
  const float* pe_w2 = (const float*)d_in[5];
  const float* pe_b2 = (const float*)d_in[6];
  const float* pre_g = (const float*)d_in[7];
  const float* pre_b = (const float*)d_in[8];
  const float* n1_g = (const float*)d_in[9];
  const float* n1_b = (const float*)d_in[10];
  const float* wqkv = (const float*)d_in[11];
  const float* bqkv = (const float*)d_in[12];
  const float* wo = (const float*)d_in[13];
  const float* bo = (const float*)d_in[14];
  const float* n2_g = (const float*)d_in[15];
  const float* n2_b = (const float*)d_in[16];
  const float* m_w1 = (const float*)d_in[17];
  const float* m_b1 = (const float*)d_in[18];
  const float* m_w2 = (const float*)d_in[19];
  const float* m_b2 = (const float*)d_in[20];
  const float* gg_w1 = (const float*)d_in[21];
  const float* gg_b1 = (const float*)d_in[22];
  const float* gg_w2 = (const float*)d_in[23];
  const float* gg_b2 = (const float*)d_in[24];
  const float* f_w1 = (const float*)d_in[25];
  const float* f_b1 = (const float*)d_in[26];
  const float* f_w2 = (const float*)d_in[27];
  const float* f_b2 = (const float*)d_in[28];
  float* out = (float*)d_out;

  // workspace layout (~323 MiB total)
  char* ws = (char*)d_ws;
  const size_t SZ_ND = (size_t)NTOT * D_DIM * 4;            // 128 MiB
  float* xsbuf = (float*)(ws);                              // serialized stream
  float* xobuf = (float*)(ws + SZ_ND);                      // unserialized / fused
  float* qkvbuf = (float*)(ws + 2 * SZ_ND);                 // chunk: CROWS x 768 (48 MiB)
  float* tbuf = qkvbuf;                                     // chunk: CROWS x 512 (MLP, aliases qkv)
  float* aobuf = (float*)(ws + 2 * SZ_ND + (size_t)CROWS * 768 * 4);  // chunk: CROWS x 256
  size_t off = 2 * SZ_ND + (size_t)CROWS * 768 * 4 + (size_t)CROWS * D_DIM * 4;
  u64* keybuf = (u64*)(ws + off); off += (size_t)NTOT * 8;
  int* orderbuf = (int*)(ws + off); off += (size_t)NTOT * 4;
  int* rankbuf = (int*)(ws + off); off += (size_t)NTOT * 4;
  float* statsbuf = (float*)(ws + off); off += 4096;
  float* gtpart = (float*)(ws + off); off += (size_t)NCLOUD * 32 * D_DIM * 4;
  float* gtbuf = (float*)(ws + off); off += NCLOUD * D_DIM * 4;
  float* ggtbuf = (float*)(ws + off); off += NCLOUD * D_DIM * 4;
  float* fgtbuf = (float*)(ws + off); off += NCLOUD * D_DIM * 4;
  float* hbuf = out;  // reuse d_out as full-N LN / g1 / u1 scratch
  float* gatebuf = xsbuf;   // after MLP+scatter, xs is free -> gate
  float* fusedbuf = xobuf;  // after fuse-relu, xo is free -> fused

  // 1. coord stats
  stats_kernel<<<NCLOUD, 256, 0, stream>>>(coord, statsbuf);
  // 2. serialization keys + per-cloud bitonic sort + order/rank
  key_kernel<<<NTOT / 256, 256, 0, stream>>>(coord, statsbuf, keybuf);
  sort_local_kernel<<<NTOT / 4096, 256, 0, stream>>>(keybuf);
  for (int k = 8192; k <= 32768; k <<= 1) {
    for (int j = k >> 1; j >= 4096; j >>= 1)
      sort_global_kernel<<<NTOT / 512, 256, 0, stream>>>(keybuf, k, j);
    sort_finish_kernel<<<NTOT / 4096, 256, 0, stream>>>(keybuf, k);
  }
  rank_kernel<<<NTOT / 256, 256, 0, stream>>>(keybuf, orderbuf, rankbuf);
  // 3. PE + pre-LN written directly in serialized order
  pe_ln_kernel<<<NTOT, 256, 0, stream>>>(feats, coord, statsbuf, rankbuf, pe_w1, pe_b1,
                                         pe_w2, pe_b2, pre_g, pre_b, xsbuf);
  // 4. attention block (chunked): xs += attn(LN(xs)) @ wo + bo
  ln_kernel<<<NTOT, 256, 0, stream>>>(xsbuf, n1_g, n1_b, hbuf);
  for (int ch = 0; ch < NCHUNK; ch++) {
    const size_t ro = (size_t)ch * CROWS;
    gemm_kernel<0, false, false><<<dim3(768 / 64, CROWS / 64), 256, 0, stream>>>(
        hbuf + ro * D_DIM, wqkv, bqkv, nullptr, qkvbuf, 256, 768, 0);
    attn_kernel<<<dim3(CROWS / PATCH, NHEAD), 256, 0, stream>>>(qkvbuf, aobuf);
    gemm_kernel<0, true, false><<<dim3(4, CROWS / 64), 256, 0, stream>>>(
        aobuf, wo, bo, nullptr, xsbuf + ro * D_DIM, 256, 256, 0);
  }
  // 5. MLP block (chunked): xs += gelu(LN(xs) @ m_w1 + b) @ m_w2 + b
  ln_kernel<<<NTOT, 256, 0, stream>>>(xsbuf, n2_g, n2_b, hbuf);
  for (int ch = 0; ch < NCHUNK; ch++) {
    const size_t ro = (size_t)ch * CROWS;
    gemm_kernel<2, false, false><<<dim3(MLPD / 64, CROWS / 64), 256, 0, stream>>>(
        hbuf + ro * D_DIM, m_w1, m_b1, nullptr, tbuf, 256, MLPD, 0);
    gemm_kernel<0, true, false><<<dim3(4, CROWS / 64), 256, 0, stream>>>(
        tbuf, m_w2, m_b2, nullptr, xsbuf + ro * D_DIM, MLPD, 256, 0);
  }
  // 6. un-serialize
  scatter_kernel<<<NTOT, 256, 0, stream>>>(orderbuf, xsbuf, xobuf);
  // 7. global token mean + per-cloud bottom-half weight vectors
  gt_partial_kernel<<<dim3(32, NCLOUD), 256, 0, stream>>>(xobuf, gtpart);
  gt_reduce_kernel<<<NCLOUD, 256, 0, stream>>>(gtpart, gtbuf);
  pervec_kernel<<<dim3(NCLOUD, 2), 256, 0, stream>>>(gtbuf, gg_w1, f_w1, ggtbuf, fgtbuf);
  // 8. gate path: g1 = relu(f@gg_w1_top + ggt + b) -> hbuf; gate = sigmoid(g1@gg_w2 + b) -> xs
  gemm_kernel<1, false, true><<<dim3(4, NTOT / 64), 256, 0, stream>>>(
      feats, gg_w1, gg_b1, ggtbuf, hbuf, 256, 256, 0);
  gemm_kernel<3, false, false><<<dim3(4, NTOT / 64), 256, 0, stream>>>(
      hbuf, gg_w2, gg_b2, nullptr, gatebuf, 256, 256, 0);
  // 9. fuse path: u1 = relu(xo@f_w1_top + fgt + b) -> hbuf; fused = u1@f_w2 + b -> xo
  gemm_kernel<1, false, true><<<dim3(4, NTOT / 64), 256, 0, stream>>>(
      xobuf, f_w1, f_b1, fgtbuf, hbuf, 256, 256, 0);
  gemm_kernel<0, false, false><<<dim3(4, NTOT / 64), 256, 0, stream>>>(
      hbuf, f_w2, f_b2, nullptr, fusedbuf, 256, 256, 0);
  // 10. out = f + gate * fused
  final_kernel<<<NTOT / 4, 256, 0, stream>>>(feats, gatebuf, fusedbuf, out);
  (void)in_sizes; (void)n_in; (void)out_size; (void)ws_size;
}

// Round 3
// 2456.701 us; speedup vs baseline: 2.0055x; 2.0055x over previous
//
#include <hip/hip_runtime.h>
#include <hip/hip_bf16.h>
#include <math.h>

#define D_DIM 256
#define NHEAD 8
#define HDIM 32
#define PATCH 256
#define NCLOUD 4
#define LPC 32768
#define NTOT (NCLOUD * LPC)
#define MLPD 512
#define PEHID 64
#define LN_EPS 1e-5f
#define NCHUNK 8
#define CROWS (NTOT / NCHUNK)   // 16384 rows per chunk

typedef unsigned long long u64;
typedef unsigned short u16;
typedef short bf16x8 __attribute__((ext_vector_type(8)));  // 8 bf16 (4 VGPRs)
typedef float f32x4 __attribute__((ext_vector_type(4)));

__device__ __forceinline__ u16 f2bf(float x) {
  unsigned u = __float_as_uint(x);
  u += 0x7fffu + ((u >> 16) & 1u);
  return (u16)(u >> 16);
}
__device__ __forceinline__ float bf2f(u16 u) {
  return __uint_as_float(((unsigned)u) << 16);
}

// ---------------- per-cloud coordinate stats ----------------
// stats[c*16 + {0..2 mean, 3..5 pescale, 6..8 kmin, 9..11 kscale}]
__global__ __launch_bounds__(256) void stats_kernel(const float* __restrict__ coord,
                                                    float* __restrict__ stats) {
  const int c = blockIdx.x, t = threadIdx.x;
  float sm[3] = {0.f, 0.f, 0.f};
  float mn[3] = {1e30f, 1e30f, 1e30f};
  float mx[3] = {-1e30f, -1e30f, -1e30f};
  const float* cp = coord + (size_t)c * LPC * 3;
  for (int i = t; i < LPC; i += 256) {
#pragma unroll
    for (int a = 0; a < 3; a++) {
      float v = cp[(size_t)i * 3 + a];
      sm[a] += v;
      mn[a] = fminf(mn[a], v);
      mx[a] = fmaxf(mx[a], v);
    }
  }
  __shared__ float sb[256];
  float rsum[3], rmn[3], rmx[3];
#pragma unroll
  for (int a = 0; a < 3; a++) {
    sb[t] = sm[a]; __syncthreads();
    for (int s = 128; s > 0; s >>= 1) { if (t < s) sb[t] += sb[t + s]; __syncthreads(); }
    rsum[a] = sb[0]; __syncthreads();
    sb[t] = mn[a]; __syncthreads();
    for (int s = 128; s > 0; s >>= 1) { if (t < s) sb[t] = fminf(sb[t], sb[t + s]); __syncthreads(); }
    rmn[a] = sb[0]; __syncthreads();
    sb[t] = mx[a]; __syncthreads();
    for (int s = 128; s > 0; s >>= 1) { if (t < s) sb[t] = fmaxf(sb[t], sb[t + s]); __syncthreads(); }
    rmx[a] = sb[0]; __syncthreads();
  }
  if (t == 0) {
    float* st = stats + c * 16;
#pragma unroll
    for (int a = 0; a < 3; a++) {
      float mean = rsum[a] / (float)LPC;
      st[a] = mean;
      st[3 + a] = fmaxf(fmaxf(rmx[a] - mean, mean - rmn[a]), 1e-6f);
      st[6 + a] = rmn[a];
      st[9 + a] = fmaxf(rmx[a] - rmn[a], 1e-6f);
    }
  }
}

// ---------------- serialization keys (bit-exact vs numpy; stable tie-break) ----------------
__global__ __launch_bounds__(256) void key_kernel(const float* __restrict__ coord,
                                                  const float* __restrict__ stats,
                                                  u64* __restrict__ keys) {
#pragma clang fp contract(off)
  const int g = blockIdx.x * 256 + threadIdx.x;
  const int c = g >> 15;
  const float* st = stats + c * 16;
  float k0 = (coord[(size_t)g * 3 + 0] - st[6]) / st[9];
  float k1 = (coord[(size_t)g * 3 + 1] - st[7]) / st[10];
  float k2 = (coord[(size_t)g * 3 + 2] - st[8]) / st[11];
  float key = k0 + 2.17f * k1;
  key = key + 3.31f * k2;
  keys[g] = ((u64)__float_as_uint(key) << 32) | (unsigned)(g & (LPC - 1));
}

// ---------------- bitonic sort (per-cloud, u64 packed key|idx) ----------------
__global__ __launch_bounds__(256) void sort_local_kernel(u64* __restrict__ keys) {
  __shared__ u64 s[4096];
  const int base = blockIdx.x * 4096;
  const int t = threadIdx.x;
  for (int i = t; i < 4096; i += 256) s[i] = keys[base + i];
  __syncthreads();
  for (int k = 2; k <= 4096; k <<= 1) {
    for (int j = k >> 1; j > 0; j >>= 1) {
      for (int p = t; p < 2048; p += 256) {
        int i = ((p & ~(j - 1)) << 1) | (p & (j - 1));
        int l = i | j;
        bool asc = (((base + i) & (LPC - 1)) & k) == 0;
        u64 a = s[i], bb = s[l];
        if (asc ? (a > bb) : (a < bb)) { s[i] = bb; s[l] = a; }
      }
      __syncthreads();
    }
  }
  for (int i = t; i < 4096; i += 256) keys[base + i] = s[i];
}

__global__ __launch_bounds__(256) void sort_global_kernel(u64* __restrict__ keys, int k, int j) {
  int p = blockIdx.x * 256 + threadIdx.x;
  int i = ((p & ~(j - 1)) << 1) | (p & (j - 1));
  int l = i | j;
  bool asc = ((i & (LPC - 1)) & k) == 0;
  u64 a = keys[i], b = keys[l];
  if (asc ? (a > b) : (a < b)) { keys[i] = b; keys[l] = a; }
}

__global__ __launch_bounds__(256) void sort_finish_kernel(u64* __restrict__ keys, int k) {
  __shared__ u64 s[4096];
  const int base = blockIdx.x * 4096;
  const int t = threadIdx.x;
  for (int i = t; i < 4096; i += 256) s[i] = keys[base + i];
  __syncthreads();
  for (int j = 2048; j > 0; j >>= 1) {
    for (int p = t; p < 2048; p += 256) {
      int i = ((p & ~(j - 1)) << 1) | (p & (j - 1));
      int l = i | j;
      bool asc = (((base + i) & (LPC - 1)) & k) == 0;
      u64 a = s[i], bb = s[l];
      if (asc ? (a > bb) : (a < bb)) { s[i] = bb; s[l] = a; }
    }
    __syncthreads();
  }
  for (int i = t; i < 4096; i += 256) keys[base + i] = s[i];
}

// ---------------- order + rank from sorted keys ----------------
__global__ __launch_bounds__(256) void rank_kernel(const u64* __restrict__ keys,
                                                   int* __restrict__ order,
                                                   int* __restrict__ rank) {
  const int g = blockIdx.x * 256 + threadIdx.x;
  const int src = (int)(unsigned)(keys[g] & 0xffffffffULL) + (g & ~(LPC - 1));
  order[g] = src;
  rank[src] = g;
}

// ---------------- weight transpose + fp32->bf16: dst[C][R] = src[R][C] ----------------
__global__ __launch_bounds__(256) void wtrans_kernel(const float* __restrict__ src,
                                                     u16* __restrict__ dst, int R, int C) {
  __shared__ float t[32][33];
  const int bx = blockIdx.x * 32, by = blockIdx.y * 32;
  const int lc = threadIdx.x & 31, lr = threadIdx.x >> 5;  // 8 rows per pass
  for (int i = 0; i < 32; i += 8) t[lr + i][lc] = src[(size_t)(by + lr + i) * C + bx + lc];
  __syncthreads();
  for (int i = 0; i < 32; i += 8)
    dst[(size_t)(bx + lr + i) * R + by + lc] = f2bf(t[lc][lr + i]);
}

// ---------------- fp32 -> bf16 elementwise ----------------
__global__ __launch_bounds__(256) void conv_bf16_kernel(const float* __restrict__ in,
                                                        u16* __restrict__ out) {
  size_t i = ((size_t)blockIdx.x * 256 + threadIdx.x) * 4;
  float4 v = *(const float4*)(in + i);
  ushort4 o;
  o.x = f2bf(v.x); o.y = f2bf(v.y); o.z = f2bf(v.z); o.w = f2bf(v.w);
  *(ushort4*)(out + i) = o;
}

// ---------------- H = relu(scs @ pw1 + pb1), bf16 [N][64] ----------------
__global__ __launch_bounds__(256) void h_kernel(const float* __restrict__ coord,
                                                const float* __restrict__ stats,
                                                const float* __restrict__ pw1,
                                                const float* __restrict__ pb1,
                                                u16* __restrict__ H) {
  const int idx = blockIdx.x * 256 + threadIdx.x;
  const int row = idx >> 6, j = idx & 63;
  const int c = row >> 15;
  const float* st = stats + c * 16;
  float s0 = (coord[(size_t)row * 3 + 0] - st[0]) / st[3];
  float s1 = (coord[(size_t)row * 3 + 1] - st[1]) / st[4];
  float s2 = (coord[(size_t)row * 3 + 2] - st[2]) / st[5];
  float h = pb1[j] + s0 * pw1[j] + s1 * pw1[64 + j] + s2 * pw1[128 + j];
  H[idx] = f2bf(fmaxf(h, 0.f));
}

// ---------------- wave-per-row: xs[rank[row]] = LN(feats + pe) (fp32) ----------------
__global__ __launch_bounds__(256) void add_ln_kernel(const float* __restrict__ feats,
                                                     const u16* __restrict__ pe,
                                                     const int* __restrict__ rank,
                                                     const float* __restrict__ g,
                                                     const float* __restrict__ b,
                                                     float* __restrict__ xs) {
  const int row = blockIdx.x * 4 + (threadIdx.x >> 6);
  const int lane = threadIdx.x & 63;
  float4 f = *(const float4*)(feats + (size_t)row * 256 + lane * 4);
  ushort4 p = *(const ushort4*)(pe + (size_t)row * 256 + lane * 4);
  float v0 = f.x + bf2f(p.x), v1 = f.y + bf2f(p.y);
  float v2 = f.z + bf2f(p.z), v3 = f.w + bf2f(p.w);
  float s = v0 + v1 + v2 + v3;
#pragma unroll
  for (int o = 32; o > 0; o >>= 1) s += __shfl_xor(s, o);
  float mean = s * (1.f / 256.f);
  float d0 = v0 - mean, d1 = v1 - mean, d2 = v2 - mean, d3 = v3 - mean;
  float ss = d0 * d0 + d1 * d1 + d2 * d2 + d3 * d3;
#pragma unroll
  for (int o = 32; o > 0; o >>= 1) ss += __shfl_xor(ss, o);
  float inv = 1.f / sqrtf(ss * (1.f / 256.f) + LN_EPS);
  float4 gv = *(const float4*)(g + lane * 4);
  float4 bv = *(const float4*)(b + lane * 4);
  int dst = rank[row];
  float4 o4;
  o4.x = d0 * inv * gv.x + bv.x; o4.y = d1 * inv * gv.y + bv.y;
  o4.z = d2 * inv * gv.z + bv.z; o4.w = d3 * inv * gv.w + bv.w;
  *(float4*)(xs + (size_t)dst * 256 + lane * 4) = o4;
}

// ---------------- wave-per-row LN: fp32 in -> bf16 out ----------------
__global__ __launch_bounds__(256) void ln_bf16_kernel(const float* __restrict__ in,
                                                      const float* __restrict__ g,
                                                      const float* __restrict__ b,
                                                      u16* __restrict__ out) {
  const int row = blockIdx.x * 4 + (threadIdx.x >> 6);
  const int lane = threadIdx.x & 63;
  float4 v = *(const float4*)(in + (size_t)row * 256 + lane * 4);
  float s = v.x + v.y + v.z + v.w;
#pragma unroll
  for (int o = 32; o > 0; o >>= 1) s += __shfl_xor(s, o);
  float mean = s * (1.f / 256.f);
  float d0 = v.x - mean, d1 = v.y - mean, d2 = v.z - mean, d3 = v.w - mean;
  float ss = d0 * d0 + d1 * d1 + d2 * d2 + d3 * d3;
#pragma unroll
  for (int o = 32; o > 0; o >>= 1) ss += __shfl_xor(ss, o);
  float inv = 1.f / sqrtf(ss * (1.f / 256.f) + LN_EPS);
  float4 gv = *(const float4*)(g + lane * 4);
  float4 bv = *(const float4*)(b + lane * 4);
  ushort4 o4;
  o4.x = f2bf(d0 * inv * gv.x + bv.x); o4.y = f2bf(d1 * inv * gv.y + bv.y);
  o4.z = f2bf(d2 * inv * gv.z + bv.z); o4.w = f2bf(d3 * inv * gv.w + bv.w);
  *(ushort4*)(out + (size_t)row * 256 + lane * 4) = o4;
}

// ---------------- scatter xs (fp32, serialized) -> xo (bf16, original order) ----------------
__global__ __launch_bounds__(256) void scatter_bf16_kernel(const int* __restrict__ order,
                                                           const float* __restrict__ xs,
                                                           u16* __restrict__ xo) {
  const int row = blockIdx.x * 4 + (threadIdx.x >> 6);
  const int lane = threadIdx.x & 63;
  float4 v = *(const float4*)(xs + (size_t)row * 256 + lane * 4);
  const int dst = order[row];
  ushort4 o;
  o.x = f2bf(v.x); o.y = f2bf(v.y); o.z = f2bf(v.z); o.w = f2bf(v.w);
  *(ushort4*)(xo + (size_t)dst * 256 + lane * 4) = o;
}

// ---------------- MFMA GEMM: C[M x Ko] = act(A[M x K]bf16 @ Wt[Ko x K]bf16^T + bias) ----------------
// MODE: 0 fp32 store, 1 fp32 resid +=, 2 bf16 store, 3 final out=feats+gate*v
template <int K, int ACT, int MODE, bool EXTRA>
__global__ __launch_bounds__(256) void mfma_gemm(const u16* __restrict__ A,
                                                 const u16* __restrict__ Wt,
                                                 const float* __restrict__ bias,
                                                 const float* __restrict__ extra,
                                                 void* __restrict__ Cout,
                                                 const u16* __restrict__ gate,
                                                 const float* __restrict__ feats, int Ko) {
  __shared__ u16 Al[4][130][8];
  __shared__ u16 Bl[4][130][8];
  const int tid = threadIdx.x;
  const int lane = tid & 63, wave = tid >> 6;
  const int wr = wave >> 1, wc = wave & 1;
  const int l15 = lane & 15, l4 = lane >> 4;
  const size_t row0 = (size_t)blockIdx.y * 128;
  const int col0 = blockIdx.x * 128;
  f32x4 acc[4][4];
#pragma unroll
  for (int i = 0; i < 4; i++)
#pragma unroll
    for (int j = 0; j < 4; j++) acc[i][j] = f32x4{0.f, 0.f, 0.f, 0.f};
  for (int k0 = 0; k0 < K; k0 += 32) {
#pragma unroll
    for (int s = tid; s < 512; s += 256) {
      int r = s >> 2, ch = s & 3;
      *(uint4*)&Al[ch][r][0] = *(const uint4*)(A + (row0 + r) * K + k0 + ch * 8);
      *(uint4*)&Bl[ch][r][0] = *(const uint4*)(Wt + (size_t)(col0 + r) * K + k0 + ch * 8);
    }
    __syncthreads();
    bf16x8 af[4], bfr[4];
#pragma unroll
    for (int rb = 0; rb < 4; rb++)
      af[rb] = *(const bf16x8*)&Al[l4][wr * 64 + rb * 16 + l15][0];
#pragma unroll
    for (int cb = 0; cb < 4; cb++)
      bfr[cb] = *(const bf16x8*)&Bl[l4][wc * 64 + cb * 16 + l15][0];
#pragma unroll
    for (int rb = 0; rb < 4; rb++)
#pragma unroll
      for (int cb = 0; cb < 4; cb++)
        acc[rb][cb] = __builtin_amdgcn_mfma_f32_16x16x32_bf16(af[rb], bfr[cb], acc[rb][cb], 0, 0, 0);
    __syncthreads();
  }
#pragma unroll
  for (int rb = 0; rb < 4; rb++)
#pragma unroll
    for (int cb = 0; cb < 4; cb++)
#pragma unroll
      for (int r = 0; r < 4; r++) {
        size_t row = row0 + wr * 64 + rb * 16 + l4 * 4 + r;
        int col = col0 + wc * 64 + cb * 16 + l15;
        float v = acc[rb][cb][r] + bias[col];
        if (EXTRA) v += extra[((int)(row >> 15)) * 256 + col];
        if (ACT == 1) v = fmaxf(v, 0.f);
        else if (ACT == 2) v = 0.5f * v * (1.f + erff(v * 0.70710678118654752440f));
        else if (ACT == 3) v = 1.f / (1.f + __expf(-v));
        size_t o = row * (size_t)Ko + col;
        if (MODE == 0) ((float*)Cout)[o] = v;
        else if (MODE == 1) ((float*)Cout)[o] += v;
        else if (MODE == 2) ((u16*)Cout)[o] = f2bf(v);
        else ((float*)Cout)[o] = feats[o] + bf2f(gate[o]) * v;
      }
}

// ---------------- attention: one (window, head) per block; bf16 qkv; fp32 LDS ----------------
__global__ __launch_bounds__(256) void attn_kernel(const u16* __restrict__ qkv,
                                                   u16* __restrict__ ao) {
  __shared__ float ks[PATCH][HDIM];
  __shared__ float vs[PATCH][HDIM];
  const int w = blockIdx.x, hh = blockIdx.y;
  const int t = threadIdx.x;
  const size_t base = (size_t)w * PATCH;
  const u16* rowp = qkv + (base + t) * 768 + hh * HDIM;
  float q[HDIM];
#pragma unroll
  for (int d4 = 0; d4 < 8; d4++) {
    ushort4 qv = *(const ushort4*)(rowp + d4 * 4);
    q[d4 * 4 + 0] = bf2f(qv.x); q[d4 * 4 + 1] = bf2f(qv.y);
    q[d4 * 4 + 2] = bf2f(qv.z); q[d4 * 4 + 3] = bf2f(qv.w);
  }
#pragma unroll
  for (int d4 = 0; d4 < 8; d4++) {
    ushort4 kv = *(const ushort4*)(rowp + 256 + d4 * 4);
    ushort4 vv = *(const ushort4*)(rowp + 512 + d4 * 4);
    ks[t][d4 * 4 + 0] = bf2f(kv.x); ks[t][d4 * 4 + 1] = bf2f(kv.y);
    ks[t][d4 * 4 + 2] = bf2f(kv.z); ks[t][d4 * 4 + 3] = bf2f(kv.w);
    vs[t][d4 * 4 + 0] = bf2f(vv.x); vs[t][d4 * 4 + 1] = bf2f(vv.y);
    vs[t][d4 * 4 + 2] = bf2f(vv.z); vs[t][d4 * 4 + 3] = bf2f(vv.w);
  }
  __syncthreads();
  const float scale = 0.17677669529663687f;  // 1/sqrt(32)
  float m = -1e30f, l = 0.f;
  float o[HDIM];
#pragma unroll
  for (int d = 0; d < HDIM; d++) o[d] = 0.f;
  for (int j = 0; j < PATCH; j++) {
    float s = 0.f;
#pragma unroll
    for (int d = 0; d < HDIM; d++) s += q[d] * ks[j][d];
    s *= scale;
    float p;
    if (s > m) {  // rescale only on new max
      float corr = __expf(m - s);
      l *= corr;
#pragma unroll
      for (int d = 0; d < HDIM; d++) o[d] *= corr;
      m = s;
      p = 1.f;
    } else {
      p = __expf(s - m);
    }
    l += p;
#pragma unroll
    for (int d = 0; d < HDIM; d++) o[d] += p * vs[j][d];
  }
  float inv = 1.f / l;
  u16* op = ao + (base + t) * D_DIM + hh * HDIM;
#pragma unroll
  for (int d4 = 0; d4 < 8; d4++) {
    ushort4 v;
    v.x = f2bf(o[d4 * 4 + 0] * inv); v.y = f2bf(o[d4 * 4 + 1] * inv);
    v.z = f2bf(o[d4 * 4 + 2] * inv); v.w = f2bf(o[d4 * 4 + 3] * inv);
    *(ushort4*)(op + d4 * 4) = v;
  }
}

// ---------------- global-token mean from xs (permutation-invariant) ----------------
__global__ __launch_bounds__(256) void gt_partial_kernel(const float* __restrict__ xs,
                                                         float* __restrict__ part) {
  const int s = blockIdx.x, c = blockIdx.y;
  const int t = threadIdx.x;
  float acc = 0.f;
  const size_t base = (size_t)c * LPC + (size_t)s * 256;
  for (int r = 0; r < 256; r++) acc += xs[(base + r) * D_DIM + t];
  part[(size_t)(c * 128 + s) * D_DIM + t] = acc;
}

__global__ __launch_bounds__(256) void gt_reduce_kernel(const float* __restrict__ part,
                                                        float* __restrict__ gt) {
  const int c = blockIdx.x, t = threadIdx.x;
  float s = 0.f;
  for (int i = 0; i < 128; i++) s += part[(size_t)(c * 128 + i) * D_DIM + t];
  gt[c * D_DIM + t] = s * (1.f / (float)LPC);
}

// ---------------- per-cloud gt @ bottom-half weights (fp32) ----------------
__global__ __launch_bounds__(256) void pervec_kernel(const float* __restrict__ gt,
                                                     const float* __restrict__ ggw1,
                                                     const float* __restrict__ fw1,
                                                     float* __restrict__ ggt,
                                                     float* __restrict__ fgt) {
  const int c = blockIdx.x, which = blockIdx.y;
  const int t = threadIdx.x;
  const float* W = which ? fw1 : ggw1;
  float* o = which ? fgt : ggt;
  __shared__ float g[D_DIM];
  g[t] = gt[c * D_DIM + t];
  __syncthreads();
  float acc = 0.f;
#pragma unroll 8
  for (int k = 0; k < D_DIM; k++) acc += g[k] * W[(size_t)(256 + k) * D_DIM + t];
  o[c * D_DIM + t] = acc;
}

extern "C" void kernel_launch(void* const* d_in, const int* in_sizes, int n_in,
                              void* d_out, int out_size, void* d_ws, size_t ws_size,
                              hipStream_t stream) {
  const float* feats = (const float*)d_in[0];
  const float* coord = (const float*)d_in[1];
  const float* pe_w1 = (const float*)d_in[3];
  const float* pe_b1 = (const float*)d_in[4];
  const float* pe_w2 = (const float*)d_in[5];
  const float* pe_b2 = (const float*)d_in[6];
  const float* pre_g = (const float*)d_in[7];
  const float* pre_b = (const float*)d_in[8];
  const float* n1_g = (const float*)d_in[9];
  const float* n1_b = (const float*)d_in[10];
  const float* wqkv = (const float*)d_in[11];
  const float* bqkv = (const float*)d_in[12];
  const float* wo = (const float*)d_in[13];
  const float* bo = (const float*)d_in[14];
  const float* n2_g = (const float*)d_in[15];
  const float* n2_b = (const float*)d_in[16];
  const float* m_w1 = (const float*)d_in[17];
  const float* m_b1 = (const float*)d_in[18];
  const float* m_w2 = (const float*)d_in[19];
  const float* m_b2 = (const float*)d_in[20];
  const float* gg_w1 = (const float*)d_in[21];
  const float* gg_b1 = (const float*)d_in[22];
  const float* gg_w2 = (const float*)d_in[23];
  const float* gg_b2 = (const float*)d_in[24];
  const float* f_w1 = (const float*)d_in[25];
  const float* f_b1 = (const float*)d_in[26];
  const float* f_w2 = (const float*)d_in[27];
  const float* f_b2 = (const float*)d_in[28];
  float* out = (float*)d_out;

  // ---------------- workspace layout (~306 MiB) ----------------
  char* ws = (char*)d_ws;
  float* xs = (float*)(ws);                         // 128 MiB fp32 residual stream
  u16* hbuf = (u16*)(ws + 134217728);               // 64 MiB bf16 (pe / LN out / g1 / u1)
  u16* xobf = (u16*)(ws + 201326592);               // 64 MiB bf16
  u16* qkvchunk = (u16*)(ws + 268435456);           // 24 MiB bf16 chunk (alias: Hbuf, tbuf)
  u16* aochunk = (u16*)(ws + 293601280);            // 8 MiB bf16 chunk
  size_t off = 301989888;
  u64* keybuf = (u64*)(ws + off); off += (size_t)NTOT * 8;
  int* orderbuf = (int*)(ws + off); off += (size_t)NTOT * 4;
  int* rankbuf = (int*)(ws + off); off += (size_t)NTOT * 4;
  float* statsbuf = (float*)(ws + off); off += 4096;
  float* gtpart = (float*)(ws + off); off += (size_t)NCLOUD * 128 * D_DIM * 4;
  float* gtbuf = (float*)(ws + off); off += 4096;
  float* ggtbuf = (float*)(ws + off); off += 4096;
  float* fgtbuf = (float*)(ws + off); off += 4096;
  u16* wqkvT = (u16*)(ws + off); off += 768 * 256 * 2;
  u16* woT = (u16*)(ws + off); off += 256 * 256 * 2;
  u16* mw1T = (u16*)(ws + off); off += 512 * 256 * 2;
  u16* mw2T = (u16*)(ws + off); off += 256 * 512 * 2;
  u16* ggw1T = (u16*)(ws + off); off += 256 * 256 * 2;
  u16* ggw2T = (u16*)(ws + off); off += 256 * 256 * 2;
  u16* fw1T = (u16*)(ws + off); off += 256 * 256 * 2;
  u16* fw2T = (u16*)(ws + off); off += 256 * 256 * 2;
  u16* pw2T = (u16*)(ws + off); off += 64 * 256 * 2;
  u16* Hbuf = qkvchunk;                             // [N][64] bf16, 16 MiB (pre-attn only)
  u16* tbuf = qkvchunk;                             // [CROWS][512] bf16 (MLP mid)
  u16* featsbf = (u16*)(ws);                        // aliases dead xs region [0,64MiB)
  u16* gatebuf = (u16*)(ws + 67108864);             // aliases dead xs region [64,128MiB)

  // 1. stats + keys + sort + order/rank
  stats_kernel<<<NCLOUD, 256, 0, stream>>>(coord, statsbuf);
  key_kernel<<<NTOT / 256, 256, 0, stream>>>(coord, statsbuf, keybuf);
  sort_local_kernel<<<NTOT / 4096, 256, 0, stream>>>(keybuf);
  for (int k = 8192; k <= 32768; k <<= 1) {
    for (int j = k >> 1; j >= 4096; j >>= 1)
      sort_global_kernel<<<NTOT / 512, 256, 0, stream>>>(keybuf, k, j);
    sort_finish_kernel<<<NTOT / 4096, 256, 0, stream>>>(keybuf, k);
  }
  rank_kernel<<<NTOT / 256, 256, 0, stream>>>(keybuf, orderbuf, rankbuf);
  // 2. weight convert+transpose (bf16)
  wtrans_kernel<<<dim3(24, 8), 256, 0, stream>>>(wqkv, wqkvT, 256, 768);
  wtrans_kernel<<<dim3(8, 8), 256, 0, stream>>>(wo, woT, 256, 256);
  wtrans_kernel<<<dim3(16, 8), 256, 0, stream>>>(m_w1, mw1T, 256, 512);
  wtrans_kernel<<<dim3(8, 16), 256, 0, stream>>>(m_w2, mw2T, 512, 256);
  wtrans_kernel<<<dim3(8, 8), 256, 0, stream>>>(gg_w1, ggw1T, 256, 256);  // top half
  wtrans_kernel<<<dim3(8, 8), 256, 0, stream>>>(gg_w2, ggw2T, 256, 256);
  wtrans_kernel<<<dim3(8, 8), 256, 0, stream>>>(f_w1, fw1T, 256, 256);    // top half
  wtrans_kernel<<<dim3(8, 8), 256, 0, stream>>>(f_w2, fw2T, 256, 256);
  wtrans_kernel<<<dim3(8, 2), 256, 0, stream>>>(pe_w2, pw2T, 64, 256);
  // 3. PE: H = relu(scs@pw1+b1); pe = H @ pw2 + b2 (MFMA, K=64) -> hbuf bf16
  h_kernel<<<NTOT * 64 / 256, 256, 0, stream>>>(coord, statsbuf, pe_w1, pe_b1, Hbuf);
  mfma_gemm<64, 0, 2, false><<<dim3(2, NTOT / 128), 256, 0, stream>>>(
      Hbuf, pw2T, pe_b2, nullptr, hbuf, nullptr, nullptr, 256);
  // 4. xs[rank] = LN(feats + pe)
  add_ln_kernel<<<NTOT / 4, 256, 0, stream>>>(feats, hbuf, rankbuf, pre_g, pre_b, xs);
  // 5. attention block (chunked): xs += attn(LN1(xs)) @ wo + bo
  ln_bf16_kernel<<<NTOT / 4, 256, 0, stream>>>(xs, n1_g, n1_b, hbuf);
  for (int ch = 0; ch < NCHUNK; ch++) {
    const size_t ro = (size_t)ch * CROWS;
    mfma_gemm<256, 0, 2, false><<<dim3(6, CROWS / 128), 256, 0, stream>>>(
        hbuf + ro * 256, wqkvT, bqkv, nullptr, qkvchunk, nullptr, nullptr, 768);
    attn_kernel<<<dim3(CROWS / PATCH, NHEAD), 256, 0, stream>>>(qkvchunk, aochunk);
    mfma_gemm<256, 0, 1, false><<<dim3(2, CROWS / 128), 256, 0, stream>>>(
        aochunk, woT, bo, nullptr, xs + ro * 256, nullptr, nullptr, 256);
  }
  // 6. MLP block (chunked): xs += gelu(LN2(xs)@m_w1+b)@m_w2+b
  ln_bf16_kernel<<<NTOT / 4, 256, 0, stream>>>(xs, n2_g, n2_b, hbuf);
  for (int ch = 0; ch < NCHUNK; ch++) {
    const size_t ro = (size_t)ch * CROWS;
    mfma_gemm<256, 2, 2, false><<<dim3(4, CROWS / 128), 256, 0, stream>>>(
        hbuf + ro * 256, mw1T, m_b1, nullptr, tbuf, nullptr, nullptr, 512);
    mfma_gemm<512, 0, 1, false><<<dim3(2, CROWS / 128), 256, 0, stream>>>(
        tbuf, mw2T, m_b2, nullptr, xs + ro * 256, nullptr, nullptr, 256);
  }
  // 7. un-serialize to bf16 + global token from xs (mean is permutation-invariant)
  scatter_bf16_kernel<<<NTOT / 4, 256, 0, stream>>>(orderbuf, xs, xobf);
  gt_partial_kernel<<<dim3(128, NCLOUD), 256, 0, stream>>>(xs, gtpart);
  gt_reduce_kernel<<<NCLOUD, 256, 0, stream>>>(gtpart, gtbuf);
  pervec_kernel<<<dim3(NCLOUD, 2), 256, 0, stream>>>(gtbuf, gg_w1, f_w1, ggtbuf, fgtbuf);
  // 8. xs region dead -> feats bf16 + gate
  conv_bf16_kernel<<<NTOT * 256 / 1024, 256, 0, stream>>>(feats, featsbf);
  mfma_gemm<256, 1, 2, true><<<dim3(2, NTOT / 128), 256, 0, stream>>>(
      featsbf, ggw1T, gg_b1, ggtbuf, hbuf, nullptr, nullptr, 256);
  mfma_gemm<256, 3, 2, false><<<dim3(2, NTOT / 128), 256, 0, stream>>>(
      hbuf, ggw2T, gg_b2, nullptr, gatebuf, nullptr, nullptr, 256);
  // 9. fuse path + final: out = feats + gate * (relu(xo@f_w1+fgt+b)@f_w2+b)
  mfma_gemm<256, 1, 2, true><<<dim3(2, NTOT / 128), 256, 0, stream>>>(
      xobf, fw1T, f_b1, fgtbuf, hbuf, nullptr, nullptr, 256);
  mfma_gemm<256, 0, 3, false><<<dim3(2, NTOT / 128), 256, 0, stream>>>(
      hbuf, fw2T, f_b2, nullptr, out, gatebuf, feats, 256);
  (void)in_sizes; (void)n_in; (void)out_size; (void)ws_size;
}

// Round 4
// 2263.595 us; speedup vs baseline: 2.1766x; 1.0853x over previous
//
#include <hip/hip_runtime.h>
#include <hip/hip_bf16.h>
#include <math.h>

#define D_DIM 256
#define NHEAD 8
#define HDIM 32
#define PATCH 256
#define NCLOUD 4
#define LPC 32768
#define NTOT (NCLOUD * LPC)
#define MLPD 512
#define PEHID 64
#define LN_EPS 1e-5f
#define NCHUNK 8
#define CROWS (NTOT / NCHUNK)   // 16384 rows per chunk

typedef unsigned long long u64;
typedef unsigned short u16;
typedef short bf16x8 __attribute__((ext_vector_type(8)));  // 8 bf16 (4 VGPRs)
typedef float f32x4 __attribute__((ext_vector_type(4)));

__device__ __forceinline__ u16 f2bf(float x) {
  unsigned u = __float_as_uint(x);
  u += 0x7fffu + ((u >> 16) & 1u);
  return (u16)(u >> 16);
}
__device__ __forceinline__ float bf2f(u16 u) {
  return __uint_as_float(((unsigned)u) << 16);
}

// async global->LDS DMA, 16B per lane; lds ptr must be wave-uniform base (+lane*16 implicit)
__device__ __forceinline__ void gload_lds16(const u16* g, u16* l) {
  __builtin_amdgcn_global_load_lds((const __attribute__((address_space(1))) void*)g,
                                   (__attribute__((address_space(3))) void*)l, 16, 0, 0);
}

// ---------------- per-cloud coordinate stats ----------------
// stats[c*16 + {0..2 mean, 3..5 pescale, 6..8 kmin, 9..11 kscale}]
__global__ __launch_bounds__(256) void stats_kernel(const float* __restrict__ coord,
                                                    float* __restrict__ stats) {
  const int c = blockIdx.x, t = threadIdx.x;
  float sm[3] = {0.f, 0.f, 0.f};
  float mn[3] = {1e30f, 1e30f, 1e30f};
  float mx[3] = {-1e30f, -1e30f, -1e30f};
  const float* cp = coord + (size_t)c * LPC * 3;
  for (int i = t; i < LPC; i += 256) {
#pragma unroll
    for (int a = 0; a < 3; a++) {
      float v = cp[(size_t)i * 3 + a];
      sm[a] += v;
      mn[a] = fminf(mn[a], v);
      mx[a] = fmaxf(mx[a], v);
    }
  }
  __shared__ float sb[256];
  float rsum[3], rmn[3], rmx[3];
#pragma unroll
  for (int a = 0; a < 3; a++) {
    sb[t] = sm[a]; __syncthreads();
    for (int s = 128; s > 0; s >>= 1) { if (t < s) sb[t] += sb[t + s]; __syncthreads(); }
    rsum[a] = sb[0]; __syncthreads();
    sb[t] = mn[a]; __syncthreads();
    for (int s = 128; s > 0; s >>= 1) { if (t < s) sb[t] = fminf(sb[t], sb[t + s]); __syncthreads(); }
    rmn[a] = sb[0]; __syncthreads();
    sb[t] = mx[a]; __syncthreads();
    for (int s = 128; s > 0; s >>= 1) { if (t < s) sb[t] = fmaxf(sb[t], sb[t + s]); __syncthreads(); }
    rmx[a] = sb[0]; __syncthreads();
  }
  if (t == 0) {
    float* st = stats + c * 16;
#pragma unroll
    for (int a = 0; a < 3; a++) {
      float mean = rsum[a] / (float)LPC;
      st[a] = mean;
      st[3 + a] = fmaxf(fmaxf(rmx[a] - mean, mean - rmn[a]), 1e-6f);
      st[6 + a] = rmn[a];
      st[9 + a] = fmaxf(rmx[a] - rmn[a], 1e-6f);
    }
  }
}

// ---------------- serialization keys (bit-exact vs numpy; stable tie-break) ----------------
__global__ __launch_bounds__(256) void key_kernel(const float* __restrict__ coord,
                                                  const float* __restrict__ stats,
                                                  u64* __restrict__ keys) {
#pragma clang fp contract(off)
  const int g = blockIdx.x * 256 + threadIdx.x;
  const int c = g >> 15;
  const float* st = stats + c * 16;
  float k0 = (coord[(size_t)g * 3 + 0] - st[6]) / st[9];
  float k1 = (coord[(size_t)g * 3 + 1] - st[7]) / st[10];
  float k2 = (coord[(size_t)g * 3 + 2] - st[8]) / st[11];
  float key = k0 + 2.17f * k1;
  key = key + 3.31f * k2;
  keys[g] = ((u64)__float_as_uint(key) << 32) | (unsigned)(g & (LPC - 1));
}

// ---------------- bitonic sort (per-cloud, u64 packed key|idx) ----------------
__global__ __launch_bounds__(256) void sort_local_kernel(u64* __restrict__ keys) {
  __shared__ u64 s[4096];
  const int base = blockIdx.x * 4096;
  const int t = threadIdx.x;
  for (int i = t; i < 4096; i += 256) s[i] = keys[base + i];
  __syncthreads();
  for (int k = 2; k <= 4096; k <<= 1) {
    for (int j = k >> 1; j > 0; j >>= 1) {
      for (int p = t; p < 2048; p += 256) {
        int i = ((p & ~(j - 1)) << 1) | (p & (j - 1));
        int l = i | j;
        bool asc = (((base + i) & (LPC - 1)) & k) == 0;
        u64 a = s[i], bb = s[l];
        if (asc ? (a > bb) : (a < bb)) { s[i] = bb; s[l] = a; }
      }
      __syncthreads();
    }
  }
  for (int i = t; i < 4096; i += 256) keys[base + i] = s[i];
}

__global__ __launch_bounds__(256) void sort_global_kernel(u64* __restrict__ keys, int k, int j) {
  int p = blockIdx.x * 256 + threadIdx.x;
  int i = ((p & ~(j - 1)) << 1) | (p & (j - 1));
  int l = i | j;
  bool asc = ((i & (LPC - 1)) & k) == 0;
  u64 a = keys[i], b = keys[l];
  if (asc ? (a > b) : (a < b)) { keys[i] = b; keys[l] = a; }
}

__global__ __launch_bounds__(256) void sort_finish_kernel(u64* __restrict__ keys, int k) {
  __shared__ u64 s[4096];
  const int base = blockIdx.x * 4096;
  const int t = threadIdx.x;
  for (int i = t; i < 4096; i += 256) s[i] = keys[base + i];
  __syncthreads();
  for (int j = 2048; j > 0; j >>= 1) {
    for (int p = t; p < 2048; p += 256) {
      int i = ((p & ~(j - 1)) << 1) | (p & (j - 1));
      int l = i | j;
      bool asc = (((base + i) & (LPC - 1)) & k) == 0;
      u64 a = s[i], bb = s[l];
      if (asc ? (a > bb) : (a < bb)) { s[i] = bb; s[l] = a; }
    }
    __syncthreads();
  }
  for (int i = t; i < 4096; i += 256) keys[base + i] = s[i];
}

// ---------------- order + rank from sorted keys ----------------
__global__ __launch_bounds__(256) void rank_kernel(const u64* __restrict__ keys,
                                                   int* __restrict__ order,
                                                   int* __restrict__ rank) {
  const int g = blockIdx.x * 256 + threadIdx.x;
  const int src = (int)(unsigned)(keys[g] & 0xffffffffULL) + (g & ~(LPC - 1));
  order[g] = src;
  rank[src] = g;
}

// ---------------- weight transpose + fp32->bf16: dst[C][R] = src[R][C] ----------------
__global__ __launch_bounds__(256) void wtrans_kernel(const float* __restrict__ src,
                                                     u16* __restrict__ dst, int R, int C) {
  __shared__ float t[32][33];
  const int bx = blockIdx.x * 32, by = blockIdx.y * 32;
  const int lc = threadIdx.x & 31, lr = threadIdx.x >> 5;  // 8 rows per pass
  for (int i = 0; i < 32; i += 8) t[lr + i][lc] = src[(size_t)(by + lr + i) * C + bx + lc];
  __syncthreads();
  for (int i = 0; i < 32; i += 8)
    dst[(size_t)(bx + lr + i) * R + by + lc] = f2bf(t[lc][lr + i]);
}

// ---------------- fp32 -> bf16 elementwise ----------------
__global__ __launch_bounds__(256) void conv_bf16_kernel(const float* __restrict__ in,
                                                        u16* __restrict__ out) {
  size_t i = ((size_t)blockIdx.x * 256 + threadIdx.x) * 4;
  float4 v = *(const float4*)(in + i);
  ushort4 o;
  o.x = f2bf(v.x); o.y = f2bf(v.y); o.z = f2bf(v.z); o.w = f2bf(v.w);
  *(ushort4*)(out + i) = o;
}

// ---------------- H = relu(scs @ pw1 + pb1), bf16 [N][64] ----------------
__global__ __launch_bounds__(256) void h_kernel(const float* __restrict__ coord,
                                                const float* __restrict__ stats,
                                                const float* __restrict__ pw1,
                                                const float* __restrict__ pb1,
                                                u16* __restrict__ H) {
  const int idx = blockIdx.x * 256 + threadIdx.x;
  const int row = idx >> 6, j = idx & 63;
  const int c = row >> 15;
  const float* st = stats + c * 16;
  float s0 = (coord[(size_t)row * 3 + 0] - st[0]) / st[3];
  float s1 = (coord[(size_t)row * 3 + 1] - st[1]) / st[4];
  float s2 = (coord[(size_t)row * 3 + 2] - st[2]) / st[5];
  float h = pb1[j] + s0 * pw1[j] + s1 * pw1[64 + j] + s2 * pw1[128 + j];
  H[idx] = f2bf(fmaxf(h, 0.f));
}

// ---------------- wave-per-row: xs[rank[row]] = LN(feats + pe) (fp32) ----------------
__global__ __launch_bounds__(256) void add_ln_kernel(const float* __restrict__ feats,
                                                     const u16* __restrict__ pe,
                                                     const int* __restrict__ rank,
                                                     const float* __restrict__ g,
                                                     const float* __restrict__ b,
                                                     float* __restrict__ xs) {
  const int row = blockIdx.x * 4 + (threadIdx.x >> 6);
  const int lane = threadIdx.x & 63;
  float4 f = *(const float4*)(feats + (size_t)row * 256 + lane * 4);
  ushort4 p = *(const ushort4*)(pe + (size_t)row * 256 + lane * 4);
  float v0 = f.x + bf2f(p.x), v1 = f.y + bf2f(p.y);
  float v2 = f.z + bf2f(p.z), v3 = f.w + bf2f(p.w);
  float s = v0 + v1 + v2 + v3;
#pragma unroll
  for (int o = 32; o > 0; o >>= 1) s += __shfl_xor(s, o);
  float mean = s * (1.f / 256.f);
  float d0 = v0 - mean, d1 = v1 - mean, d2 = v2 - mean, d3 = v3 - mean;
  float ss = d0 * d0 + d1 * d1 + d2 * d2 + d3 * d3;
#pragma unroll
  for (int o = 32; o > 0; o >>= 1) ss += __shfl_xor(ss, o);
  float inv = 1.f / sqrtf(ss * (1.f / 256.f) + LN_EPS);
  float4 gv = *(const float4*)(g + lane * 4);
  float4 bv = *(const float4*)(b + lane * 4);
  int dst = rank[row];
  float4 o4;
  o4.x = d0 * inv * gv.x + bv.x; o4.y = d1 * inv * gv.y + bv.y;
  o4.z = d2 * inv * gv.z + bv.z; o4.w = d3 * inv * gv.w + bv.w;
  *(float4*)(xs + (size_t)dst * 256 + lane * 4) = o4;
}

// ---------------- wave-per-row LN: fp32 in -> bf16 out ----------------
__global__ __launch_bounds__(256) void ln_bf16_kernel(const float* __restrict__ in,
                                                      const float* __restrict__ g,
                                                      const float* __restrict__ b,
                                                      u16* __restrict__ out) {
  const int row = blockIdx.x * 4 + (threadIdx.x >> 6);
  const int lane = threadIdx.x & 63;
  float4 v = *(const float4*)(in + (size_t)row * 256 + lane * 4);
  float s = v.x + v.y + v.z + v.w;
#pragma unroll
  for (int o = 32; o > 0; o >>= 1) s += __shfl_xor(s, o);
  float mean = s * (1.f / 256.f);
  float d0 = v.x - mean, d1 = v.y - mean, d2 = v.z - mean, d3 = v.w - mean;
  float ss = d0 * d0 + d1 * d1 + d2 * d2 + d3 * d3;
#pragma unroll
  for (int o = 32; o > 0; o >>= 1) ss += __shfl_xor(ss, o);
  float inv = 1.f / sqrtf(ss * (1.f / 256.f) + LN_EPS);
  float4 gv = *(const float4*)(g + lane * 4);
  float4 bv = *(const float4*)(b + lane * 4);
  ushort4 o4;
  o4.x = f2bf(d0 * inv * gv.x + bv.x); o4.y = f2bf(d1 * inv * gv.y + bv.y);
  o4.z = f2bf(d2 * inv * gv.z + bv.z); o4.w = f2bf(d3 * inv * gv.w + bv.w);
  *(ushort4*)(out + (size_t)row * 256 + lane * 4) = o4;
}

// ---------------- scatter xs (fp32, serialized) -> xo (bf16, original order) ----------------
__global__ __launch_bounds__(256) void scatter_bf16_kernel(const int* __restrict__ order,
                                                           const float* __restrict__ xs,
                                                           u16* __restrict__ xo) {
  const int row = blockIdx.x * 4 + (threadIdx.x >> 6);
  const int lane = threadIdx.x & 63;
  float4 v = *(const float4*)(xs + (size_t)row * 256 + lane * 4);
  const int dst = order[row];
  ushort4 o;
  o.x = f2bf(v.x); o.y = f2bf(v.y); o.z = f2bf(v.z); o.w = f2bf(v.w);
  *(ushort4*)(xo + (size_t)dst * 256 + lane * 4) = o;
}

// ---------------- MFMA GEMM (m97 structure): C[M x Ko] = act(A@Wt^T + bias) ----------------
// BK=32, 128x128 tile, 4 waves, global_load_lds width-16 staging, linear [128][32] LDS.
// MODE: 0 fp32 store, 1 fp32 resid +=, 2 bf16 store, 3 final out=feats+gate*v
template <int K, int ACT, int MODE, bool EXTRA>
__global__ __launch_bounds__(256, 4) void mfma_gemm(const u16* __restrict__ A,
                                                    const u16* __restrict__ Wt,
                                                    const float* __restrict__ bias,
                                                    const float* __restrict__ extra,
                                                    void* __restrict__ Cout,
                                                    const u16* __restrict__ gate,
                                                    const float* __restrict__ feats, int Ko) {
  __shared__ __align__(16) u16 Al[128 * 32];
  __shared__ __align__(16) u16 Bl[128 * 32];
  const int tid = threadIdx.x;
  const int lane = tid & 63, wave = tid >> 6;
  const int wr = wave >> 1, wc = wave & 1;
  const int l15 = lane & 15, l4 = lane >> 4;
  const size_t row0 = (size_t)blockIdx.y * 128;
  const int col0 = blockIdx.x * 128;
  // staging: slot q in [0,512): row=q>>2, 16B chunk=q&3; LDS linear [row][32] bf16
  const int q0 = wave * 64 + lane;
  const int q1 = q0 + 256;
  const u16* gA0 = A + (row0 + (q0 >> 2)) * K + (q0 & 3) * 8;
  const u16* gA1 = A + (row0 + (q1 >> 2)) * K + (q1 & 3) * 8;
  const u16* gB0 = Wt + (size_t)(col0 + (q0 >> 2)) * K + (q0 & 3) * 8;
  const u16* gB1 = Wt + (size_t)(col0 + (q1 >> 2)) * K + (q1 & 3) * 8;
  u16* lA0 = Al + wave * 512;   // wave-uniform base; lane*16B implicit
  u16* lA1 = Al + 2048 + wave * 512;
  u16* lB0 = Bl + wave * 512;
  u16* lB1 = Bl + 2048 + wave * 512;
  f32x4 acc[4][4];
#pragma unroll
  for (int i = 0; i < 4; i++)
#pragma unroll
    for (int j = 0; j < 4; j++) acc[i][j] = f32x4{0.f, 0.f, 0.f, 0.f};
#pragma unroll 1
  for (int k0 = 0; k0 < K; k0 += 32) {
    gload_lds16(gA0 + k0, lA0);
    gload_lds16(gA1 + k0, lA1);
    gload_lds16(gB0 + k0, lB0);
    gload_lds16(gB1 + k0, lB1);
    __syncthreads();
    bf16x8 af[4], bfr[4];
#pragma unroll
    for (int rb = 0; rb < 4; rb++)
      af[rb] = *(const bf16x8*)&Al[(wr * 64 + rb * 16 + l15) * 32 + l4 * 8];
#pragma unroll
    for (int cb = 0; cb < 4; cb++)
      bfr[cb] = *(const bf16x8*)&Bl[(wc * 64 + cb * 16 + l15) * 32 + l4 * 8];
#pragma unroll
    for (int rb = 0; rb < 4; rb++)
#pragma unroll
      for (int cb = 0; cb < 4; cb++)
        acc[rb][cb] = __builtin_amdgcn_mfma_f32_16x16x32_bf16(af[rb], bfr[cb], acc[rb][cb], 0, 0, 0);
    __syncthreads();
  }
#pragma unroll
  for (int rb = 0; rb < 4; rb++)
#pragma unroll
    for (int cb = 0; cb < 4; cb++)
#pragma unroll
      for (int r = 0; r < 4; r++) {
        size_t row = row0 + wr * 64 + rb * 16 + l4 * 4 + r;
        int col = col0 + wc * 64 + cb * 16 + l15;
        float v = acc[rb][cb][r] + bias[col];
        if (EXTRA) v += extra[((int)(row >> 15)) * 256 + col];
        if (ACT == 1) v = fmaxf(v, 0.f);
        else if (ACT == 2) v = 0.5f * v * (1.f + erff(v * 0.70710678118654752440f));
        else if (ACT == 3) v = 1.f / (1.f + __expf(-v));
        size_t o = row * (size_t)Ko + col;
        if (MODE == 0) ((float*)Cout)[o] = v;
        else if (MODE == 1) ((float*)Cout)[o] += v;
        else if (MODE == 2) ((u16*)Cout)[o] = f2bf(v);
        else ((float*)Cout)[o] = feats[o] + bf2f(gate[o]) * v;
      }
}

// ---------------- attention: one (window, head) per block; bf16 qkv; fp32 LDS ----------------
__global__ __launch_bounds__(256) void attn_kernel(const u16* __restrict__ qkv,
                                                   u16* __restrict__ ao) {
  __shared__ float ks[PATCH][HDIM];
  __shared__ float vs[PATCH][HDIM];
  const int w = blockIdx.x, hh = blockIdx.y;
  const int t = threadIdx.x;
  const size_t base = (size_t)w * PATCH;
  const u16* rowp = qkv + (base + t) * 768 + hh * HDIM;
  float q[HDIM];
#pragma unroll
  for (int d4 = 0; d4 < 8; d4++) {
    ushort4 qv = *(const ushort4*)(rowp + d4 * 4);
    q[d4 * 4 + 0] = bf2f(qv.x); q[d4 * 4 + 1] = bf2f(qv.y);
    q[d4 * 4 + 2] = bf2f(qv.z); q[d4 * 4 + 3] = bf2f(qv.w);
  }
#pragma unroll
  for (int d4 = 0; d4 < 8; d4++) {
    ushort4 kv = *(const ushort4*)(rowp + 256 + d4 * 4);
    ushort4 vv = *(const ushort4*)(rowp + 512 + d4 * 4);
    ks[t][d4 * 4 + 0] = bf2f(kv.x); ks[t][d4 * 4 + 1] = bf2f(kv.y);
    ks[t][d4 * 4 + 2] = bf2f(kv.z); ks[t][d4 * 4 + 3] = bf2f(kv.w);
    vs[t][d4 * 4 + 0] = bf2f(vv.x); vs[t][d4 * 4 + 1] = bf2f(vv.y);
    vs[t][d4 * 4 + 2] = bf2f(vv.z); vs[t][d4 * 4 + 3] = bf2f(vv.w);
  }
  __syncthreads();
  const float scale = 0.17677669529663687f;  // 1/sqrt(32)
  float m = -1e30f, l = 0.f;
  float o[HDIM];
#pragma unroll
  for (int d = 0; d < HDIM; d++) o[d] = 0.f;
  for (int j = 0; j < PATCH; j++) {
    float s = 0.f;
#pragma unroll
    for (int d = 0; d < HDIM; d++) s += q[d] * ks[j][d];
    s *= scale;
    float p;
    if (s > m) {  // rescale only on new max
      float corr = __expf(m - s);
      l *= corr;
#pragma unroll
      for (int d = 0; d < HDIM; d++) o[d] *= corr;
      m = s;
      p = 1.f;
    } else {
      p = __expf(s - m);
    }
    l += p;
#pragma unroll
    for (int d = 0; d < HDIM; d++) o[d] += p * vs[j][d];
  }
  float inv = 1.f / l;
  u16* op = ao + (base + t) * D_DIM + hh * HDIM;
#pragma unroll
  for (int d4 = 0; d4 < 8; d4++) {
    ushort4 v;
    v.x = f2bf(o[d4 * 4 + 0] * inv); v.y = f2bf(o[d4 * 4 + 1] * inv);
    v.z = f2bf(o[d4 * 4 + 2] * inv); v.w = f2bf(o[d4 * 4 + 3] * inv);
    *(ushort4*)(op + d4 * 4) = v;
  }
}

// ---------------- global-token mean from xs (permutation-invariant) ----------------
__global__ __launch_bounds__(256) void gt_partial_kernel(const float* __restrict__ xs,
                                                         float* __restrict__ part) {
  const int s = blockIdx.x, c = blockIdx.y;
  const int t = threadIdx.x;
  float acc = 0.f;
  const size_t base = (size_t)c * LPC + (size_t)s * 256;
  for (int r = 0; r < 256; r++) acc += xs[(base + r) * D_DIM + t];
  part[(size_t)(c * 128 + s) * D_DIM + t] = acc;
}

__global__ __launch_bounds__(256) void gt_reduce_kernel(const float* __restrict__ part,
                                                        float* __restrict__ gt) {
  const int c = blockIdx.x, t = threadIdx.x;
  float s = 0.f;
  for (int i = 0; i < 128; i++) s += part[(size_t)(c * 128 + i) * D_DIM + t];
  gt[c * D_DIM + t] = s * (1.f / (float)LPC);
}

// ---------------- per-cloud gt @ bottom-half weights (fp32) ----------------
__global__ __launch_bounds__(256) void pervec_kernel(const float* __restrict__ gt,
                                                     const float* __restrict__ ggw1,
                                                     const float* __restrict__ fw1,
                                                     float* __restrict__ ggt,
                                                     float* __restrict__ fgt) {
  const int c = blockIdx.x, which = blockIdx.y;
  const int t = threadIdx.x;
  const float* W = which ? fw1 : ggw1;
  float* o = which ? fgt : ggt;
  __shared__ float g[D_DIM];
  g[t] = gt[c * D_DIM + t];
  __syncthreads();
  float acc = 0.f;
#pragma unroll 8
  for (int k = 0; k < D_DIM; k++) acc += g[k] * W[(size_t)(256 + k) * D_DIM + t];
  o[c * D_DIM + t] = acc;
}

extern "C" void kernel_launch(void* const* d_in, const int* in_sizes, int n_in,
                              void* d_out, int out_size, void* d_ws, size_t ws_size,
                              hipStream_t stream) {
  const float* feats = (const float*)d_in[0];
  const float* coord = (const float*)d_in[1];
  const float* pe_w1 = (const float*)d_in[3];
  const float* pe_b1 = (const float*)d_in[4];
  const float* pe_w2 = (const float*)d_in[5];
  const float* pe_b2 = (const float*)d_in[6];
  const float* pre_g = (const float*)d_in[7];
  const float* pre_b = (const float*)d_in[8];
  const float* n1_g = (const float*)d_in[9];
  const float* n1_b = (const float*)d_in[10];
  const float* wqkv = (const float*)d_in[11];
  const float* bqkv = (const float*)d_in[12];
  const float* wo = (const float*)d_in[13];
  const float* bo = (const float*)d_in[14];
  const float* n2_g = (const float*)d_in[15];
  const float* n2_b = (const float*)d_in[16];
  const float* m_w1 = (const float*)d_in[17];
  const float* m_b1 = (const float*)d_in[18];
  const float* m_w2 = (const float*)d_in[19];
  const float* m_b2 = (const float*)d_in[20];
  const float* gg_w1 = (const float*)d_in[21];
  const float* gg_b1 = (const float*)d_in[22];
  const float* gg_w2 = (const float*)d_in[23];
  const float* gg_b2 = (const float*)d_in[24];
  const float* f_w1 = (const float*)d_in[25];
  const float* f_b1 = (const float*)d_in[26];
  const float* f_w2 = (const float*)d_in[27];
  const float* f_b2 = (const float*)d_in[28];
  float* out = (float*)d_out;

  // ---------------- workspace layout (~306 MiB) ----------------
  char* ws = (char*)d_ws;
  float* xs = (float*)(ws);                         // 128 MiB fp32 residual stream
  u16* hbuf = (u16*)(ws + 134217728);               // 64 MiB bf16 (pe / LN out / g1 / u1)
  u16* xobf = (u16*)(ws + 201326592);               // 64 MiB bf16
  u16* qkvchunk = (u16*)(ws + 268435456);           // 24 MiB bf16 chunk (alias: Hbuf, tbuf)
  u16* aochunk = (u16*)(ws + 293601280);            // 8 MiB bf16 chunk
  size_t off = 301989888;
  u64* keybuf = (u64*)(ws + off); off += (size_t)NTOT * 8;
  int* orderbuf = (int*)(ws + off); off += (size_t)NTOT * 4;
  int* rankbuf = (int*)(ws + off); off += (size_t)NTOT * 4;
  float* statsbuf = (float*)(ws + off); off += 4096;
  float* gtpart = (float*)(ws + off); off += (size_t)NCLOUD * 128 * D_DIM * 4;
  float* gtbuf = (float*)(ws + off); off += 4096;
  float* ggtbuf = (float*)(ws + off); off += 4096;
  float* fgtbuf = (float*)(ws + off); off += 4096;
  u16* wqkvT = (u16*)(ws + off); off += 768 * 256 * 2;
  u16* woT = (u16*)(ws + off); off += 256 * 256 * 2;
  u16* mw1T = (u16*)(ws + off); off += 512 * 256 * 2;
  u16* mw2T = (u16*)(ws + off); off += 256 * 512 * 2;
  u16* ggw1T = (u16*)(ws + off); off += 256 * 256 * 2;
  u16* ggw2T = (u16*)(ws + off); off += 256 * 256 * 2;
  u16* fw1T = (u16*)(ws + off); off += 256 * 256 * 2;
  u16* fw2T = (u16*)(ws + off); off += 256 * 256 * 2;
  u16* pw2T = (u16*)(ws + off); off += 64 * 256 * 2;
  u16* Hbuf = qkvchunk;                             // [N][64] bf16, 16 MiB (pre-attn only)
  u16* tbuf = qkvchunk;                             // [CROWS][512] bf16 (MLP mid)
  u16* featsbf = (u16*)(ws);                        // aliases dead xs region [0,64MiB)
  u16* gatebuf = (u16*)(ws + 67108864);             // aliases dead xs region [64,128MiB)

  // 1. stats + keys + sort + order/rank
  stats_kernel<<<NCLOUD, 256, 0, stream>>>(coord, statsbuf);
  key_kernel<<<NTOT / 256, 256, 0, stream>>>(coord, statsbuf, keybuf);
  sort_local_kernel<<<NTOT / 4096, 256, 0, stream>>>(keybuf);
  for (int k = 8192; k <= 32768; k <<= 1) {
    for (int j = k >> 1; j >= 4096; j >>= 1)
      sort_global_kernel<<<NTOT / 512, 256, 0, stream>>>(keybuf, k, j);
    sort_finish_kernel<<<NTOT / 4096, 256, 0, stream>>>(keybuf, k);
  }
  rank_kernel<<<NTOT / 256, 256, 0, stream>>>(keybuf, orderbuf, rankbuf);
  // 2. weight convert+transpose (bf16)
  wtrans_kernel<<<dim3(24, 8), 256, 0, stream>>>(wqkv, wqkvT, 256, 768);
  wtrans_kernel<<<dim3(8, 8), 256, 0, stream>>>(wo, woT, 256, 256);
  wtrans_kernel<<<dim3(16, 8), 256, 0, stream>>>(m_w1, mw1T, 256, 512);
  wtrans_kernel<<<dim3(8, 16), 256, 0, stream>>>(m_w2, mw2T, 512, 256);
  wtrans_kernel<<<dim3(8, 8), 256, 0, stream>>>(gg_w1, ggw1T, 256, 256);  // top half
  wtrans_kernel<<<dim3(8, 8), 256, 0, stream>>>(gg_w2, ggw2T, 256, 256);
  wtrans_kernel<<<dim3(8, 8), 256, 0, stream>>>(f_w1, fw1T, 256, 256);    // top half
  wtrans_kernel<<<dim3(8, 8), 256, 0, stream>>>(f_w2, fw2T, 256, 256);
  wtrans_kernel<<<dim3(8, 2), 256, 0, stream>>>(pe_w2, pw2T, 64, 256);
  // 3. PE: H = relu(scs@pw1+b1); pe = H @ pw2 + b2 (MFMA, K=64) -> hbuf bf16
  h_kernel<<<NTOT * 64 / 256, 256, 0, stream>>>(coord, statsbuf, pe_w1, pe_b1, Hbuf);
  mfma_gemm<64, 0, 2, false><<<dim3(2, NTOT / 128), 256, 0, stream>>>(
      Hbuf, pw2T, pe_b2, nullptr, hbuf, nullptr, nullptr, 256);
  // 4. xs[rank] = LN(feats + pe)
  add_ln_kernel<<<NTOT / 4, 256, 0, stream>>>(feats, hbuf, rankbuf, pre_g, pre_b, xs);
  // 5. attention block (chunked): xs += attn(LN1(xs)) @ wo + bo
  ln_bf16_kernel<<<NTOT / 4, 256, 0, stream>>>(xs, n1_g, n1_b, hbuf);
  for (int ch = 0; ch < NCHUNK; ch++) {
    const size_t ro = (size_t)ch * CROWS;
    mfma_gemm<256, 0, 2, false><<<dim3(6, CROWS / 128), 256, 0, stream>>>(
        hbuf + ro * 256, wqkvT, bqkv, nullptr, qkvchunk, nullptr, nullptr, 768);
    attn_kernel<<<dim3(CROWS / PATCH, NHEAD), 256, 0, stream>>>(qkvchunk, aochunk);
    mfma_gemm<256, 0, 1, false><<<dim3(2, CROWS / 128), 256, 0, stream>>>(
        aochunk, woT, bo, nullptr, xs + ro * 256, nullptr, nullptr, 256);
  }
  // 6. MLP block (chunked): xs += gelu(LN2(xs)@m_w1+b)@m_w2+b
  ln_bf16_kernel<<<NTOT / 4, 256, 0, stream>>>(xs, n2_g, n2_b, hbuf);
  for (int ch = 0; ch < NCHUNK; ch++) {
    const size_t ro = (size_t)ch * CROWS;
    mfma_gemm<256, 2, 2, false><<<dim3(MLPD / 128, CROWS / 128), 256, 0, stream>>>(
        hbuf + ro * 256, mw1T, m_b1, nullptr, tbuf, nullptr, nullptr, 512);
    mfma_gemm<512, 0, 1, false><<<dim3(2, CROWS / 128), 256, 0, stream>>>(
        tbuf, mw2T, m_b2, nullptr, xs + ro * 256, nullptr, nullptr, 256);
  }
  // 7. un-serialize to bf16 + global token from xs (mean is permutation-invariant)
  scatter_bf16_kernel<<<NTOT / 4, 256, 0, stream>>>(orderbuf, xs, xobf);
  gt_partial_kernel<<<dim3(128, NCLOUD), 256, 0, stream>>>(xs, gtpart);
  gt_reduce_kernel<<<NCLOUD, 256, 0, stream>>>(gtpart, gtbuf);
  pervec_kernel<<<dim3(NCLOUD, 2), 256, 0, stream>>>(gtbuf, gg_w1, f_w1, ggtbuf, fgtbuf);
  // 8. xs region dead -> feats bf16 + gate
  conv_bf16_kernel<<<NTOT * 256 / 1024, 256, 0, stream>>>(feats, featsbf);
  mfma_gemm<256, 1, 2, true><<<dim3(2, NTOT / 128), 256, 0, stream>>>(
      featsbf, ggw1T, gg_b1, ggtbuf, hbuf, nullptr, nullptr, 256);
  mfma_gemm<256, 3, 2, false><<<dim3(2, NTOT / 128), 256, 0, stream>>>(
      hbuf, ggw2T, gg_b2, nullptr, gatebuf, nullptr, nullptr, 256);
  // 9. fuse path + final: out = feats + gate * (relu(xo@f_w1+fgt+b)@f_w2+b)
  mfma_gemm<256, 1, 2, true><<<dim3(2, NTOT / 128), 256, 0, stream>>>(
      xobf, fw1T, f_b1, fgtbuf, hbuf, nullptr, nullptr, 256);
  mfma_gemm<256, 0, 3, false><<<dim3(2, NTOT / 128), 256, 0, stream>>>(
      hbuf, fw2T, f_b2, nullptr, out, gatebuf, feats, 256);
  (void)in_sizes; (void)n_in; (void)out_size; (void)ws_size;
}

// Round 5
// 1539.092 us; speedup vs baseline: 3.2012x; 1.4707x over previous
//
#include <hip/hip_runtime.h>
#include <hip/hip_bf16.h>
#include <math.h>

#define D_DIM 256
#define NHEAD 8
#define HDIM 32
#define PATCH 256
#define NCLOUD 4
#define LPC 32768
#define NTOT (NCLOUD * LPC)
#define MLPD 512
#define PEHID 64
#define LN_EPS 1e-5f
#define NCHUNK 4
#define CROWS (NTOT / NCHUNK)   // 32768 rows per chunk

typedef unsigned long long u64;
typedef unsigned short u16;
typedef short bf16x8 __attribute__((ext_vector_type(8)));  // 8 bf16 (4 VGPRs)
typedef float f32x4 __attribute__((ext_vector_type(4)));

__device__ __forceinline__ u16 f2bf(float x) {
  unsigned u = __float_as_uint(x);
  u += 0x7fffu + ((u >> 16) & 1u);
  return (u16)(u >> 16);
}
__device__ __forceinline__ float bf2f(u16 u) {
  return __uint_as_float(((unsigned)u) << 16);
}

// async global->LDS DMA, 16B per lane; lds ptr must be wave-uniform base (+lane*16 implicit)
__device__ __forceinline__ void gload_lds16(const u16* g, u16* l) {
  __builtin_amdgcn_global_load_lds((const __attribute__((address_space(1))) void*)g,
                                   (__attribute__((address_space(3))) void*)l, 16, 0, 0);
}

// ---------------- per-cloud coordinate stats ----------------
// stats[c*16 + {0..2 mean, 3..5 pescale, 6..8 kmin, 9..11 kscale}]
__global__ __launch_bounds__(256) void stats_kernel(const float* __restrict__ coord,
                                                    float* __restrict__ stats) {
  const int c = blockIdx.x, t = threadIdx.x;
  float sm[3] = {0.f, 0.f, 0.f};
  float mn[3] = {1e30f, 1e30f, 1e30f};
  float mx[3] = {-1e30f, -1e30f, -1e30f};
  const float* cp = coord + (size_t)c * LPC * 3;
  for (int i = t; i < LPC; i += 256) {
#pragma unroll
    for (int a = 0; a < 3; a++) {
      float v = cp[(size_t)i * 3 + a];
      sm[a] += v;
      mn[a] = fminf(mn[a], v);
      mx[a] = fmaxf(mx[a], v);
    }
  }
  __shared__ float sb[256];
  float rsum[3], rmn[3], rmx[3];
#pragma unroll
  for (int a = 0; a < 3; a++) {
    sb[t] = sm[a]; __syncthreads();
    for (int s = 128; s > 0; s >>= 1) { if (t < s) sb[t] += sb[t + s]; __syncthreads(); }
    rsum[a] = sb[0]; __syncthreads();
    sb[t] = mn[a]; __syncthreads();
    for (int s = 128; s > 0; s >>= 1) { if (t < s) sb[t] = fminf(sb[t], sb[t + s]); __syncthreads(); }
    rmn[a] = sb[0]; __syncthreads();
    sb[t] = mx[a]; __syncthreads();
    for (int s = 128; s > 0; s >>= 1) { if (t < s) sb[t] = fmaxf(sb[t], sb[t + s]); __syncthreads(); }
    rmx[a] = sb[0]; __syncthreads();
  }
  if (t == 0) {
    float* st = stats + c * 16;
#pragma unroll
    for (int a = 0; a < 3; a++) {
      float mean = rsum[a] / (float)LPC;
      st[a] = mean;
      st[3 + a] = fmaxf(fmaxf(rmx[a] - mean, mean - rmn[a]), 1e-6f);
      st[6 + a] = rmn[a];
      st[9 + a] = fmaxf(rmx[a] - rmn[a], 1e-6f);
    }
  }
}

// ---------------- serialization keys (bit-exact vs numpy; stable tie-break) ----------------
__global__ __launch_bounds__(256) void key_kernel(const float* __restrict__ coord,
                                                  const float* __restrict__ stats,
                                                  u64* __restrict__ keys) {
#pragma clang fp contract(off)
  const int g = blockIdx.x * 256 + threadIdx.x;
  const int c = g >> 15;
  const float* st = stats + c * 16;
  float k0 = (coord[(size_t)g * 3 + 0] - st[6]) / st[9];
  float k1 = (coord[(size_t)g * 3 + 1] - st[7]) / st[10];
  float k2 = (coord[(size_t)g * 3 + 2] - st[8]) / st[11];
  float key = k0 + 2.17f * k1;
  key = key + 3.31f * k2;
  keys[g] = ((u64)__float_as_uint(key) << 32) | (unsigned)(g & (LPC - 1));
}

// ---------------- bitonic sort (per-cloud, u64 packed key|idx) ----------------
__global__ __launch_bounds__(256) void sort_local_kernel(u64* __restrict__ keys) {
  __shared__ u64 s[4096];
  const int base = blockIdx.x * 4096;
  const int t = threadIdx.x;
  for (int i = t; i < 4096; i += 256) s[i] = keys[base + i];
  __syncthreads();
  for (int k = 2; k <= 4096; k <<= 1) {
    for (int j = k >> 1; j > 0; j >>= 1) {
      for (int p = t; p < 2048; p += 256) {
        int i = ((p & ~(j - 1)) << 1) | (p & (j - 1));
        int l = i | j;
        bool asc = (((base + i) & (LPC - 1)) & k) == 0;
        u64 a = s[i], bb = s[l];
        if (asc ? (a > bb) : (a < bb)) { s[i] = bb; s[l] = a; }
      }
      __syncthreads();
    }
  }
  for (int i = t; i < 4096; i += 256) keys[base + i] = s[i];
}

__global__ __launch_bounds__(256) void sort_global_kernel(u64* __restrict__ keys, int k, int j) {
  int p = blockIdx.x * 256 + threadIdx.x;
  int i = ((p & ~(j - 1)) << 1) | (p & (j - 1));
  int l = i | j;
  bool asc = ((i & (LPC - 1)) & k) == 0;
  u64 a = keys[i], b = keys[l];
  if (asc ? (a > b) : (a < b)) { keys[i] = b; keys[l] = a; }
}

__global__ __launch_bounds__(256) void sort_finish_kernel(u64* __restrict__ keys, int k) {
  __shared__ u64 s[4096];
  const int base = blockIdx.x * 4096;
  const int t = threadIdx.x;
  for (int i = t; i < 4096; i += 256) s[i] = keys[base + i];
  __syncthreads();
  for (int j = 2048; j > 0; j >>= 1) {
    for (int p = t; p < 2048; p += 256) {
      int i = ((p & ~(j - 1)) << 1) | (p & (j - 1));
      int l = i | j;
      bool asc = (((base + i) & (LPC - 1)) & k) == 0;
      u64 a = s[i], bb = s[l];
      if (asc ? (a > bb) : (a < bb)) { s[i] = bb; s[l] = a; }
    }
    __syncthreads();
  }
  for (int i = t; i < 4096; i += 256) keys[base + i] = s[i];
}

// ---------------- order + rank from sorted keys ----------------
__global__ __launch_bounds__(256) void rank_kernel(const u64* __restrict__ keys,
                                                   int* __restrict__ order,
                                                   int* __restrict__ rank) {
  const int g = blockIdx.x * 256 + threadIdx.x;
  const int src = (int)(unsigned)(keys[g] & 0xffffffffULL) + (g & ~(LPC - 1));
  order[g] = src;
  rank[src] = g;
}

// ---------------- weight transpose + fp32->bf16: dst[C][R] = src[R][C] ----------------
__global__ __launch_bounds__(256) void wtrans_kernel(const float* __restrict__ src,
                                                     u16* __restrict__ dst, int R, int C) {
  __shared__ float t[32][33];
  const int bx = blockIdx.x * 32, by = blockIdx.y * 32;
  const int lc = threadIdx.x & 31, lr = threadIdx.x >> 5;  // 8 rows per pass
  for (int i = 0; i < 32; i += 8) t[lr + i][lc] = src[(size_t)(by + lr + i) * C + bx + lc];
  __syncthreads();
  for (int i = 0; i < 32; i += 8)
    dst[(size_t)(bx + lr + i) * R + by + lc] = f2bf(t[lc][lr + i]);
}

// ---------------- fp32 -> bf16 elementwise ----------------
__global__ __launch_bounds__(256) void conv_bf16_kernel(const float* __restrict__ in,
                                                        u16* __restrict__ out) {
  size_t i = ((size_t)blockIdx.x * 256 + threadIdx.x) * 4;
  float4 v = *(const float4*)(in + i);
  ushort4 o;
  o.x = f2bf(v.x); o.y = f2bf(v.y); o.z = f2bf(v.z); o.w = f2bf(v.w);
  *(ushort4*)(out + i) = o;
}

// ---------------- H = relu(scs @ pw1 + pb1), bf16 [N][64] ----------------
__global__ __launch_bounds__(256) void h_kernel(const float* __restrict__ coord,
                                                const float* __restrict__ stats,
                                                const float* __restrict__ pw1,
                                                const float* __restrict__ pb1,
                                                u16* __restrict__ H) {
  const int idx = blockIdx.x * 256 + threadIdx.x;
  const int row = idx >> 6, j = idx & 63;
  const int c = row >> 15;
  const float* st = stats + c * 16;
  float s0 = (coord[(size_t)row * 3 + 0] - st[0]) / st[3];
  float s1 = (coord[(size_t)row * 3 + 1] - st[1]) / st[4];
  float s2 = (coord[(size_t)row * 3 + 2] - st[2]) / st[5];
  float h = pb1[j] + s0 * pw1[j] + s1 * pw1[64 + j] + s2 * pw1[128 + j];
  H[idx] = f2bf(fmaxf(h, 0.f));
}

// ---------------- wave-per-row: xs[rank[row]] = LN(feats + pe) (fp32) ----------------
__global__ __launch_bounds__(256) void add_ln_kernel(const float* __restrict__ feats,
                                                     const u16* __restrict__ pe,
                                                     const int* __restrict__ rank,
                                                     const float* __restrict__ g,
                                                     const float* __restrict__ b,
                                                     float* __restrict__ xs) {
  const int row = blockIdx.x * 4 + (threadIdx.x >> 6);
  const int lane = threadIdx.x & 63;
  float4 f = *(const float4*)(feats + (size_t)row * 256 + lane * 4);
  ushort4 p = *(const ushort4*)(pe + (size_t)row * 256 + lane * 4);
  float v0 = f.x + bf2f(p.x), v1 = f.y + bf2f(p.y);
  float v2 = f.z + bf2f(p.z), v3 = f.w + bf2f(p.w);
  float s = v0 + v1 + v2 + v3;
#pragma unroll
  for (int o = 32; o > 0; o >>= 1) s += __shfl_xor(s, o);
  float mean = s * (1.f / 256.f);
  float d0 = v0 - mean, d1 = v1 - mean, d2 = v2 - mean, d3 = v3 - mean;
  float ss = d0 * d0 + d1 * d1 + d2 * d2 + d3 * d3;
#pragma unroll
  for (int o = 32; o > 0; o >>= 1) ss += __shfl_xor(ss, o);
  float inv = 1.f / sqrtf(ss * (1.f / 256.f) + LN_EPS);
  float4 gv = *(const float4*)(g + lane * 4);
  float4 bv = *(const float4*)(b + lane * 4);
  int dst = rank[row];
  float4 o4;
  o4.x = d0 * inv * gv.x + bv.x; o4.y = d1 * inv * gv.y + bv.y;
  o4.z = d2 * inv * gv.z + bv.z; o4.w = d3 * inv * gv.w + bv.w;
  *(float4*)(xs + (size_t)dst * 256 + lane * 4) = o4;
}

// ---------------- wave-per-row LN: fp32 in -> bf16 out ----------------
__global__ __launch_bounds__(256) void ln_bf16_kernel(const float* __restrict__ in,
                                                      const float* __restrict__ g,
                                                      const float* __restrict__ b,
                                                      u16* __restrict__ out) {
  const int row = blockIdx.x * 4 + (threadIdx.x >> 6);
  const int lane = threadIdx.x & 63;
  float4 v = *(const float4*)(in + (size_t)row * 256 + lane * 4);
  float s = v.x + v.y + v.z + v.w;
#pragma unroll
  for (int o = 32; o > 0; o >>= 1) s += __shfl_xor(s, o);
  float mean = s * (1.f / 256.f);
  float d0 = v.x - mean, d1 = v.y - mean, d2 = v.z - mean, d3 = v.w - mean;
  float ss = d0 * d0 + d1 * d1 + d2 * d2 + d3 * d3;
#pragma unroll
  for (int o = 32; o > 0; o >>= 1) ss += __shfl_xor(ss, o);
  float inv = 1.f / sqrtf(ss * (1.f / 256.f) + LN_EPS);
  float4 gv = *(const float4*)(g + lane * 4);
  float4 bv = *(const float4*)(b + lane * 4);
  ushort4 o4;
  o4.x = f2bf(d0 * inv * gv.x + bv.x); o4.y = f2bf(d1 * inv * gv.y + bv.y);
  o4.z = f2bf(d2 * inv * gv.z + bv.z); o4.w = f2bf(d3 * inv * gv.w + bv.w);
  *(ushort4*)(out + (size_t)row * 256 + lane * 4) = o4;
}

// ---------------- scatter xs (fp32, serialized) -> xo (bf16, original order) ----------------
__global__ __launch_bounds__(256) void scatter_bf16_kernel(const int* __restrict__ order,
                                                           const float* __restrict__ xs,
                                                           u16* __restrict__ xo) {
  const int row = blockIdx.x * 4 + (threadIdx.x >> 6);
  const int lane = threadIdx.x & 63;
  float4 v = *(const float4*)(xs + (size_t)row * 256 + lane * 4);
  const int dst = order[row];
  ushort4 o;
  o.x = f2bf(v.x); o.y = f2bf(v.y); o.z = f2bf(v.z); o.w = f2bf(v.w);
  *(ushort4*)(xo + (size_t)dst * 256 + lane * 4) = o;
}

// ---------------- MFMA GEMM (m97 structure): C[M x Ko] = act(A@Wt^T + bias) ----------------
// MODE: 0 fp32 store, 1 fp32 resid +=, 2 bf16 store, 3 final out=feats+gate*v
template <int K, int ACT, int MODE, bool EXTRA>
__global__ __launch_bounds__(256, 4) void mfma_gemm(const u16* __restrict__ A,
                                                    const u16* __restrict__ Wt,
                                                    const float* __restrict__ bias,
                                                    const float* __restrict__ extra,
                                                    void* __restrict__ Cout,
                                                    const u16* __restrict__ gate,
                                                    const float* __restrict__ feats, int Ko) {
  __shared__ __align__(16) u16 Al[128 * 32];
  __shared__ __align__(16) u16 Bl[128 * 32];
  const int tid = threadIdx.x;
  const int lane = tid & 63, wave = tid >> 6;
  const int wr = wave >> 1, wc = wave & 1;
  const int l15 = lane & 15, l4 = lane >> 4;
  const size_t row0 = (size_t)blockIdx.y * 128;
  const int col0 = blockIdx.x * 128;
  const int q0 = wave * 64 + lane;
  const int q1 = q0 + 256;
  const u16* gA0 = A + (row0 + (q0 >> 2)) * K + (q0 & 3) * 8;
  const u16* gA1 = A + (row0 + (q1 >> 2)) * K + (q1 & 3) * 8;
  const u16* gB0 = Wt + (size_t)(col0 + (q0 >> 2)) * K + (q0 & 3) * 8;
  const u16* gB1 = Wt + (size_t)(col0 + (q1 >> 2)) * K + (q1 & 3) * 8;
  u16* lA0 = Al + wave * 512;
  u16* lA1 = Al + 2048 + wave * 512;
  u16* lB0 = Bl + wave * 512;
  u16* lB1 = Bl + 2048 + wave * 512;
  f32x4 acc[4][4];
#pragma unroll
  for (int i = 0; i < 4; i++)
#pragma unroll
    for (int j = 0; j < 4; j++) acc[i][j] = f32x4{0.f, 0.f, 0.f, 0.f};
#pragma unroll 1
  for (int k0 = 0; k0 < K; k0 += 32) {
    gload_lds16(gA0 + k0, lA0);
    gload_lds16(gA1 + k0, lA1);
    gload_lds16(gB0 + k0, lB0);
    gload_lds16(gB1 + k0, lB1);
    __syncthreads();
    bf16x8 af[4], bfr[4];
#pragma unroll
    for (int rb = 0; rb < 4; rb++)
      af[rb] = *(const bf16x8*)&Al[(wr * 64 + rb * 16 + l15) * 32 + l4 * 8];
#pragma unroll
    for (int cb = 0; cb < 4; cb++)
      bfr[cb] = *(const bf16x8*)&Bl[(wc * 64 + cb * 16 + l15) * 32 + l4 * 8];
#pragma unroll
    for (int rb = 0; rb < 4; rb++)
#pragma unroll
      for (int cb = 0; cb < 4; cb++)
        acc[rb][cb] = __builtin_amdgcn_mfma_f32_16x16x32_bf16(af[rb], bfr[cb], acc[rb][cb], 0, 0, 0);
    __syncthreads();
  }
#pragma unroll
  for (int rb = 0; rb < 4; rb++)
#pragma unroll
    for (int cb = 0; cb < 4; cb++)
#pragma unroll
      for (int r = 0; r < 4; r++) {
        size_t row = row0 + wr * 64 + rb * 16 + l4 * 4 + r;
        int col = col0 + wc * 64 + cb * 16 + l15;
        float v = acc[rb][cb][r] + bias[col];
        if (EXTRA) v += extra[((int)(row >> 15)) * 256 + col];
        if (ACT == 1) v = fmaxf(v, 0.f);
        else if (ACT == 2) v = 0.5f * v * (1.f + erff(v * 0.70710678118654752440f));
        else if (ACT == 3) v = 1.f / (1.f + __expf(-v));
        size_t o = row * (size_t)Ko + col;
        if (MODE == 0) ((float*)Cout)[o] = v;
        else if (MODE == 1) ((float*)Cout)[o] += v;
        else if (MODE == 2) ((u16*)Cout)[o] = f2bf(v);
        else ((float*)Cout)[o] = feats[o] + bf2f(gate[o]) * v;
      }
}

// ---------------- MFMA attention: one (window, head) per block, 4 waves x 64 queries ----
// Swapped QK^T: S^T = mfma(K_frag, Q_frag) -> lane holds 64 scores for query q=lane&15.
// P round-trips through per-wave LDS; PV: O^T = mfma(VT_frag, P_frag). One barrier total.
__global__ __launch_bounds__(256, 3) void attn_mfma_kernel(const u16* __restrict__ qkv,
                                                           u16* __restrict__ ao) {
  __shared__ __align__(16) u16 VT[32 * 264];       // V^T [d][k], padded stride 264
  __shared__ __align__(16) u16 Pl[4][16 * 264];    // per-wave P [q][k]
  const int w = blockIdx.x, h = blockIdx.y;
  const int tid = threadIdx.x;
  const int lane = tid & 63, wave = tid >> 6;
  const int l15 = lane & 15, l4 = lane >> 4;
  const size_t base = (size_t)w * PATCH;
  // stage V^T: thread t owns key row t
  {
    const u16* vrow = qkv + (base + tid) * 768 + 512 + h * HDIM;
#pragma unroll
    for (int d4 = 0; d4 < 8; d4++) {
      ushort4 v4 = *(const ushort4*)(vrow + d4 * 4);
      VT[(d4 * 4 + 0) * 264 + tid] = v4.x;
      VT[(d4 * 4 + 1) * 264 + tid] = v4.y;
      VT[(d4 * 4 + 2) * 264 + tid] = v4.z;
      VT[(d4 * 4 + 3) * 264 + tid] = v4.w;
    }
  }
  __syncthreads();
  u16* Pw = &Pl[wave][0];
  const float scale = 0.17677669529663687f;  // 1/sqrt(32)
  const f32x4 zero = {0.f, 0.f, 0.f, 0.f};
  for (int qt = 0; qt < 4; qt++) {
    const int qbase = wave * 64 + qt * 16;
    // Q fragment (B operand): col=q=l15, k=d=l4*8+j
    bf16x8 qf = *(const bf16x8*)(qkv + (base + qbase + l15) * 768 + h * HDIM + l4 * 8);
    // S^T tiles: 16 MFMAs over key tiles
    f32x4 s[16];
#pragma unroll
    for (int kt = 0; kt < 16; kt++) {
      bf16x8 kf = *(const bf16x8*)(qkv + (base + kt * 16 + l15) * 768 + 256 + h * HDIM + l4 * 8);
      s[kt] = __builtin_amdgcn_mfma_f32_16x16x32_bf16(kf, qf, zero, 0, 0, 0);
    }
    // softmax for query q=l15: 64 lane-local + reduce over 4 lanes (xor 16,32)
    float m = -1e30f;
#pragma unroll
    for (int kt = 0; kt < 16; kt++)
#pragma unroll
      for (int r = 0; r < 4; r++) { s[kt][r] *= scale; m = fmaxf(m, s[kt][r]); }
    m = fmaxf(m, __shfl_xor(m, 16));
    m = fmaxf(m, __shfl_xor(m, 32));
    float lsum = 0.f;
#pragma unroll
    for (int kt = 0; kt < 16; kt++) {
      float p0 = __expf(s[kt][0] - m), p1 = __expf(s[kt][1] - m);
      float p2 = __expf(s[kt][2] - m), p3 = __expf(s[kt][3] - m);
      lsum += (p0 + p1) + (p2 + p3);
      ushort4 pw4;
      pw4.x = f2bf(p0); pw4.y = f2bf(p1); pw4.z = f2bf(p2); pw4.w = f2bf(p3);
      *(ushort4*)&Pw[l15 * 264 + kt * 16 + l4 * 4] = pw4;  // P[q][k..k+3]
    }
    lsum += __shfl_xor(lsum, 16);
    lsum += __shfl_xor(lsum, 32);
    // PV: O^T[d][q] = sum_k V^T[d][k] P[k][q]
    f32x4 o0 = zero, o1 = zero;
#pragma unroll
    for (int kc = 0; kc < 8; kc++) {
      bf16x8 pf = *(const bf16x8*)&Pw[l15 * 264 + kc * 32 + l4 * 8];
      bf16x8 va = *(const bf16x8*)&VT[l15 * 264 + kc * 32 + l4 * 8];
      bf16x8 vb = *(const bf16x8*)&VT[(16 + l15) * 264 + kc * 32 + l4 * 8];
      o0 = __builtin_amdgcn_mfma_f32_16x16x32_bf16(va, pf, o0, 0, 0, 0);
      o1 = __builtin_amdgcn_mfma_f32_16x16x32_bf16(vb, pf, o1, 0, 0, 0);
    }
    float inv = 1.f / lsum;  // lane's q=l15 sum
    u16* op = ao + (base + qbase + l15) * D_DIM + h * HDIM;
    ushort4 w0, w1;
    w0.x = f2bf(o0[0] * inv); w0.y = f2bf(o0[1] * inv);
    w0.z = f2bf(o0[2] * inv); w0.w = f2bf(o0[3] * inv);
    w1.x = f2bf(o1[0] * inv); w1.y = f2bf(o1[1] * inv);
    w1.z = f2bf(o1[2] * inv); w1.w = f2bf(o1[3] * inv);
    *(ushort4*)(op + l4 * 4) = w0;        // d = l4*4+r
    *(ushort4*)(op + 16 + l4 * 4) = w1;   // d = 16+l4*4+r
  }
}

// ---------------- global-token mean from xs (permutation-invariant) ----------------
__global__ __launch_bounds__(256) void gt_partial_kernel(const float* __restrict__ xs,
                                                         float* __restrict__ part) {
  const int s = blockIdx.x, c = blockIdx.y;
  const int t = threadIdx.x;
  float acc = 0.f;
  const size_t base = (size_t)c * LPC + (size_t)s * 256;
  for (int r = 0; r < 256; r++) acc += xs[(base + r) * D_DIM + t];
  part[(size_t)(c * 128 + s) * D_DIM + t] = acc;
}

__global__ __launch_bounds__(256) void gt_reduce_kernel(const float* __restrict__ part,
                                                        float* __restrict__ gt) {
  const int c = blockIdx.x, t = threadIdx.x;
  float s = 0.f;
  for (int i = 0; i < 128; i++) s += part[(size_t)(c * 128 + i) * D_DIM + t];
  gt[c * D_DIM + t] = s * (1.f / (float)LPC);
}

// ---------------- per-cloud gt @ bottom-half weights (fp32) ----------------
__global__ __launch_bounds__(256) void pervec_kernel(const float* __restrict__ gt,
                                                     const float* __restrict__ ggw1,
                                                     const float* __restrict__ fw1,
                                                     float* __restrict__ ggt,
                                                     float* __restrict__ fgt) {
  const int c = blockIdx.x, which = blockIdx.y;
  const int t = threadIdx.x;
  const float* W = which ? fw1 : ggw1;
  float* o = which ? fgt : ggt;
  __shared__ float g[D_DIM];
  g[t] = gt[c * D_DIM + t];
  __syncthreads();
  float acc = 0.f;
#pragma unroll 8
  for (int k = 0; k < D_DIM; k++) acc += g[k] * W[(size_t)(256 + k) * D_DIM + t];
  o[c * D_DIM + t] = acc;
}

extern "C" void kernel_launch(void* const* d_in, const int* in_sizes, int n_in,
                              void* d_out, int out_size, void* d_ws, size_t ws_size,
                              hipStream_t stream) {
  const float* feats = (const float*)d_in[0];
  const float* coord = (const float*)d_in[1];
  const float* pe_w1 = (const float*)d_in[3];
  const float* pe_b1 = (const float*)d_in[4];
  const float* pe_w2 = (const float*)d_in[5];
  const float* pe_b2 = (const float*)d_in[6];
  const float* pre_g = (const float*)d_in[7];
  const float* pre_b = (const float*)d_in[8];
  const float* n1_g = (const float*)d_in[9];
  const float* n1_b = (const float*)d_in[10];
  const float* wqkv = (const float*)d_in[11];
  const float* bqkv = (const float*)d_in[12];
  const float* wo = (const float*)d_in[13];
  const float* bo = (const float*)d_in[14];
  const float* n2_g = (const float*)d_in[15];
  const float* n2_b = (const float*)d_in[16];
  const float* m_w1 = (const float*)d_in[17];
  const float* m_b1 = (const float*)d_in[18];
  const float* m_w2 = (const float*)d_in[19];
  const float* m_b2 = (const float*)d_in[20];
  const float* gg_w1 = (const float*)d_in[21];
  const float* gg_b1 = (const float*)d_in[22];
  const float* gg_w2 = (const float*)d_in[23];
  const float* gg_b2 = (const float*)d_in[24];
  const float* f_w1 = (const float*)d_in[25];
  const float* f_b1 = (const float*)d_in[26];
  const float* f_w2 = (const float*)d_in[27];
  const float* f_b2 = (const float*)d_in[28];
  float* out = (float*)d_out;

  // ---------------- workspace layout (~306 MiB) ----------------
  char* ws = (char*)d_ws;
  float* xs = (float*)(ws);                         // [0,128MiB) fp32 residual stream
  u16* hbuf = (u16*)(ws + 134217728);               // [128,192MiB) bf16 (pe / LN out / g1 / u1)
  u16* qkvchunk = (u16*)(ws + 201326592);           // [192..240MiB) chunk qkv (48 MiB)
  u16* aochunk = (u16*)(ws + 251658240);            // [240..256MiB) chunk attn out (16 MiB)
  u16* tbuf = (u16*)(ws + 268435456);               // [256..288MiB) chunk MLP mid (32 MiB)
  u16* Hbuf = (u16*)(ws + 268435456);               // [N][64] bf16 (16 MiB, pre-attn only)
  u16* xobf = (u16*)(ws + 201326592);               // post-MLP: bf16 xo (64 MiB, reuses qkv region)
  size_t off = 301989888;
  u64* keybuf = (u64*)(ws + off); off += (size_t)NTOT * 8;
  int* orderbuf = (int*)(ws + off); off += (size_t)NTOT * 4;
  int* rankbuf = (int*)(ws + off); off += (size_t)NTOT * 4;
  float* statsbuf = (float*)(ws + off); off += 4096;
  float* gtpart = (float*)(ws + off); off += (size_t)NCLOUD * 128 * D_DIM * 4;
  float* gtbuf = (float*)(ws + off); off += 4096;
  float* ggtbuf = (float*)(ws + off); off += 4096;
  float* fgtbuf = (float*)(ws + off); off += 4096;
  u16* wqkvT = (u16*)(ws + off); off += 768 * 256 * 2;
  u16* woT = (u16*)(ws + off); off += 256 * 256 * 2;
  u16* mw1T = (u16*)(ws + off); off += 512 * 256 * 2;
  u16* mw2T = (u16*)(ws + off); off += 256 * 512 * 2;
  u16* ggw1T = (u16*)(ws + off); off += 256 * 256 * 2;
  u16* ggw2T = (u16*)(ws + off); off += 256 * 256 * 2;
  u16* fw1T = (u16*)(ws + off); off += 256 * 256 * 2;
  u16* fw2T = (u16*)(ws + off); off += 256 * 256 * 2;
  u16* pw2T = (u16*)(ws + off); off += 64 * 256 * 2;
  u16* featsbf = (u16*)(ws);                        // aliases dead xs region [0,64MiB)
  u16* gatebuf = (u16*)(ws + 67108864);             // aliases dead xs region [64,128MiB)

  // 1. stats + keys + sort + order/rank
  stats_kernel<<<NCLOUD, 256, 0, stream>>>(coord, statsbuf);
  key_kernel<<<NTOT / 256, 256, 0, stream>>>(coord, statsbuf, keybuf);
  sort_local_kernel<<<NTOT / 4096, 256, 0, stream>>>(keybuf);
  for (int k = 8192; k <= 32768; k <<= 1) {
    for (int j = k >> 1; j >= 4096; j >>= 1)
      sort_global_kernel<<<NTOT / 512, 256, 0, stream>>>(keybuf, k, j);
    sort_finish_kernel<<<NTOT / 4096, 256, 0, stream>>>(keybuf, k);
  }
  rank_kernel<<<NTOT / 256, 256, 0, stream>>>(keybuf, orderbuf, rankbuf);
  // 2. weight convert+transpose (bf16)
  wtrans_kernel<<<dim3(24, 8), 256, 0, stream>>>(wqkv, wqkvT, 256, 768);
  wtrans_kernel<<<dim3(8, 8), 256, 0, stream>>>(wo, woT, 256, 256);
  wtrans_kernel<<<dim3(16, 8), 256, 0, stream>>>(m_w1, mw1T, 256, 512);
  wtrans_kernel<<<dim3(8, 16), 256, 0, stream>>>(m_w2, mw2T, 512, 256);
  wtrans_kernel<<<dim3(8, 8), 256, 0, stream>>>(gg_w1, ggw1T, 256, 256);  // top half
  wtrans_kernel<<<dim3(8, 8), 256, 0, stream>>>(gg_w2, ggw2T, 256, 256);
  wtrans_kernel<<<dim3(8, 8), 256, 0, stream>>>(f_w1, fw1T, 256, 256);    // top half
  wtrans_kernel<<<dim3(8, 8), 256, 0, stream>>>(f_w2, fw2T, 256, 256);
  wtrans_kernel<<<dim3(8, 2), 256, 0, stream>>>(pe_w2, pw2T, 64, 256);
  // 3. PE: H = relu(scs@pw1+b1); pe = H @ pw2 + b2 (MFMA, K=64) -> hbuf bf16
  h_kernel<<<NTOT * 64 / 256, 256, 0, stream>>>(coord, statsbuf, pe_w1, pe_b1, Hbuf);
  mfma_gemm<64, 0, 2, false><<<dim3(2, NTOT / 128), 256, 0, stream>>>(
      Hbuf, pw2T, pe_b2, nullptr, hbuf, nullptr, nullptr, 256);
  // 4. xs[rank] = LN(feats + pe)
  add_ln_kernel<<<NTOT / 4, 256, 0, stream>>>(feats, hbuf, rankbuf, pre_g, pre_b, xs);
  // 5. attention block (chunked): xs += attn(LN1(xs)) @ wo + bo
  ln_bf16_kernel<<<NTOT / 4, 256, 0, stream>>>(xs, n1_g, n1_b, hbuf);
  for (int ch = 0; ch < NCHUNK; ch++) {
    const size_t ro = (size_t)ch * CROWS;
    mfma_gemm<256, 0, 2, false><<<dim3(6, CROWS / 128), 256, 0, stream>>>(
        hbuf + ro * 256, wqkvT, bqkv, nullptr, qkvchunk, nullptr, nullptr, 768);
    attn_mfma_kernel<<<dim3(CROWS / PATCH, NHEAD), 256, 0, stream>>>(qkvchunk, aochunk);
    mfma_gemm<256, 0, 1, false><<<dim3(2, CROWS / 128), 256, 0, stream>>>(
        aochunk, woT, bo, nullptr, xs + ro * 256, nullptr, nullptr, 256);
  }
  // 6. MLP block (chunked): xs += gelu(LN2(xs)@m_w1+b)@m_w2+b
  ln_bf16_kernel<<<NTOT / 4, 256, 0, stream>>>(xs, n2_g, n2_b, hbuf);
  for (int ch = 0; ch < NCHUNK; ch++) {
    const size_t ro = (size_t)ch * CROWS;
    mfma_gemm<256, 2, 2, false><<<dim3(MLPD / 128, CROWS / 128), 256, 0, stream>>>(
        hbuf + ro * 256, mw1T, m_b1, nullptr, tbuf, nullptr, nullptr, 512);
    mfma_gemm<512, 0, 1, false><<<dim3(2, CROWS / 128), 256, 0, stream>>>(
        tbuf, mw2T, m_b2, nullptr, xs + ro * 256, nullptr, nullptr, 256);
  }
  // 7. un-serialize to bf16 + global token from xs (mean is permutation-invariant)
  scatter_bf16_kernel<<<NTOT / 4, 256, 0, stream>>>(orderbuf, xs, xobf);
  gt_partial_kernel<<<dim3(128, NCLOUD), 256, 0, stream>>>(xs, gtpart);
  gt_reduce_kernel<<<NCLOUD, 256, 0, stream>>>(gtpart, gtbuf);
  pervec_kernel<<<dim3(NCLOUD, 2), 256, 0, stream>>>(gtbuf, gg_w1, f_w1, ggtbuf, fgtbuf);
  // 8. xs region dead -> feats bf16 + gate
  conv_bf16_kernel<<<NTOT * 256 / 1024, 256, 0, stream>>>(feats, featsbf);
  mfma_gemm<256, 1, 2, true><<<dim3(2, NTOT / 128), 256, 0, stream>>>(
      featsbf, ggw1T, gg_b1, ggtbuf, hbuf, nullptr, nullptr, 256);
  mfma_gemm<256, 3, 2, false><<<dim3(2, NTOT / 128), 256, 0, stream>>>(
      hbuf, ggw2T, gg_b2, nullptr, gatebuf, nullptr, nullptr, 256);
  // 9. fuse path + final: out = feats + gate * (relu(xo@f_w1+fgt+b)@f_w2+b)
  mfma_gemm<256, 1, 2, true><<<dim3(2, NTOT / 128), 256, 0, stream>>>(
      xobf, fw1T, f_b1, fgtbuf, hbuf, nullptr, nullptr, 256);
  mfma_gemm<256, 0, 3, false><<<dim3(2, NTOT / 128), 256, 0, stream>>>(
      hbuf, fw2T, f_b2, nullptr, out, gatebuf, feats, 256);
  (void)in_sizes; (void)n_in; (void)out_size; (void)ws_size;
}

// Round 6
// 1421.614 us; speedup vs baseline: 3.4657x; 1.0826x over previous
//
#include <hip/hip_runtime.h>
#include <hip/hip_bf16.h>
#include <math.h>

#define D_DIM 256
#define NHEAD 8
#define HDIM 32
#define PATCH 256
#define NCLOUD 4
#define LPC 32768
#define NTOT (NCLOUD * LPC)
#define MLPD 512
#define PEHID 64
#define LN_EPS 1e-5f
#define NCHUNK 4
#define CROWS (NTOT / NCHUNK)   // 32768 rows per chunk

typedef unsigned long long u64;
typedef unsigned short u16;
typedef short bf16x8 __attribute__((ext_vector_type(8)));  // 8 bf16 (4 VGPRs)
typedef float f32x4 __attribute__((ext_vector_type(4)));

__device__ __forceinline__ u16 f2bf(float x) {
  unsigned u = __float_as_uint(x);
  u += 0x7fffu + ((u >> 16) & 1u);
  return (u16)(u >> 16);
}
__device__ __forceinline__ float bf2f(u16 u) {
  return __uint_as_float(((unsigned)u) << 16);
}

// async global->LDS DMA, 16B per lane; lds ptr must be wave-uniform base (+lane*16 implicit)
__device__ __forceinline__ void gload_lds16(const u16* g, u16* l) {
  __builtin_amdgcn_global_load_lds((const __attribute__((address_space(1))) void*)g,
                                   (__attribute__((address_space(3))) void*)l, 16, 0, 0);
}

// ---------------- per-cloud coordinate stats ----------------
// stats[c*16 + {0..2 mean, 3..5 pescale, 6..8 kmin, 9..11 kscale}]
__global__ __launch_bounds__(256) void stats_kernel(const float* __restrict__ coord,
                                                    float* __restrict__ stats) {
  const int c = blockIdx.x, t = threadIdx.x;
  float sm[3] = {0.f, 0.f, 0.f};
  float mn[3] = {1e30f, 1e30f, 1e30f};
  float mx[3] = {-1e30f, -1e30f, -1e30f};
  const float* cp = coord + (size_t)c * LPC * 3;
  for (int i = t; i < LPC; i += 256) {
#pragma unroll
    for (int a = 0; a < 3; a++) {
      float v = cp[(size_t)i * 3 + a];
      sm[a] += v;
      mn[a] = fminf(mn[a], v);
      mx[a] = fmaxf(mx[a], v);
    }
  }
  __shared__ float sb[256];
  float rsum[3], rmn[3], rmx[3];
#pragma unroll
  for (int a = 0; a < 3; a++) {
    sb[t] = sm[a]; __syncthreads();
    for (int s = 128; s > 0; s >>= 1) { if (t < s) sb[t] += sb[t + s]; __syncthreads(); }
    rsum[a] = sb[0]; __syncthreads();
    sb[t] = mn[a]; __syncthreads();
    for (int s = 128; s > 0; s >>= 1) { if (t < s) sb[t] = fminf(sb[t], sb[t + s]); __syncthreads(); }
    rmn[a] = sb[0]; __syncthreads();
    sb[t] = mx[a]; __syncthreads();
    for (int s = 128; s > 0; s >>= 1) { if (t < s) sb[t] = fmaxf(sb[t], sb[t + s]); __syncthreads(); }
    rmx[a] = sb[0]; __syncthreads();
  }
  if (t == 0) {
    float* st = stats + c * 16;
#pragma unroll
    for (int a = 0; a < 3; a++) {
      float mean = rsum[a] / (float)LPC;
      st[a] = mean;
      st[3 + a] = fmaxf(fmaxf(rmx[a] - mean, mean - rmn[a]), 1e-6f);
      st[6 + a] = rmn[a];
      st[9 + a] = fmaxf(rmx[a] - rmn[a], 1e-6f);
    }
  }
}

// ---------------- serialization keys (bit-exact vs numpy; stable tie-break) ----------------
__global__ __launch_bounds__(256) void key_kernel(const float* __restrict__ coord,
                                                  const float* __restrict__ stats,
                                                  u64* __restrict__ keys) {
#pragma clang fp contract(off)
  const int g = blockIdx.x * 256 + threadIdx.x;
  const int c = g >> 15;
  const float* st = stats + c * 16;
  float k0 = (coord[(size_t)g * 3 + 0] - st[6]) / st[9];
  float k1 = (coord[(size_t)g * 3 + 1] - st[7]) / st[10];
  float k2 = (coord[(size_t)g * 3 + 2] - st[8]) / st[11];
  float key = k0 + 2.17f * k1;
  key = key + 3.31f * k2;
  keys[g] = ((u64)__float_as_uint(key) << 32) | (unsigned)(g & (LPC - 1));
}

// ---------------- bitonic sort (per-cloud, u64 packed key|idx), 1024 threads ----------------
__global__ __launch_bounds__(1024) void sort_local_kernel(u64* __restrict__ keys) {
  __shared__ u64 s[4096];
  const int base = blockIdx.x * 4096;
  const int t = threadIdx.x;
  for (int i = t; i < 4096; i += 1024) s[i] = keys[base + i];
  __syncthreads();
  for (int k = 2; k <= 4096; k <<= 1) {
    for (int j = k >> 1; j > 0; j >>= 1) {
      for (int p = t; p < 2048; p += 1024) {
        int i = ((p & ~(j - 1)) << 1) | (p & (j - 1));
        int l = i | j;
        bool asc = (((base + i) & (LPC - 1)) & k) == 0;
        u64 a = s[i], bb = s[l];
        if (asc ? (a > bb) : (a < bb)) { s[i] = bb; s[l] = a; }
      }
      __syncthreads();
    }
  }
  for (int i = t; i < 4096; i += 1024) keys[base + i] = s[i];
}

__global__ __launch_bounds__(256) void sort_global_kernel(u64* __restrict__ keys, int k, int j) {
  int p = blockIdx.x * 256 + threadIdx.x;
  int i = ((p & ~(j - 1)) << 1) | (p & (j - 1));
  int l = i | j;
  bool asc = ((i & (LPC - 1)) & k) == 0;
  u64 a = keys[i], b = keys[l];
  if (asc ? (a > b) : (a < b)) { keys[i] = b; keys[l] = a; }
}

__global__ __launch_bounds__(1024) void sort_finish_kernel(u64* __restrict__ keys, int k) {
  __shared__ u64 s[4096];
  const int base = blockIdx.x * 4096;
  const int t = threadIdx.x;
  for (int i = t; i < 4096; i += 1024) s[i] = keys[base + i];
  __syncthreads();
  for (int j = 2048; j > 0; j >>= 1) {
    for (int p = t; p < 2048; p += 1024) {
      int i = ((p & ~(j - 1)) << 1) | (p & (j - 1));
      int l = i | j;
      bool asc = (((base + i) & (LPC - 1)) & k) == 0;
      u64 a = s[i], bb = s[l];
      if (asc ? (a > bb) : (a < bb)) { s[i] = bb; s[l] = a; }
    }
    __syncthreads();
  }
  for (int i = t; i < 4096; i += 1024) keys[base + i] = s[i];
}

// ---------------- order + rank from sorted keys ----------------
__global__ __launch_bounds__(256) void rank_kernel(const u64* __restrict__ keys,
                                                   int* __restrict__ order,
                                                   int* __restrict__ rank) {
  const int g = blockIdx.x * 256 + threadIdx.x;
  const int src = (int)(unsigned)(keys[g] & 0xffffffffULL) + (g & ~(LPC - 1));
  order[g] = src;
  rank[src] = g;
}

// ---------------- weight transpose + fp32->bf16: dst[C][R] = src[R][C] ----------------
__global__ __launch_bounds__(256) void wtrans_kernel(const float* __restrict__ src,
                                                     u16* __restrict__ dst, int R, int C) {
  __shared__ float t[32][33];
  const int bx = blockIdx.x * 32, by = blockIdx.y * 32;
  const int lc = threadIdx.x & 31, lr = threadIdx.x >> 5;  // 8 rows per pass
  for (int i = 0; i < 32; i += 8) t[lr + i][lc] = src[(size_t)(by + lr + i) * C + bx + lc];
  __syncthreads();
  for (int i = 0; i < 32; i += 8)
    dst[(size_t)(bx + lr + i) * R + by + lc] = f2bf(t[lc][lr + i]);
}

// ---------------- fp32 -> bf16 elementwise ----------------
__global__ __launch_bounds__(256) void conv_bf16_kernel(const float* __restrict__ in,
                                                        u16* __restrict__ out) {
  size_t i = ((size_t)blockIdx.x * 256 + threadIdx.x) * 4;
  float4 v = *(const float4*)(in + i);
  ushort4 o;
  o.x = f2bf(v.x); o.y = f2bf(v.y); o.z = f2bf(v.z); o.w = f2bf(v.w);
  *(ushort4*)(out + i) = o;
}

// ---------------- H = relu(scs @ pw1 + pb1), bf16 [N][64] ----------------
__global__ __launch_bounds__(256) void h_kernel(const float* __restrict__ coord,
                                                const float* __restrict__ stats,
                                                const float* __restrict__ pw1,
                                                const float* __restrict__ pb1,
                                                u16* __restrict__ H) {
  const int idx = blockIdx.x * 256 + threadIdx.x;
  const int row = idx >> 6, j = idx & 63;
  const int c = row >> 15;
  const float* st = stats + c * 16;
  float s0 = (coord[(size_t)row * 3 + 0] - st[0]) / st[3];
  float s1 = (coord[(size_t)row * 3 + 1] - st[1]) / st[4];
  float s2 = (coord[(size_t)row * 3 + 2] - st[2]) / st[5];
  float h = pb1[j] + s0 * pw1[j] + s1 * pw1[64 + j] + s2 * pw1[128 + j];
  H[idx] = f2bf(fmaxf(h, 0.f));
}

// ---------------- wave-per-row: xs[rank[row]] = LN(feats + pe) (fp32) ----------------
__global__ __launch_bounds__(256) void add_ln_kernel(const float* __restrict__ feats,
                                                     const u16* __restrict__ pe,
                                                     const int* __restrict__ rank,
                                                     const float* __restrict__ g,
                                                     const float* __restrict__ b,
                                                     float* __restrict__ xs) {
  const int row = blockIdx.x * 4 + (threadIdx.x >> 6);
  const int lane = threadIdx.x & 63;
  float4 f = *(const float4*)(feats + (size_t)row * 256 + lane * 4);
  ushort4 p = *(const ushort4*)(pe + (size_t)row * 256 + lane * 4);
  float v0 = f.x + bf2f(p.x), v1 = f.y + bf2f(p.y);
  float v2 = f.z + bf2f(p.z), v3 = f.w + bf2f(p.w);
  float s = v0 + v1 + v2 + v3;
#pragma unroll
  for (int o = 32; o > 0; o >>= 1) s += __shfl_xor(s, o);
  float mean = s * (1.f / 256.f);
  float d0 = v0 - mean, d1 = v1 - mean, d2 = v2 - mean, d3 = v3 - mean;
  float ss = d0 * d0 + d1 * d1 + d2 * d2 + d3 * d3;
#pragma unroll
  for (int o = 32; o > 0; o >>= 1) ss += __shfl_xor(ss, o);
  float inv = 1.f / sqrtf(ss * (1.f / 256.f) + LN_EPS);
  float4 gv = *(const float4*)(g + lane * 4);
  float4 bv = *(const float4*)(b + lane * 4);
  int dst = rank[row];
  float4 o4;
  o4.x = d0 * inv * gv.x + bv.x; o4.y = d1 * inv * gv.y + bv.y;
  o4.z = d2 * inv * gv.z + bv.z; o4.w = d3 * inv * gv.w + bv.w;
  *(float4*)(xs + (size_t)dst * 256 + lane * 4) = o4;
}

// ---------------- wave-per-row LN: fp32 in -> bf16 out ----------------
__global__ __launch_bounds__(256) void ln_bf16_kernel(const float* __restrict__ in,
                                                      const float* __restrict__ g,
                                                      const float* __restrict__ b,
                                                      u16* __restrict__ out) {
  const int row = blockIdx.x * 4 + (threadIdx.x >> 6);
  const int lane = threadIdx.x & 63;
  float4 v = *(const float4*)(in + (size_t)row * 256 + lane * 4);
  float s = v.x + v.y + v.z + v.w;
#pragma unroll
  for (int o = 32; o > 0; o >>= 1) s += __shfl_xor(s, o);
  float mean = s * (1.f / 256.f);
  float d0 = v.x - mean, d1 = v.y - mean, d2 = v.z - mean, d3 = v.w - mean;
  float ss = d0 * d0 + d1 * d1 + d2 * d2 + d3 * d3;
#pragma unroll
  for (int o = 32; o > 0; o >>= 1) ss += __shfl_xor(ss, o);
  float inv = 1.f / sqrtf(ss * (1.f / 256.f) + LN_EPS);
  float4 gv = *(const float4*)(g + lane * 4);
  float4 bv = *(const float4*)(b + lane * 4);
  ushort4 o4;
  o4.x = f2bf(d0 * inv * gv.x + bv.x); o4.y = f2bf(d1 * inv * gv.y + bv.y);
  o4.z = f2bf(d2 * inv * gv.z + bv.z); o4.w = f2bf(d3 * inv * gv.w + bv.w);
  *(ushort4*)(out + (size_t)row * 256 + lane * 4) = o4;
}

// ---------------- scatter xs (fp32, serialized) -> xo (bf16, original order) ----------------
__global__ __launch_bounds__(256) void scatter_bf16_kernel(const int* __restrict__ order,
                                                           const float* __restrict__ xs,
                                                           u16* __restrict__ xo) {
  const int row = blockIdx.x * 4 + (threadIdx.x >> 6);
  const int lane = threadIdx.x & 63;
  float4 v = *(const float4*)(xs + (size_t)row * 256 + lane * 4);
  const int dst = order[row];
  ushort4 o;
  o.x = f2bf(v.x); o.y = f2bf(v.y); o.z = f2bf(v.z); o.w = f2bf(v.w);
  *(ushort4*)(xo + (size_t)dst * 256 + lane * 4) = o;
}

// ---------------- MFMA GEMM (m97 structure): C[M x Ko] = act(A@Wt^T + bias) ----------------
// MODE: 0 fp32 store, 1 fp32 resid +=, 2 bf16 store
template <int K, int ACT, int MODE, bool EXTRA>
__global__ __launch_bounds__(256, 4) void mfma_gemm(const u16* __restrict__ A,
                                                    const u16* __restrict__ Wt,
                                                    const float* __restrict__ bias,
                                                    const float* __restrict__ extra,
                                                    void* __restrict__ Cout, int Ko) {
  __shared__ __align__(16) u16 Al[128 * 32];
  __shared__ __align__(16) u16 Bl[128 * 32];
  const int tid = threadIdx.x;
  const int lane = tid & 63, wave = tid >> 6;
  const int wr = wave >> 1, wc = wave & 1;
  const int l15 = lane & 15, l4 = lane >> 4;
  const size_t row0 = (size_t)blockIdx.y * 128;
  const int col0 = blockIdx.x * 128;
  const int q0 = wave * 64 + lane;
  const int q1 = q0 + 256;
  const u16* gA0 = A + (row0 + (q0 >> 2)) * K + (q0 & 3) * 8;
  const u16* gA1 = A + (row0 + (q1 >> 2)) * K + (q1 & 3) * 8;
  const u16* gB0 = Wt + (size_t)(col0 + (q0 >> 2)) * K + (q0 & 3) * 8;
  const u16* gB1 = Wt + (size_t)(col0 + (q1 >> 2)) * K + (q1 & 3) * 8;
  u16* lA0 = Al + wave * 512;
  u16* lA1 = Al + 2048 + wave * 512;
  u16* lB0 = Bl + wave * 512;
  u16* lB1 = Bl + 2048 + wave * 512;
  f32x4 acc[4][4];
#pragma unroll
  for (int i = 0; i < 4; i++)
#pragma unroll
    for (int j = 0; j < 4; j++) acc[i][j] = f32x4{0.f, 0.f, 0.f, 0.f};
#pragma unroll 1
  for (int k0 = 0; k0 < K; k0 += 32) {
    gload_lds16(gA0 + k0, lA0);
    gload_lds16(gA1 + k0, lA1);
    gload_lds16(gB0 + k0, lB0);
    gload_lds16(gB1 + k0, lB1);
    __syncthreads();
    bf16x8 af[4], bfr[4];
#pragma unroll
    for (int rb = 0; rb < 4; rb++)
      af[rb] = *(const bf16x8*)&Al[(wr * 64 + rb * 16 + l15) * 32 + l4 * 8];
#pragma unroll
    for (int cb = 0; cb < 4; cb++)
      bfr[cb] = *(const bf16x8*)&Bl[(wc * 64 + cb * 16 + l15) * 32 + l4 * 8];
#pragma unroll
    for (int rb = 0; rb < 4; rb++)
#pragma unroll
      for (int cb = 0; cb < 4; cb++)
        acc[rb][cb] = __builtin_amdgcn_mfma_f32_16x16x32_bf16(af[rb], bfr[cb], acc[rb][cb], 0, 0, 0);
    __syncthreads();
  }
#pragma unroll
  for (int rb = 0; rb < 4; rb++)
#pragma unroll
    for (int cb = 0; cb < 4; cb++)
#pragma unroll
      for (int r = 0; r < 4; r++) {
        size_t row = row0 + wr * 64 + rb * 16 + l4 * 4 + r;
        int col = col0 + wc * 64 + cb * 16 + l15;
        float v = acc[rb][cb][r] + bias[col];
        if (EXTRA) v += extra[((int)(row >> 15)) * 256 + col];
        if (ACT == 1) v = fmaxf(v, 0.f);
        else if (ACT == 2) v = 0.5f * v * (1.f + erff(v * 0.70710678118654752440f));
        else if (ACT == 3) v = 1.f / (1.f + __expf(-v));
        size_t o = row * (size_t)Ko + col;
        if (MODE == 0) ((float*)Cout)[o] = v;
        else if (MODE == 1) ((float*)Cout)[o] += v;
        else ((u16*)Cout)[o] = f2bf(v);
      }
}

// ---------------- fused tail: out = feats + sigmoid(A1@B1+b1) * (A2@B2+b2), K=256 ----------
__global__ __launch_bounds__(256, 2) void fuse2_kernel(const u16* __restrict__ A1,
                                                       const u16* __restrict__ A2,
                                                       const u16* __restrict__ B1t,
                                                       const u16* __restrict__ B2t,
                                                       const float* __restrict__ bias1,
                                                       const float* __restrict__ bias2,
                                                       const float* __restrict__ feats,
                                                       float* __restrict__ out) {
  __shared__ __align__(16) u16 A1l[128 * 32];
  __shared__ __align__(16) u16 A2l[128 * 32];
  __shared__ __align__(16) u16 B1l[128 * 32];
  __shared__ __align__(16) u16 B2l[128 * 32];
  const int tid = threadIdx.x;
  const int lane = tid & 63, wave = tid >> 6;
  const int wr = wave >> 1, wc = wave & 1;
  const int l15 = lane & 15, l4 = lane >> 4;
  const size_t row0 = (size_t)blockIdx.y * 128;
  const int col0 = blockIdx.x * 128;
  const int q0 = wave * 64 + lane;
  const int q1 = q0 + 256;
  const size_t a0off = (row0 + (q0 >> 2)) * 256 + (q0 & 3) * 8;
  const size_t a1off = (row0 + (q1 >> 2)) * 256 + (q1 & 3) * 8;
  const size_t b0off = (size_t)(col0 + (q0 >> 2)) * 256 + (q0 & 3) * 8;
  const size_t b1off = (size_t)(col0 + (q1 >> 2)) * 256 + (q1 & 3) * 8;
  f32x4 acc1[4][4], acc2[4][4];
#pragma unroll
  for (int i = 0; i < 4; i++)
#pragma unroll
    for (int j = 0; j < 4; j++) {
      acc1[i][j] = f32x4{0.f, 0.f, 0.f, 0.f};
      acc2[i][j] = f32x4{0.f, 0.f, 0.f, 0.f};
    }
#pragma unroll 1
  for (int k0 = 0; k0 < 256; k0 += 32) {
    gload_lds16(A1 + a0off + k0, A1l + wave * 512);
    gload_lds16(A1 + a1off + k0, A1l + 2048 + wave * 512);
    gload_lds16(A2 + a0off + k0, A2l + wave * 512);
    gload_lds16(A2 + a1off + k0, A2l + 2048 + wave * 512);
    gload_lds16(B1t + b0off + k0, B1l + wave * 512);
    gload_lds16(B1t + b1off + k0, B1l + 2048 + wave * 512);
    gload_lds16(B2t + b0off + k0, B2l + wave * 512);
    gload_lds16(B2t + b1off + k0, B2l + 2048 + wave * 512);
    __syncthreads();
#pragma unroll
    for (int rb = 0; rb < 4; rb++) {
      bf16x8 a1f = *(const bf16x8*)&A1l[(wr * 64 + rb * 16 + l15) * 32 + l4 * 8];
      bf16x8 a2f = *(const bf16x8*)&A2l[(wr * 64 + rb * 16 + l15) * 32 + l4 * 8];
#pragma unroll
      for (int cb = 0; cb < 4; cb++) {
        bf16x8 b1f = *(const bf16x8*)&B1l[(wc * 64 + cb * 16 + l15) * 32 + l4 * 8];
        bf16x8 b2f = *(const bf16x8*)&B2l[(wc * 64 + cb * 16 + l15) * 32 + l4 * 8];
        acc1[rb][cb] = __builtin_amdgcn_mfma_f32_16x16x32_bf16(a1f, b1f, acc1[rb][cb], 0, 0, 0);
        acc2[rb][cb] = __builtin_amdgcn_mfma_f32_16x16x32_bf16(a2f, b2f, acc2[rb][cb], 0, 0, 0);
      }
    }
    __syncthreads();
  }
#pragma unroll
  for (int rb = 0; rb < 4; rb++)
#pragma unroll
    for (int cb = 0; cb < 4; cb++)
#pragma unroll
      for (int r = 0; r < 4; r++) {
        size_t row = row0 + wr * 64 + rb * 16 + l4 * 4 + r;
        int col = col0 + wc * 64 + cb * 16 + l15;
        float g = 1.f / (1.f + __expf(-(acc1[rb][cb][r] + bias1[col])));
        float fv = acc2[rb][cb][r] + bias2[col];
        size_t o = row * 256 + col;
        out[o] = feats[o] + g * fv;
      }
}

// ---------------- MFMA attention: one (window, head) per block, 4 waves x 64 queries ----
__global__ __launch_bounds__(256, 3) void attn_mfma_kernel(const u16* __restrict__ qkv,
                                                           u16* __restrict__ ao) {
  __shared__ __align__(16) u16 VT[32 * 264];       // V^T [d][k], padded stride 264
  __shared__ __align__(16) u16 Pl[4][16 * 264];    // per-wave P [q][k]
  const int w = blockIdx.x, h = blockIdx.y;
  const int tid = threadIdx.x;
  const int lane = tid & 63, wave = tid >> 6;
  const int l15 = lane & 15, l4 = lane >> 4;
  const size_t base = (size_t)w * PATCH;
  {
    const u16* vrow = qkv + (base + tid) * 768 + 512 + h * HDIM;
#pragma unroll
    for (int d4 = 0; d4 < 8; d4++) {
      ushort4 v4 = *(const ushort4*)(vrow + d4 * 4);
      VT[(d4 * 4 + 0) * 264 + tid] = v4.x;
      VT[(d4 * 4 + 1) * 264 + tid] = v4.y;
      VT[(d4 * 4 + 2) * 264 + tid] = v4.z;
      VT[(d4 * 4 + 3) * 264 + tid] = v4.w;
    }
  }
  __syncthreads();
  u16* Pw = &Pl[wave][0];
  const float scale = 0.17677669529663687f;  // 1/sqrt(32)
  const f32x4 zero = {0.f, 0.f, 0.f, 0.f};
  for (int qt = 0; qt < 4; qt++) {
    const int qbase = wave * 64 + qt * 16;
    bf16x8 qf = *(const bf16x8*)(qkv + (base + qbase + l15) * 768 + h * HDIM + l4 * 8);
    f32x4 s[16];
#pragma unroll
    for (int kt = 0; kt < 16; kt++) {
      bf16x8 kf = *(const bf16x8*)(qkv + (base + kt * 16 + l15) * 768 + 256 + h * HDIM + l4 * 8);
      s[kt] = __builtin_amdgcn_mfma_f32_16x16x32_bf16(kf, qf, zero, 0, 0, 0);
    }
    float m = -1e30f;
#pragma unroll
    for (int kt = 0; kt < 16; kt++)
#pragma unroll
      for (int r = 0; r < 4; r++) { s[kt][r] *= scale; m = fmaxf(m, s[kt][r]); }
    m = fmaxf(m, __shfl_xor(m, 16));
    m = fmaxf(m, __shfl_xor(m, 32));
    float lsum = 0.f;
#pragma unroll
    for (int kt = 0; kt < 16; kt++) {
      float p0 = __expf(s[kt][0] - m), p1 = __expf(s[kt][1] - m);
      float p2 = __expf(s[kt][2] - m), p3 = __expf(s[kt][3] - m);
      lsum += (p0 + p1) + (p2 + p3);
      ushort4 pw4;
      pw4.x = f2bf(p0); pw4.y = f2bf(p1); pw4.z = f2bf(p2); pw4.w = f2bf(p3);
      *(ushort4*)&Pw[l15 * 264 + kt * 16 + l4 * 4] = pw4;
    }
    lsum += __shfl_xor(lsum, 16);
    lsum += __shfl_xor(lsum, 32);
    f32x4 o0 = zero, o1 = zero;
#pragma unroll
    for (int kc = 0; kc < 8; kc++) {
      bf16x8 pf = *(const bf16x8*)&Pw[l15 * 264 + kc * 32 + l4 * 8];
      bf16x8 va = *(const bf16x8*)&VT[l15 * 264 + kc * 32 + l4 * 8];
      bf16x8 vb = *(const bf16x8*)&VT[(16 + l15) * 264 + kc * 32 + l4 * 8];
      o0 = __builtin_amdgcn_mfma_f32_16x16x32_bf16(va, pf, o0, 0, 0, 0);
      o1 = __builtin_amdgcn_mfma_f32_16x16x32_bf16(vb, pf, o1, 0, 0, 0);
    }
    float inv = 1.f / lsum;
    u16* op = ao + (base + qbase + l15) * D_DIM + h * HDIM;
    ushort4 w0, w1;
    w0.x = f2bf(o0[0] * inv); w0.y = f2bf(o0[1] * inv);
    w0.z = f2bf(o0[2] * inv); w0.w = f2bf(o0[3] * inv);
    w1.x = f2bf(o1[0] * inv); w1.y = f2bf(o1[1] * inv);
    w1.z = f2bf(o1[2] * inv); w1.w = f2bf(o1[3] * inv);
    *(ushort4*)(op + l4 * 4) = w0;
    *(ushort4*)(op + 16 + l4 * 4) = w1;
  }
}

// ---------------- global-token mean from xs (permutation-invariant) ----------------
__global__ __launch_bounds__(256) void gt_partial_kernel(const float* __restrict__ xs,
                                                         float* __restrict__ part) {
  const int s = blockIdx.x, c = blockIdx.y;
  const int t = threadIdx.x;
  float acc = 0.f;
  const size_t base = (size_t)c * LPC + (size_t)s * 256;
  for (int r = 0; r < 256; r++) acc += xs[(base + r) * D_DIM + t];
  part[(size_t)(c * 128 + s) * D_DIM + t] = acc;
}

__global__ __launch_bounds__(256) void gt_reduce_kernel(const float* __restrict__ part,
                                                        float* __restrict__ gt) {
  const int c = blockIdx.x, t = threadIdx.x;
  float s = 0.f;
  for (int i = 0; i < 128; i++) s += part[(size_t)(c * 128 + i) * D_DIM + t];
  gt[c * D_DIM + t] = s * (1.f / (float)LPC);
}

// ---------------- per-cloud gt @ bottom-half weights (fp32) ----------------
__global__ __launch_bounds__(256) void pervec_kernel(const float* __restrict__ gt,
                                                     const float* __restrict__ ggw1,
                                                     const float* __restrict__ fw1,
                                                     float* __restrict__ ggt,
                                                     float* __restrict__ fgt) {
  const int c = blockIdx.x, which = blockIdx.y;
  const int t = threadIdx.x;
  const float* W = which ? fw1 : ggw1;
  float* o = which ? fgt : ggt;
  __shared__ float g[D_DIM];
  g[t] = gt[c * D_DIM + t];
  __syncthreads();
  float acc = 0.f;
#pragma unroll 8
  for (int k = 0; k < D_DIM; k++) acc += g[k] * W[(size_t)(256 + k) * D_DIM + t];
  o[c * D_DIM + t] = acc;
}

extern "C" void kernel_launch(void* const* d_in, const int* in_sizes, int n_in,
                              void* d_out, int out_size, void* d_ws, size_t ws_size,
                              hipStream_t stream) {
  const float* feats = (const float*)d_in[0];
  const float* coord = (const float*)d_in[1];
  const float* pe_w1 = (const float*)d_in[3];
  const float* pe_b1 = (const float*)d_in[4];
  const float* pe_w2 = (const float*)d_in[5];
  const float* pe_b2 = (const float*)d_in[6];
  const float* pre_g = (const float*)d_in[7];
  const float* pre_b = (const float*)d_in[8];
  const float* n1_g = (const float*)d_in[9];
  const float* n1_b = (const float*)d_in[10];
  const float* wqkv = (const float*)d_in[11];
  const float* bqkv = (const float*)d_in[12];
  const float* wo = (const float*)d_in[13];
  const float* bo = (const float*)d_in[14];
  const float* n2_g = (const float*)d_in[15];
  const float* n2_b = (const float*)d_in[16];
  const float* m_w1 = (const float*)d_in[17];
  const float* m_b1 = (const float*)d_in[18];
  const float* m_w2 = (const float*)d_in[19];
  const float* m_b2 = (const float*)d_in[20];
  const float* gg_w1 = (const float*)d_in[21];
  const float* gg_b1 = (const float*)d_in[22];
  const float* gg_w2 = (const float*)d_in[23];
  const float* gg_b2 = (const float*)d_in[24];
  const float* f_w1 = (const float*)d_in[25];
  const float* f_b1 = (const float*)d_in[26];
  const float* f_w2 = (const float*)d_in[27];
  const float* f_b2 = (const float*)d_in[28];
  float* out = (float*)d_out;

  // ---------------- workspace layout (~306 MiB) ----------------
  char* ws = (char*)d_ws;
  float* xs = (float*)(ws);                         // [0,128MiB) fp32 residual stream
  u16* hbuf = (u16*)(ws + 134217728);               // [128,192MiB) bf16 (pe / LN out / g1)
  u16* qkvchunk = (u16*)(ws + 201326592);           // [192..240MiB) chunk qkv (48 MiB)
  u16* aochunk = (u16*)(ws + 251658240);            // [240..256MiB) chunk attn out (16 MiB)
  u16* tbuf = (u16*)(ws + 268435456);               // [256..288MiB) chunk MLP mid (32 MiB)
  u16* Hbuf = (u16*)(ws + 268435456);               // [N][64] bf16 (16 MiB, pre-attn only)
  u16* xobf = (u16*)(ws + 201326592);               // post-MLP: bf16 xo (64 MiB, reuses qkv region)
  size_t off = 301989888;
  u64* keybuf = (u64*)(ws + off); off += (size_t)NTOT * 8;
  int* orderbuf = (int*)(ws + off); off += (size_t)NTOT * 4;
  int* rankbuf = (int*)(ws + off); off += (size_t)NTOT * 4;
  float* statsbuf = (float*)(ws + off); off += 4096;
  float* gtpart = (float*)(ws + off); off += (size_t)NCLOUD * 128 * D_DIM * 4;
  float* gtbuf = (float*)(ws + off); off += 4096;
  float* ggtbuf = (float*)(ws + off); off += 4096;
  float* fgtbuf = (float*)(ws + off); off += 4096;
  u16* wqkvT = (u16*)(ws + off); off += 768 * 256 * 2;
  u16* woT = (u16*)(ws + off); off += 256 * 256 * 2;
  u16* mw1T = (u16*)(ws + off); off += 512 * 256 * 2;
  u16* mw2T = (u16*)(ws + off); off += 256 * 512 * 2;
  u16* ggw1T = (u16*)(ws + off); off += 256 * 256 * 2;
  u16* ggw2T = (u16*)(ws + off); off += 256 * 256 * 2;
  u16* fw1T = (u16*)(ws + off); off += 256 * 256 * 2;
  u16* fw2T = (u16*)(ws + off); off += 256 * 256 * 2;
  u16* pw2T = (u16*)(ws + off); off += 64 * 256 * 2;
  u16* featsbf = (u16*)(ws);                        // aliases dead xs region [0,64MiB)
  u16* u1buf = (u16*)(ws + 67108864);               // aliases dead xs region [64,128MiB)

  // 1. stats + keys + sort + order/rank
  stats_kernel<<<NCLOUD, 256, 0, stream>>>(coord, statsbuf);
  key_kernel<<<NTOT / 256, 256, 0, stream>>>(coord, statsbuf, keybuf);
  sort_local_kernel<<<NTOT / 4096, 1024, 0, stream>>>(keybuf);
  for (int k = 8192; k <= 32768; k <<= 1) {
    for (int j = k >> 1; j >= 4096; j >>= 1)
      sort_global_kernel<<<NTOT / 512, 256, 0, stream>>>(keybuf, k, j);
    sort_finish_kernel<<<NTOT / 4096, 1024, 0, stream>>>(keybuf, k);
  }
  rank_kernel<<<NTOT / 256, 256, 0, stream>>>(keybuf, orderbuf, rankbuf);
  // 2. weight convert+transpose (bf16)
  wtrans_kernel<<<dim3(24, 8), 256, 0, stream>>>(wqkv, wqkvT, 256, 768);
  wtrans_kernel<<<dim3(8, 8), 256, 0, stream>>>(wo, woT, 256, 256);
  wtrans_kernel<<<dim3(16, 8), 256, 0, stream>>>(m_w1, mw1T, 256, 512);
  wtrans_kernel<<<dim3(8, 16), 256, 0, stream>>>(m_w2, mw2T, 512, 256);
  wtrans_kernel<<<dim3(8, 8), 256, 0, stream>>>(gg_w1, ggw1T, 256, 256);  // top half
  wtrans_kernel<<<dim3(8, 8), 256, 0, stream>>>(gg_w2, ggw2T, 256, 256);
  wtrans_kernel<<<dim3(8, 8), 256, 0, stream>>>(f_w1, fw1T, 256, 256);    // top half
  wtrans_kernel<<<dim3(8, 8), 256, 0, stream>>>(f_w2, fw2T, 256, 256);
  wtrans_kernel<<<dim3(8, 2), 256, 0, stream>>>(pe_w2, pw2T, 64, 256);
  // 3. PE: H = relu(scs@pw1+b1); pe = H @ pw2 + b2 (MFMA, K=64) -> hbuf bf16
  h_kernel<<<NTOT * 64 / 256, 256, 0, stream>>>(coord, statsbuf, pe_w1, pe_b1, Hbuf);
  mfma_gemm<64, 0, 2, false><<<dim3(2, NTOT / 128), 256, 0, stream>>>(
      Hbuf, pw2T, pe_b2, nullptr, hbuf, 256);
  // 4. xs[rank] = LN(feats + pe)
  add_ln_kernel<<<NTOT / 4, 256, 0, stream>>>(feats, hbuf, rankbuf, pre_g, pre_b, xs);
  // 5. attention block (chunked): xs += attn(LN1(xs)) @ wo + bo
  ln_bf16_kernel<<<NTOT / 4, 256, 0, stream>>>(xs, n1_g, n1_b, hbuf);
  for (int ch = 0; ch < NCHUNK; ch++) {
    const size_t ro = (size_t)ch * CROWS;
    mfma_gemm<256, 0, 2, false><<<dim3(6, CROWS / 128), 256, 0, stream>>>(
        hbuf + ro * 256, wqkvT, bqkv, nullptr, qkvchunk, 768);
    attn_mfma_kernel<<<dim3(CROWS / PATCH, NHEAD), 256, 0, stream>>>(qkvchunk, aochunk);
    mfma_gemm<256, 0, 1, false><<<dim3(2, CROWS / 128), 256, 0, stream>>>(
        aochunk, woT, bo, nullptr, xs + ro * 256, 256);
  }
  // 6. MLP block (chunked): xs += gelu(LN2(xs)@m_w1+b)@m_w2+b
  ln_bf16_kernel<<<NTOT / 4, 256, 0, stream>>>(xs, n2_g, n2_b, hbuf);
  for (int ch = 0; ch < NCHUNK; ch++) {
    const size_t ro = (size_t)ch * CROWS;
    mfma_gemm<256, 2, 2, false><<<dim3(MLPD / 128, CROWS / 128), 256, 0, stream>>>(
        hbuf + ro * 256, mw1T, m_b1, nullptr, tbuf, 512);
    mfma_gemm<512, 0, 1, false><<<dim3(2, CROWS / 128), 256, 0, stream>>>(
        tbuf, mw2T, m_b2, nullptr, xs + ro * 256, 256);
  }
  // 7. un-serialize to bf16 + global token from xs (mean is permutation-invariant)
  scatter_bf16_kernel<<<NTOT / 4, 256, 0, stream>>>(orderbuf, xs, xobf);
  gt_partial_kernel<<<dim3(128, NCLOUD), 256, 0, stream>>>(xs, gtpart);
  gt_reduce_kernel<<<NCLOUD, 256, 0, stream>>>(gtpart, gtbuf);
  pervec_kernel<<<dim3(NCLOUD, 2), 256, 0, stream>>>(gtbuf, gg_w1, f_w1, ggtbuf, fgtbuf);
  // 8. xs region dead: stage-1 GEMMs -> g1 (hbuf) and u1 (u1buf)
  conv_bf16_kernel<<<NTOT * 256 / 1024, 256, 0, stream>>>(feats, featsbf);
  mfma_gemm<256, 1, 2, true><<<dim3(2, NTOT / 128), 256, 0, stream>>>(
      featsbf, ggw1T, gg_b1, ggtbuf, hbuf, 256);
  mfma_gemm<256, 1, 2, true><<<dim3(2, NTOT / 128), 256, 0, stream>>>(
      xobf, fw1T, f_b1, fgtbuf, u1buf, 256);
  // 9. fused tail: out = feats + sigmoid(g1@ggw2+b) * (u1@fw2+b)
  fuse2_kernel<<<dim3(2, NTOT / 128), 256, 0, stream>>>(
      hbuf, u1buf, ggw2T, fw2T, gg_b2, f_b2, feats, out);
  (void)in_sizes; (void)n_in; (void)out_size; (void)ws_size;
}

// Round 8
// 1397.847 us; speedup vs baseline: 3.5247x; 1.0170x over previous
//
#include <hip/hip_runtime.h>
#include <hip/hip_bf16.h>
#include <math.h>

#define D_DIM 256
#define NHEAD 8
#define HDIM 32
#define PATCH 256
#define NCLOUD 4
#define LPC 32768
#define NTOT (NCLOUD * LPC)
#define MLPD 512
#define PEHID 64
#define LN_EPS 1e-5f
#define NCHUNK 4
#define CROWS (NTOT / NCHUNK)   // 32768 rows per chunk

typedef unsigned long long u64;
typedef unsigned short u16;
typedef short bf16x8 __attribute__((ext_vector_type(8)));  // 8 bf16 (4 VGPRs)
typedef float f32x4 __attribute__((ext_vector_type(4)));

__device__ __forceinline__ u16 f2bf(float x) {
  unsigned u = __float_as_uint(x);
  u += 0x7fffu + ((u >> 16) & 1u);
  return (u16)(u >> 16);
}
__device__ __forceinline__ float bf2f(u16 u) {
  return __uint_as_float(((unsigned)u) << 16);
}

// async global->LDS DMA, 16B per lane; lds ptr must be wave-uniform base (+lane*16 implicit)
__device__ __forceinline__ void gload_lds16(const u16* g, u16* l) {
  __builtin_amdgcn_global_load_lds((const __attribute__((address_space(1))) void*)g,
                                   (__attribute__((address_space(3))) void*)l, 16, 0, 0);
}

// ---------------- per-cloud coordinate stats ----------------
__global__ __launch_bounds__(256) void stats_kernel(const float* __restrict__ coord,
                                                    float* __restrict__ stats) {
  const int c = blockIdx.x, t = threadIdx.x;
  float sm[3] = {0.f, 0.f, 0.f};
  float mn[3] = {1e30f, 1e30f, 1e30f};
  float mx[3] = {-1e30f, -1e30f, -1e30f};
  const float* cp = coord + (size_t)c * LPC * 3;
  for (int i = t; i < LPC; i += 256) {
#pragma unroll
    for (int a = 0; a < 3; a++) {
      float v = cp[(size_t)i * 3 + a];
      sm[a] += v;
      mn[a] = fminf(mn[a], v);
      mx[a] = fmaxf(mx[a], v);
    }
  }
  __shared__ float sb[256];
  float rsum[3], rmn[3], rmx[3];
#pragma unroll
  for (int a = 0; a < 3; a++) {
    sb[t] = sm[a]; __syncthreads();
    for (int s = 128; s > 0; s >>= 1) { if (t < s) sb[t] += sb[t + s]; __syncthreads(); }
    rsum[a] = sb[0]; __syncthreads();
    sb[t] = mn[a]; __syncthreads();
    for (int s = 128; s > 0; s >>= 1) { if (t < s) sb[t] = fminf(sb[t], sb[t + s]); __syncthreads(); }
    rmn[a] = sb[0]; __syncthreads();
    sb[t] = mx[a]; __syncthreads();
    for (int s = 128; s > 0; s >>= 1) { if (t < s) sb[t] = fmaxf(sb[t], sb[t + s]); __syncthreads(); }
    rmx[a] = sb[0]; __syncthreads();
  }
  if (t == 0) {
    float* st = stats + c * 16;
#pragma unroll
    for (int a = 0; a < 3; a++) {
      float mean = rsum[a] / (float)LPC;
      st[a] = mean;
      st[3 + a] = fmaxf(fmaxf(rmx[a] - mean, mean - rmn[a]), 1e-6f);
      st[6 + a] = rmn[a];
      st[9 + a] = fmaxf(rmx[a] - rmn[a], 1e-6f);
    }
  }
}

// ---------------- serialization keys (bit-exact vs numpy; stable tie-break) ----------------
__global__ __launch_bounds__(256) void key_kernel(const float* __restrict__ coord,
                                                  const float* __restrict__ stats,
                                                  u64* __restrict__ keys) {
#pragma clang fp contract(off)
  const int g = blockIdx.x * 256 + threadIdx.x;
  const int c = g >> 15;
  const float* st = stats + c * 16;
  float k0 = (coord[(size_t)g * 3 + 0] - st[6]) / st[9];
  float k1 = (coord[(size_t)g * 3 + 1] - st[7]) / st[10];
  float k2 = (coord[(size_t)g * 3 + 2] - st[8]) / st[11];
  float key = k0 + 2.17f * k1;
  key = key + 3.31f * k2;
  keys[g] = ((u64)__float_as_uint(key) << 32) | (unsigned)(g & (LPC - 1));
}

// ---------------- bitonic sort (per-cloud, u64 packed key|idx), 1024 threads ----------------
__global__ __launch_bounds__(1024) void sort_local_kernel(u64* __restrict__ keys) {
  __shared__ u64 s[4096];
  const int base = blockIdx.x * 4096;
  const int t = threadIdx.x;
  for (int i = t; i < 4096; i += 1024) s[i] = keys[base + i];
  __syncthreads();
  for (int k = 2; k <= 4096; k <<= 1) {
    for (int j = k >> 1; j > 0; j >>= 1) {
      for (int p = t; p < 2048; p += 1024) {
        int i = ((p & ~(j - 1)) << 1) | (p & (j - 1));
        int l = i | j;
        bool asc = (((base + i) & (LPC - 1)) & k) == 0;
        u64 a = s[i], bb = s[l];
        if (asc ? (a > bb) : (a < bb)) { s[i] = bb; s[l] = a; }
      }
      __syncthreads();
    }
  }
  for (int i = t; i < 4096; i += 1024) keys[base + i] = s[i];
}

__global__ __launch_bounds__(256) void sort_global_kernel(u64* __restrict__ keys, int k, int j) {
  int p = blockIdx.x * 256 + threadIdx.x;
  int i = ((p & ~(j - 1)) << 1) | (p & (j - 1));
  int l = i | j;
  bool asc = ((i & (LPC - 1)) & k) == 0;
  u64 a = keys[i], b = keys[l];
  if (asc ? (a > b) : (a < b)) { keys[i] = b; keys[l] = a; }
}

__global__ __launch_bounds__(1024) void sort_finish_kernel(u64* __restrict__ keys, int k) {
  __shared__ u64 s[4096];
  const int base = blockIdx.x * 4096;
  const int t = threadIdx.x;
  for (int i = t; i < 4096; i += 1024) s[i] = keys[base + i];
  __syncthreads();
  for (int j = 2048; j > 0; j >>= 1) {
    for (int p = t; p < 2048; p += 1024) {
      int i = ((p & ~(j - 1)) << 1) | (p & (j - 1));
      int l = i | j;
      bool asc = (((base + i) & (LPC - 1)) & k) == 0;
      u64 a = s[i], bb = s[l];
      if (asc ? (a > bb) : (a < bb)) { s[i] = bb; s[l] = a; }
    }
    __syncthreads();
  }
  for (int i = t; i < 4096; i += 1024) keys[base + i] = s[i];
}

// ---------------- order + rank from sorted keys ----------------
__global__ __launch_bounds__(256) void rank_kernel(const u64* __restrict__ keys,
                                                   int* __restrict__ order,
                                                   int* __restrict__ rank) {
  const int g = blockIdx.x * 256 + threadIdx.x;
  const int src = (int)(unsigned)(keys[g] & 0xffffffffULL) + (g & ~(LPC - 1));
  order[g] = src;
  rank[src] = g;
}

// ---------------- weight transpose + fp32->bf16: dst[C][R] = src[R][C] ----------------
__global__ __launch_bounds__(256) void wtrans_kernel(const float* __restrict__ src,
                                                     u16* __restrict__ dst, int R, int C) {
  __shared__ float t[32][33];
  const int bx = blockIdx.x * 32, by = blockIdx.y * 32;
  const int lc = threadIdx.x & 31, lr = threadIdx.x >> 5;  // 8 rows per pass
  for (int i = 0; i < 32; i += 8) t[lr + i][lc] = src[(size_t)(by + lr + i) * C + bx + lc];
  __syncthreads();
  for (int i = 0; i < 32; i += 8)
    dst[(size_t)(bx + lr + i) * R + by + lc] = f2bf(t[lc][lr + i]);
}

// ---------------- fp32 -> bf16 elementwise ----------------
__global__ __launch_bounds__(256) void conv_bf16_kernel(const float* __restrict__ in,
                                                        u16* __restrict__ out) {
  size_t i = ((size_t)blockIdx.x * 256 + threadIdx.x) * 4;
  float4 v = *(const float4*)(in + i);
  ushort4 o;
  o.x = f2bf(v.x); o.y = f2bf(v.y); o.z = f2bf(v.z); o.w = f2bf(v.w);
  *(ushort4*)(out + i) = o;
}

// ---------------- H = relu(scs @ pw1 + pb1), bf16 [N][64] ----------------
__global__ __launch_bounds__(256) void h_kernel(const float* __restrict__ coord,
                                                const float* __restrict__ stats,
                                                const float* __restrict__ pw1,
                                                const float* __restrict__ pb1,
                                                u16* __restrict__ H) {
  const int idx = blockIdx.x * 256 + threadIdx.x;
  const int row = idx >> 6, j = idx & 63;
  const int c = row >> 15;
  const float* st = stats + c * 16;
  float s0 = (coord[(size_t)row * 3 + 0] - st[0]) / st[3];
  float s1 = (coord[(size_t)row * 3 + 1] - st[1]) / st[4];
  float s2 = (coord[(size_t)row * 3 + 2] - st[2]) / st[5];
  float h = pb1[j] + s0 * pw1[j] + s1 * pw1[64 + j] + s2 * pw1[128 + j];
  H[idx] = f2bf(fmaxf(h, 0.f));
}

// ---------------- wave-per-row: xs[rank[row]] = LN(feats + pe) (fp32) ----------------
__global__ __launch_bounds__(256) void add_ln_kernel(const float* __restrict__ feats,
                                                     const u16* __restrict__ pe,
                                                     const int* __restrict__ rank,
                                                     const float* __restrict__ g,
                                                     const float* __restrict__ b,
                                                     float* __restrict__ xs) {
  const int row = blockIdx.x * 4 + (threadIdx.x >> 6);
  const int lane = threadIdx.x & 63;
  float4 f = *(const float4*)(feats + (size_t)row * 256 + lane * 4);
  ushort4 p = *(const ushort4*)(pe + (size_t)row * 256 + lane * 4);
  float v0 = f.x + bf2f(p.x), v1 = f.y + bf2f(p.y);
  float v2 = f.z + bf2f(p.z), v3 = f.w + bf2f(p.w);
  float s = v0 + v1 + v2 + v3;
#pragma unroll
  for (int o = 32; o > 0; o >>= 1) s += __shfl_xor(s, o);
  float mean = s * (1.f / 256.f);
  float d0 = v0 - mean, d1 = v1 - mean, d2 = v2 - mean, d3 = v3 - mean;
  float ss = d0 * d0 + d1 * d1 + d2 * d2 + d3 * d3;
#pragma unroll
  for (int o = 32; o > 0; o >>= 1) ss += __shfl_xor(ss, o);
  float inv = 1.f / sqrtf(ss * (1.f / 256.f) + LN_EPS);
  float4 gv = *(const float4*)(g + lane * 4);
  float4 bv = *(const float4*)(b + lane * 4);
  int dst = rank[row];
  float4 o4;
  o4.x = d0 * inv * gv.x + bv.x; o4.y = d1 * inv * gv.y + bv.y;
  o4.z = d2 * inv * gv.z + bv.z; o4.w = d3 * inv * gv.w + bv.w;
  *(float4*)(xs + (size_t)dst * 256 + lane * 4) = o4;
}

// ---------------- wave-per-row LN: fp32 in -> bf16 out ----------------
__global__ __launch_bounds__(256) void ln_bf16_kernel(const float* __restrict__ in,
                                                      const float* __restrict__ g,
                                                      const float* __restrict__ b,
                                                      u16* __restrict__ out) {
  const int row = blockIdx.x * 4 + (threadIdx.x >> 6);
  const int lane = threadIdx.x & 63;
  float4 v = *(const float4*)(in + (size_t)row * 256 + lane * 4);
  float s = v.x + v.y + v.z + v.w;
#pragma unroll
  for (int o = 32; o > 0; o >>= 1) s += __shfl_xor(s, o);
  float mean = s * (1.f / 256.f);
  float d0 = v.x - mean, d1 = v.y - mean, d2 = v.z - mean, d3 = v.w - mean;
  float ss = d0 * d0 + d1 * d1 + d2 * d2 + d3 * d3;
#pragma unroll
  for (int o = 32; o > 0; o >>= 1) ss += __shfl_xor(ss, o);
  float inv = 1.f / sqrtf(ss * (1.f / 256.f) + LN_EPS);
  float4 gv = *(const float4*)(g + lane * 4);
  float4 bv = *(const float4*)(b + lane * 4);
  ushort4 o4;
  o4.x = f2bf(d0 * inv * gv.x + bv.x); o4.y = f2bf(d1 * inv * gv.y + bv.y);
  o4.z = f2bf(d2 * inv * gv.z + bv.z); o4.w = f2bf(d3 * inv * gv.w + bv.w);
  *(ushort4*)(out + (size_t)row * 256 + lane * 4) = o4;
}

// ---------------- MFMA GEMM (m97 structure): C[M x Ko] = act(A@Wt^T + bias) ----------------
// MODE: 0 fp32 store, 1 fp32 resid +=, 2 bf16 store
template <int K, int ACT, int MODE, bool EXTRA>
__global__ __launch_bounds__(256, 4) void mfma_gemm(const u16* __restrict__ A,
                                                    const u16* __restrict__ Wt,
                                                    const float* __restrict__ bias,
                                                    const float* __restrict__ extra,
                                                    void* __restrict__ Cout, int Ko) {
  __shared__ __align__(16) u16 Al[128 * 32];
  __shared__ __align__(16) u16 Bl[128 * 32];
  const int tid = threadIdx.x;
  const int lane = tid & 63, wave = tid >> 6;
  const int wr = wave >> 1, wc = wave & 1;
  const int l15 = lane & 15, l4 = lane >> 4;
  const size_t row0 = (size_t)blockIdx.y * 128;
  const int col0 = blockIdx.x * 128;
  const int q0 = wave * 64 + lane;
  const int q1 = q0 + 256;
  const u16* gA0 = A + (row0 + (q0 >> 2)) * K + (q0 & 3) * 8;
  const u16* gA1 = A + (row0 + (q1 >> 2)) * K + (q1 & 3) * 8;
  const u16* gB0 = Wt + (size_t)(col0 + (q0 >> 2)) * K + (q0 & 3) * 8;
  const u16* gB1 = Wt + (size_t)(col0 + (q1 >> 2)) * K + (q1 & 3) * 8;
  u16* lA0 = Al + wave * 512;
  u16* lA1 = Al + 2048 + wave * 512;
  u16* lB0 = Bl + wave * 512;
  u16* lB1 = Bl + 2048 + wave * 512;
  f32x4 acc[4][4];
#pragma unroll
  for (int i = 0; i < 4; i++)
#pragma unroll
    for (int j = 0; j < 4; j++) acc[i][j] = f32x4{0.f, 0.f, 0.f, 0.f};
#pragma unroll 1
  for (int k0 = 0; k0 < K; k0 += 32) {
    gload_lds16(gA0 + k0, lA0);
    gload_lds16(gA1 + k0, lA1);
    gload_lds16(gB0 + k0, lB0);
    gload_lds16(gB1 + k0, lB1);
    __syncthreads();
    bf16x8 af[4], bfr[4];
#pragma unroll
    for (int rb = 0; rb < 4; rb++)
      af[rb] = *(const bf16x8*)&Al[(wr * 64 + rb * 16 + l15) * 32 + l4 * 8];
#pragma unroll
    for (int cb = 0; cb < 4; cb++)
      bfr[cb] = *(const bf16x8*)&Bl[(wc * 64 + cb * 16 + l15) * 32 + l4 * 8];
#pragma unroll
    for (int rb = 0; rb < 4; rb++)
#pragma unroll
      for (int cb = 0; cb < 4; cb++)
        acc[rb][cb] = __builtin_amdgcn_mfma_f32_16x16x32_bf16(af[rb], bfr[cb], acc[rb][cb], 0, 0, 0);
    __syncthreads();
  }
#pragma unroll
  for (int rb = 0; rb < 4; rb++)
#pragma unroll
    for (int cb = 0; cb < 4; cb++)
#pragma unroll
      for (int r = 0; r < 4; r++) {
        size_t row = row0 + wr * 64 + rb * 16 + l4 * 4 + r;
        int col = col0 + wc * 64 + cb * 16 + l15;
        float v = acc[rb][cb][r] + bias[col];
        if (EXTRA) v += extra[((int)(row >> 15)) * 256 + col];
        if (ACT == 1) v = fmaxf(v, 0.f);
        else if (ACT == 2) v = 0.5f * v * (1.f + erff(v * 0.70710678118654752440f));
        else if (ACT == 3) v = 1.f / (1.f + __expf(-v));
        size_t o = row * (size_t)Ko + col;
        if (MODE == 0) ((float*)Cout)[o] = v;
        else if (MODE == 1) ((float*)Cout)[o] += v;
        else ((u16*)Cout)[o] = f2bf(v);
      }
}

// ---------------- full-row MFMA GEMM: 64 rows x 256 cols per block, resid += on xs -------
// EPI 1: row-LN -> hout bf16 (g/b params). EPI 2: scatter t -> hout[order[row]*256+col].
template <int K, int EPI>
__global__ __launch_bounds__(256, 3) void mfma_row_gemm(const u16* __restrict__ A,
                                                        const u16* __restrict__ Wt,
                                                        const float* __restrict__ bias,
                                                        float* __restrict__ xs,
                                                        u16* __restrict__ hout,
                                                        const int* __restrict__ order,
                                                        const float* __restrict__ g,
                                                        const float* __restrict__ b) {
  __shared__ __align__(16) u16 Al[64 * 32];
  __shared__ __align__(16) u16 Bl[256 * 32];
  __shared__ float reds[2][4][64];
  const int tid = threadIdx.x;
  const int lane = tid & 63, wave = tid >> 6;
  const int l15 = lane & 15, l4 = lane >> 4;
  const size_t row0 = (size_t)blockIdx.x * 64;
  const u16* gA = A + (row0 + (tid >> 2)) * K + (tid & 3) * 8;
  u16* lA = Al + wave * 512;
  const u16* gB[4];
  u16* lB[4];
#pragma unroll
  for (int s = 0; s < 4; s++) {
    int q = s * 256 + tid;
    gB[s] = Wt + (size_t)(q >> 2) * K + (q & 3) * 8;
    lB[s] = Bl + s * 2048 + wave * 512;
  }
  f32x4 acc[4][4];
#pragma unroll
  for (int i = 0; i < 4; i++)
#pragma unroll
    for (int j = 0; j < 4; j++) acc[i][j] = f32x4{0.f, 0.f, 0.f, 0.f};
#pragma unroll 1
  for (int k0 = 0; k0 < K; k0 += 32) {
    gload_lds16(gA + k0, lA);
#pragma unroll
    for (int s = 0; s < 4; s++) gload_lds16(gB[s] + k0, lB[s]);
    __syncthreads();
    bf16x8 af[4], bfr[4];
#pragma unroll
    for (int rb = 0; rb < 4; rb++)
      af[rb] = *(const bf16x8*)&Al[(rb * 16 + l15) * 32 + l4 * 8];
#pragma unroll
    for (int cb = 0; cb < 4; cb++)
      bfr[cb] = *(const bf16x8*)&Bl[(wave * 64 + cb * 16 + l15) * 32 + l4 * 8];
#pragma unroll
    for (int rb = 0; rb < 4; rb++)
#pragma unroll
      for (int cb = 0; cb < 4; cb++)
        acc[rb][cb] = __builtin_amdgcn_mfma_f32_16x16x32_bf16(af[rb], bfr[cb], acc[rb][cb], 0, 0, 0);
    __syncthreads();
  }
  // epilogue: t = xs + v + bias; xs = t (keep t in acc)
#pragma unroll
  for (int rb = 0; rb < 4; rb++)
#pragma unroll
    for (int cb = 0; cb < 4; cb++)
#pragma unroll
      for (int r = 0; r < 4; r++) {
        size_t row = row0 + rb * 16 + l4 * 4 + r;
        int col = wave * 64 + cb * 16 + l15;
        size_t o = row * 256 + col;
        float t = xs[o] + acc[rb][cb][r] + bias[col];
        xs[o] = t;
        acc[rb][cb][r] = t;
      }
  if (EPI == 1) {
    float ps[4][4];
#pragma unroll
    for (int rb = 0; rb < 4; rb++)
#pragma unroll
      for (int r = 0; r < 4; r++) {
        float v = acc[rb][0][r] + acc[rb][1][r] + acc[rb][2][r] + acc[rb][3][r];
#pragma unroll
        for (int oo = 1; oo < 16; oo <<= 1) v += __shfl_xor(v, oo);
        ps[rb][r] = v;
      }
    if (l15 == 0)
#pragma unroll
      for (int rb = 0; rb < 4; rb++)
#pragma unroll
        for (int r = 0; r < 4; r++) reds[0][wave][rb * 16 + l4 * 4 + r] = ps[rb][r];
    __syncthreads();
    float mean[4][4];
#pragma unroll
    for (int rb = 0; rb < 4; rb++)
#pragma unroll
      for (int r = 0; r < 4; r++) {
        int ri = rb * 16 + l4 * 4 + r;
        mean[rb][r] = (reds[0][0][ri] + reds[0][1][ri] + reds[0][2][ri] + reds[0][3][ri]) *
                      (1.f / 256.f);
      }
#pragma unroll
    for (int rb = 0; rb < 4; rb++)
#pragma unroll
      for (int r = 0; r < 4; r++) {
        float d0 = acc[rb][0][r] - mean[rb][r], d1 = acc[rb][1][r] - mean[rb][r];
        float d2 = acc[rb][2][r] - mean[rb][r], d3 = acc[rb][3][r] - mean[rb][r];
        float v = d0 * d0 + d1 * d1 + d2 * d2 + d3 * d3;
#pragma unroll
        for (int oo = 1; oo < 16; oo <<= 1) v += __shfl_xor(v, oo);
        ps[rb][r] = v;
      }
    if (l15 == 0)
#pragma unroll
      for (int rb = 0; rb < 4; rb++)
#pragma unroll
        for (int r = 0; r < 4; r++) reds[1][wave][rb * 16 + l4 * 4 + r] = ps[rb][r];
    __syncthreads();
#pragma unroll
    for (int rb = 0; rb < 4; rb++)
#pragma unroll
      for (int r = 0; r < 4; r++) {
        int ri = rb * 16 + l4 * 4 + r;
        float var = (reds[1][0][ri] + reds[1][1][ri] + reds[1][2][ri] + reds[1][3][ri]) *
                    (1.f / 256.f);
        float inv = 1.f / sqrtf(var + LN_EPS);
        size_t row = row0 + ri;
#pragma unroll
        for (int cb = 0; cb < 4; cb++) {
          int col = wave * 64 + cb * 16 + l15;
          hout[row * 256 + col] =
              f2bf((acc[rb][cb][r] - mean[rb][r]) * inv * g[col] + b[col]);
        }
      }
  } else {
#pragma unroll
    for (int rb = 0; rb < 4; rb++)
#pragma unroll
      for (int r = 0; r < 4; r++) {
        size_t row = row0 + rb * 16 + l4 * 4 + r;
        size_t dst = (size_t)order[row];
#pragma unroll
        for (int cb = 0; cb < 4; cb++) {
          int col = wave * 64 + cb * 16 + l15;
          hout[dst * 256 + col] = f2bf(acc[rb][cb][r]);
        }
      }
  }
}

// ---------------- fused tail: out = feats + sigmoid(A1@B1+b1) * (A2@B2+b2), 128x64 tiles --
__global__ __launch_bounds__(256, 3) void fuse2_kernel(const u16* __restrict__ A1,
                                                       const u16* __restrict__ A2,
                                                       const u16* __restrict__ B1t,
                                                       const u16* __restrict__ B2t,
                                                       const float* __restrict__ bias1,
                                                       const float* __restrict__ bias2,
                                                       const float* __restrict__ feats,
                                                       float* __restrict__ out) {
  __shared__ __align__(16) u16 A1l[128 * 32];
  __shared__ __align__(16) u16 A2l[128 * 32];
  __shared__ __align__(16) u16 B1l[64 * 32];
  __shared__ __align__(16) u16 B2l[64 * 32];
  const int tid = threadIdx.x;
  const int lane = tid & 63, wave = tid >> 6;
  const int l15 = lane & 15, l4 = lane >> 4;
  const size_t row0 = (size_t)blockIdx.y * 128;
  const int col0 = blockIdx.x * 64;
  const int q0 = tid, q1 = tid + 256;
  const size_t a0off = (row0 + (q0 >> 2)) * 256 + (q0 & 3) * 8;
  const size_t a1off = (row0 + (q1 >> 2)) * 256 + (q1 & 3) * 8;
  const size_t boff = (size_t)(col0 + (q0 >> 2)) * 256 + (q0 & 3) * 8;
  f32x4 acc1[2][4], acc2[2][4];
#pragma unroll
  for (int i = 0; i < 2; i++)
#pragma unroll
    for (int j = 0; j < 4; j++) {
      acc1[i][j] = f32x4{0.f, 0.f, 0.f, 0.f};
      acc2[i][j] = f32x4{0.f, 0.f, 0.f, 0.f};
    }
#pragma unroll 1
  for (int k0 = 0; k0 < 256; k0 += 32) {
    gload_lds16(A1 + a0off + k0, A1l + wave * 512);
    gload_lds16(A1 + a1off + k0, A1l + 2048 + wave * 512);
    gload_lds16(A2 + a0off + k0, A2l + wave * 512);
    gload_lds16(A2 + a1off + k0, A2l + 2048 + wave * 512);
    gload_lds16(B1t + boff + k0, B1l + wave * 512);
    gload_lds16(B2t + boff + k0, B2l + wave * 512);
    __syncthreads();
#pragma unroll
    for (int rb = 0; rb < 2; rb++) {
      bf16x8 a1f = *(const bf16x8*)&A1l[(wave * 32 + rb * 16 + l15) * 32 + l4 * 8];
      bf16x8 a2f = *(const bf16x8*)&A2l[(wave * 32 + rb * 16 + l15) * 32 + l4 * 8];
#pragma unroll
      for (int cb = 0; cb < 4; cb++) {
        bf16x8 b1f = *(const bf16x8*)&B1l[(cb * 16 + l15) * 32 + l4 * 8];
        bf16x8 b2f = *(const bf16x8*)&B2l[(cb * 16 + l15) * 32 + l4 * 8];
        acc1[rb][cb] = __builtin_amdgcn_mfma_f32_16x16x32_bf16(a1f, b1f, acc1[rb][cb], 0, 0, 0);
        acc2[rb][cb] = __builtin_amdgcn_mfma_f32_16x16x32_bf16(a2f, b2f, acc2[rb][cb], 0, 0, 0);
      }
    }
    __syncthreads();
  }
#pragma unroll
  for (int rb = 0; rb < 2; rb++)
#pragma unroll
    for (int cb = 0; cb < 4; cb++)
#pragma unroll
      for (int r = 0; r < 4; r++) {
        size_t row = row0 + wave * 32 + rb * 16 + l4 * 4 + r;
        int col = col0 + cb * 16 + l15;
        float gg = 1.f / (1.f + __expf(-(acc1[rb][cb][r] + bias1[col])));
        float fv = acc2[rb][cb][r] + bias2[col];
        size_t o = row * 256 + col;
        out[o] = feats[o] + gg * fv;
      }
}

// ---------------- MFMA attention: one (window, head) per block, 4 waves x 64 queries ----
__global__ __launch_bounds__(256, 3) void attn_mfma_kernel(const u16* __restrict__ qkv,
                                                           u16* __restrict__ ao) {
  __shared__ __align__(16) u16 VT[32 * 264];       // V^T [d][k], padded stride 264
  __shared__ __align__(16) u16 Pl[4][16 * 264];    // per-wave P [q][k]
  const int w = blockIdx.x, h = blockIdx.y;
  const int tid = threadIdx.x;
  const int lane = tid & 63, wave = tid >> 6;
  const int l15 = lane & 15, l4 = lane >> 4;
  const size_t base = (size_t)w * PATCH;
  {
    const u16* vrow = qkv + (base + tid) * 768 + 512 + h * HDIM;
#pragma unroll
    for (int d4 = 0; d4 < 8; d4++) {
      ushort4 v4 = *(const ushort4*)(vrow + d4 * 4);
      VT[(d4 * 4 + 0) * 264 + tid] = v4.x;
      VT[(d4 * 4 + 1) * 264 + tid] = v4.y;
      VT[(d4 * 4 + 2) * 264 + tid] = v4.z;
      VT[(d4 * 4 + 3) * 264 + tid] = v4.w;
    }
  }
  __syncthreads();
  u16* Pw = &Pl[wave][0];
  const float scale = 0.17677669529663687f;  // 1/sqrt(32)
  const f32x4 zero = {0.f, 0.f, 0.f, 0.f};
  for (int qt = 0; qt < 4; qt++) {
    const int qbase = wave * 64 + qt * 16;
    bf16x8 qf = *(const bf16x8*)(qkv + (base + qbase + l15) * 768 + h * HDIM + l4 * 8);
    f32x4 s[16];
#pragma unroll
    for (int kt = 0; kt < 16; kt++) {
      bf16x8 kf = *(const bf16x8*)(qkv + (base + kt * 16 + l15) * 768 + 256 + h * HDIM + l4 * 8);
      s[kt] = __builtin_amdgcn_mfma_f32_16x16x32_bf16(kf, qf, zero, 0, 0, 0);
    }
    float m = -1e30f;
#pragma unroll
    for (int kt = 0; kt < 16; kt++)
#pragma unroll
      for (int r = 0; r < 4; r++) { s[kt][r] *= scale; m = fmaxf(m, s[kt][r]); }
    m = fmaxf(m, __shfl_xor(m, 16));
    m = fmaxf(m, __shfl_xor(m, 32));
    float lsum = 0.f;
#pragma unroll
    for (int kt = 0; kt < 16; kt++) {
      float p0 = __expf(s[kt][0] - m), p1 = __expf(s[kt][1] - m);
      float p2 = __expf(s[kt][2] - m), p3 = __expf(s[kt][3] - m);
      lsum += (p0 + p1) + (p2 + p3);
      ushort4 pw4;
      pw4.x = f2bf(p0); pw4.y = f2bf(p1); pw4.z = f2bf(p2); pw4.w = f2bf(p3);
      *(ushort4*)&Pw[l15 * 264 + kt * 16 + l4 * 4] = pw4;
    }
    lsum += __shfl_xor(lsum, 16);
    lsum += __shfl_xor(lsum, 32);
    f32x4 o0 = zero, o1 = zero;
#pragma unroll
    for (int kc = 0; kc < 8; kc++) {
      bf16x8 pf = *(const bf16x8*)&Pw[l15 * 264 + kc * 32 + l4 * 8];
      bf16x8 va = *(const bf16x8*)&VT[l15 * 264 + kc * 32 + l4 * 8];
      bf16x8 vb = *(const bf16x8*)&VT[(16 + l15) * 264 + kc * 32 + l4 * 8];
      o0 = __builtin_amdgcn_mfma_f32_16x16x32_bf16(va, pf, o0, 0, 0, 0);
      o1 = __builtin_amdgcn_mfma_f32_16x16x32_bf16(vb, pf, o1, 0, 0, 0);
    }
    float inv = 1.f / lsum;
    u16* op = ao + (base + qbase + l15) * D_DIM + h * HDIM;
    ushort4 w0, w1;
    w0.x = f2bf(o0[0] * inv); w0.y = f2bf(o0[1] * inv);
    w0.z = f2bf(o0[2] * inv); w0.w = f2bf(o0[3] * inv);
    w1.x = f2bf(o1[0] * inv); w1.y = f2bf(o1[1] * inv);
    w1.z = f2bf(o1[2] * inv); w1.w = f2bf(o1[3] * inv);
    *(ushort4*)(op + l4 * 4) = w0;
    *(ushort4*)(op + 16 + l4 * 4) = w1;
  }
}

// ---------------- global-token mean from xs (permutation-invariant) ----------------
__global__ __launch_bounds__(256) void gt_partial_kernel(const float* __restrict__ xs,
                                                         float* __restrict__ part) {
  const int s = blockIdx.x, c = blockIdx.y;
  const int t = threadIdx.x;
  float acc = 0.f;
  const size_t base = (size_t)c * LPC + (size_t)s * 256;
  for (int r = 0; r < 256; r++) acc += xs[(base + r) * D_DIM + t];
  part[(size_t)(c * 128 + s) * D_DIM + t] = acc;
}

__global__ __launch_bounds__(256) void gt_reduce_kernel(const float* __restrict__ part,
                                                        float* __restrict__ gt) {
  const int c = blockIdx.x, t = threadIdx.x;
  float s = 0.f;
  for (int i = 0; i < 128; i++) s += part[(size_t)(c * 128 + i) * D_DIM + t];
  gt[c * D_DIM + t] = s * (1.f / (float)LPC);
}

// ---------------- per-cloud gt @ bottom-half weights (fp32) ----------------
__global__ __launch_bounds__(256) void pervec_kernel(const float* __restrict__ gt,
                                                     const float* __restrict__ ggw1,
                                                     const float* __restrict__ fw1,
                                                     float* __restrict__ ggt,
                                                     float* __restrict__ fgt) {
  const int c = blockIdx.x, which = blockIdx.y;
  const int t = threadIdx.x;
  const float* W = which ? fw1 : ggw1;
  float* o = which ? fgt : ggt;
  __shared__ float g[D_DIM];
  g[t] = gt[c * D_DIM + t];
  __syncthreads();
  float acc = 0.f;
#pragma unroll 8
  for (int k = 0; k < D_DIM; k++) acc += g[k] * W[(size_t)(256 + k) * D_DIM + t];
  o[c * D_DIM + t] = acc;
}

extern "C" void kernel_launch(void* const* d_in, const int* in_sizes, int n_in,
                              void* d_out, int out_size, void* d_ws, size_t ws_size,
                              hipStream_t stream) {
  const float* feats = (const float*)d_in[0];
  const float* coord = (const float*)d_in[1];
  const float* pe_w1 = (const float*)d_in[3];
  const float* pe_b1 = (const float*)d_in[4];
  const float* pe_w2 = (const float*)d_in[5];
  const float* pe_b2 = (const float*)d_in[6];
  const float* pre_g = (const float*)d_in[7];
  const float* pre_b = (const float*)d_in[8];
  const float* n1_g = (const float*)d_in[9];
  const float* n1_b = (const float*)d_in[10];
  const float* wqkv = (const float*)d_in[11];
  const float* bqkv = (const float*)d_in[12];
  const float* wo = (const float*)d_in[13];
  const float* bo = (const float*)d_in[14];
  const float* n2_g = (const float*)d_in[15];
  const float* n2_b = (const float*)d_in[16];
  const float* m_w1 = (const float*)d_in[17];
  const float* m_b1 = (const float*)d_in[18];
  const float* m_w2 = (const float*)d_in[19];
  const float* m_b2 = (const float*)d_in[20];
  const float* gg_w1 = (const float*)d_in[21];
  const float* gg_b1 = (const float*)d_in[22];
  const float* gg_w2 = (const float*)d_in[23];
  const float* gg_b2 = (const float*)d_in[24];
  const float* f_w1 = (const float*)d_in[25];
  const float* f_b1 = (const float*)d_in[26];
  const float* f_w2 = (const float*)d_in[27];
  const float* f_b2 = (const float*)d_in[28];
  float* out = (float*)d_out;

  // ---------------- workspace layout (~308 MiB) ----------------
  char* ws = (char*)d_ws;
  float* xs = (float*)(ws);                         // [0,128MiB) fp32 residual stream
  u16* hbuf = (u16*)(ws + 134217728);               // [128,192MiB) bf16 (pe / ln1 / LN2 / g1)
  u16* qkvchunk = (u16*)(ws + 201326592);           // [192..240MiB) chunk qkv (48 MiB)
  u16* aochunk = (u16*)(ws + 251658240);            // [240..256MiB) chunk attn out (16 MiB)
  u16* tbuf = (u16*)(ws + 268435456);               // [256..288MiB) chunk MLP mid (32 MiB)
  u16* Hbuf = (u16*)(ws + 268435456);               // [N][64] bf16 (16 MiB, pre-attn only)
  u16* xobf = (u16*)(ws + 201326592);               // post-attn: bf16 xo (64 MiB, reuses qkv region)
  size_t off = 301989888;
  u64* keybuf = (u64*)(ws + off); off += (size_t)NTOT * 8;
  int* orderbuf = (int*)(ws + off); off += (size_t)NTOT * 4;
  int* rankbuf = (int*)(ws + off); off += (size_t)NTOT * 4;
  float* statsbuf = (float*)(ws + off); off += 4096;
  float* gtpart = (float*)(ws + off); off += (size_t)NCLOUD * 128 * D_DIM * 4;
  float* gtbuf = (float*)(ws + off); off += 4096;
  float* ggtbuf = (float*)(ws + off); off += 4096;
  float* fgtbuf = (float*)(ws + off); off += 4096;
  u16* wqkvT = (u16*)(ws + off); off += 768 * 256 * 2;
  u16* woT = (u16*)(ws + off); off += 256 * 256 * 2;
  u16* mw1T = (u16*)(ws + off); off += 512 * 256 * 2;
  u16* mw2T = (u16*)(ws + off); off += 256 * 512 * 2;
  u16* ggw1T = (u16*)(ws + off); off += 256 * 256 * 2;
  u16* ggw2T = (u16*)(ws + off); off += 256 * 256 * 2;
  u16* fw1T = (u16*)(ws + off); off += 256 * 256 * 2;
  u16* fw2T = (u16*)(ws + off); off += 256 * 256 * 2;
  u16* pw2T = (u16*)(ws + off); off += 64 * 256 * 2;
  u16* featsbf = (u16*)(ws);                        // aliases dead xs region [0,64MiB) (step 8+)
  u16* u1buf = (u16*)(ws + 67108864);               // aliases dead xs region [64,128MiB) (step 8+)

  // 1. stats + keys + sort + order/rank
  stats_kernel<<<NCLOUD, 256, 0, stream>>>(coord, statsbuf);
  key_kernel<<<NTOT / 256, 256, 0, stream>>>(coord, statsbuf, keybuf);
  sort_local_kernel<<<NTOT / 4096, 1024, 0, stream>>>(keybuf);
  for (int k = 8192; k <= 32768; k <<= 1) {
    for (int j = k >> 1; j >= 4096; j >>= 1)
      sort_global_kernel<<<NTOT / 512, 256, 0, stream>>>(keybuf, k, j);
    sort_finish_kernel<<<NTOT / 4096, 1024, 0, stream>>>(keybuf, k);
  }
  rank_kernel<<<NTOT / 256, 256, 0, stream>>>(keybuf, orderbuf, rankbuf);
  // 2. weight convert+transpose (bf16)
  wtrans_kernel<<<dim3(24, 8), 256, 0, stream>>>(wqkv, wqkvT, 256, 768);
  wtrans_kernel<<<dim3(8, 8), 256, 0, stream>>>(wo, woT, 256, 256);
  wtrans_kernel<<<dim3(16, 8), 256, 0, stream>>>(m_w1, mw1T, 256, 512);
  wtrans_kernel<<<dim3(8, 16), 256, 0, stream>>>(m_w2, mw2T, 512, 256);
  wtrans_kernel<<<dim3(8, 8), 256, 0, stream>>>(gg_w1, ggw1T, 256, 256);  // top half
  wtrans_kernel<<<dim3(8, 8), 256, 0, stream>>>(gg_w2, ggw2T, 256, 256);
  wtrans_kernel<<<dim3(8, 8), 256, 0, stream>>>(f_w1, fw1T, 256, 256);    // top half
  wtrans_kernel<<<dim3(8, 8), 256, 0, stream>>>(f_w2, fw2T, 256, 256);
  wtrans_kernel<<<dim3(8, 2), 256, 0, stream>>>(pe_w2, pw2T, 64, 256);
  // 3. PE: H = relu(scs@pw1+b1); pe = H @ pw2 + b2 (MFMA, K=64) -> hbuf bf16
  h_kernel<<<NTOT * 64 / 256, 256, 0, stream>>>(coord, statsbuf, pe_w1, pe_b1, Hbuf);
  mfma_gemm<64, 0, 2, false><<<dim3(2, NTOT / 128), 256, 0, stream>>>(
      Hbuf, pw2T, pe_b2, nullptr, hbuf, 256);
  // 4. xs[rank] = LN_pre(feats+pe); then ln1 = LN1(xs) -> hbuf (kernel boundary = barrier,
  //    so overwriting pe's buffer is safe)
  add_ln_kernel<<<NTOT / 4, 256, 0, stream>>>(feats, hbuf, rankbuf, pre_g, pre_b, xs);
  ln_bf16_kernel<<<NTOT / 4, 256, 0, stream>>>(xs, n1_g, n1_b, hbuf);
  // 5. attention block (chunked): xs += attn(ln1) @ wo + bo; proj also emits LN2 -> hbuf
  //    (chunk ch's qkv GEMM reads hbuf[ro..] BEFORE row_gemm overwrites the same range)
  for (int ch = 0; ch < NCHUNK; ch++) {
    const size_t ro = (size_t)ch * CROWS;
    mfma_gemm<256, 0, 2, false><<<dim3(6, CROWS / 128), 256, 0, stream>>>(
        hbuf + ro * 256, wqkvT, bqkv, nullptr, qkvchunk, 768);
    attn_mfma_kernel<<<dim3(CROWS / PATCH, NHEAD), 256, 0, stream>>>(qkvchunk, aochunk);
    mfma_row_gemm<256, 1><<<CROWS / 64, 256, 0, stream>>>(
        aochunk, woT, bo, xs + ro * 256, hbuf + ro * 256, nullptr, n2_g, n2_b);
  }
  // 6. MLP block (chunked): xs += gelu(LN2@m_w1+b)@m_w2+b; MLP2 also scatters -> xobf
  for (int ch = 0; ch < NCHUNK; ch++) {
    const size_t ro = (size_t)ch * CROWS;
    mfma_gemm<256, 2, 2, false><<<dim3(MLPD / 128, CROWS / 128), 256, 0, stream>>>(
        hbuf + ro * 256, mw1T, m_b1, nullptr, tbuf, 512);
    mfma_row_gemm<512, 2><<<CROWS / 64, 256, 0, stream>>>(
        tbuf, mw2T, m_b2, xs + ro * 256, xobf, orderbuf + ro, nullptr, nullptr);
  }
  // 7. global token from xs (mean is permutation-invariant)
  gt_partial_kernel<<<dim3(128, NCLOUD), 256, 0, stream>>>(xs, gtpart);
  gt_reduce_kernel<<<NCLOUD, 256, 0, stream>>>(gtpart, gtbuf);
  pervec_kernel<<<dim3(NCLOUD, 2), 256, 0, stream>>>(gtbuf, gg_w1, f_w1, ggtbuf, fgtbuf);
  // 8. xs region dead: stage-1 GEMMs -> g1 (hbuf) and u1 (u1buf)
  conv_bf16_kernel<<<NTOT * 256 / 1024, 256, 0, stream>>>(feats, featsbf);
  mfma_gemm<256, 1, 2, true><<<dim3(2, NTOT / 128), 256, 0, stream>>>(
      featsbf, ggw1T, gg_b1, ggtbuf, hbuf, 256);
  mfma_gemm<256, 1, 2, true><<<dim3(2, NTOT / 128), 256, 0, stream>>>(
      xobf, fw1T, f_b1, fgtbuf, u1buf, 256);
  // 9. fused tail: out = feats + sigmoid(g1@ggw2+b) * (u1@fw2+b)
  fuse2_kernel<<<dim3(4, NTOT / 128), 256, 0, stream>>>(
      hbuf, u1buf, ggw2T, fw2T, gg_b2, f_b2, feats, out);
  (void)in_sizes; (void)n_in; (void)out_size; (void)ws_size;
}

// Round 9
// 1359.001 us; speedup vs baseline: 3.6254x; 1.0286x over previous
//
#include <hip/hip_runtime.h>
#include <hip/hip_bf16.h>
#include <math.h>

#define D_DIM 256
#define NHEAD 8
#define HDIM 32
#define PATCH 256
#define NCLOUD 4
#define LPC 32768
#define NTOT (NCLOUD * LPC)
#define MLPD 512
#define PEHID 64
#define LN_EPS 1e-5f
#define NCHUNK 4
#define CROWS (NTOT / NCHUNK)   // 32768 rows per chunk

typedef unsigned long long u64;
typedef unsigned short u16;
typedef short bf16x8 __attribute__((ext_vector_type(8)));  // 8 bf16 (4 VGPRs)
typedef float f32x4 __attribute__((ext_vector_type(4)));

__device__ __forceinline__ u16 f2bf(float x) {
  unsigned u = __float_as_uint(x);
  u += 0x7fffu + ((u >> 16) & 1u);
  return (u16)(u >> 16);
}
__device__ __forceinline__ float bf2f(u16 u) {
  return __uint_as_float(((unsigned)u) << 16);
}

// async global->LDS DMA, 16B per lane; lds ptr must be wave-uniform base (+lane*16 implicit)
__device__ __forceinline__ void gload_lds16(const u16* g, u16* l) {
  __builtin_amdgcn_global_load_lds((const __attribute__((address_space(1))) void*)g,
                                   (__attribute__((address_space(3))) void*)l, 16, 0, 0);
}

// ---------------- per-cloud coordinate stats ----------------
__global__ __launch_bounds__(256) void stats_kernel(const float* __restrict__ coord,
                                                    float* __restrict__ stats) {
  const int c = blockIdx.x, t = threadIdx.x;
  float sm[3] = {0.f, 0.f, 0.f};
  float mn[3] = {1e30f, 1e30f, 1e30f};
  float mx[3] = {-1e30f, -1e30f, -1e30f};
  const float* cp = coord + (size_t)c * LPC * 3;
  for (int i = t; i < LPC; i += 256) {
#pragma unroll
    for (int a = 0; a < 3; a++) {
      float v = cp[(size_t)i * 3 + a];
      sm[a] += v;
      mn[a] = fminf(mn[a], v);
      mx[a] = fmaxf(mx[a], v);
    }
  }
  __shared__ float sb[256];
  float rsum[3], rmn[3], rmx[3];
#pragma unroll
  for (int a = 0; a < 3; a++) {
    sb[t] = sm[a]; __syncthreads();
    for (int s = 128; s > 0; s >>= 1) { if (t < s) sb[t] += sb[t + s]; __syncthreads(); }
    rsum[a] = sb[0]; __syncthreads();
    sb[t] = mn[a]; __syncthreads();
    for (int s = 128; s > 0; s >>= 1) { if (t < s) sb[t] = fminf(sb[t], sb[t + s]); __syncthreads(); }
    rmn[a] = sb[0]; __syncthreads();
    sb[t] = mx[a]; __syncthreads();
    for (int s = 128; s > 0; s >>= 1) { if (t < s) sb[t] = fmaxf(sb[t], sb[t + s]); __syncthreads(); }
    rmx[a] = sb[0]; __syncthreads();
  }
  if (t == 0) {
    float* st = stats + c * 16;
#pragma unroll
    for (int a = 0; a < 3; a++) {
      float mean = rsum[a] / (float)LPC;
      st[a] = mean;
      st[3 + a] = fmaxf(fmaxf(rmx[a] - mean, mean - rmn[a]), 1e-6f);
      st[6 + a] = rmn[a];
      st[9 + a] = fmaxf(rmx[a] - rmn[a], 1e-6f);
    }
  }
}

// ---------------- serialization keys (bit-exact vs numpy; stable tie-break) ----------------
__global__ __launch_bounds__(256) void key_kernel(const float* __restrict__ coord,
                                                  const float* __restrict__ stats,
                                                  u64* __restrict__ keys) {
#pragma clang fp contract(off)
  const int g = blockIdx.x * 256 + threadIdx.x;
  const int c = g >> 15;
  const float* st = stats + c * 16;
  float k0 = (coord[(size_t)g * 3 + 0] - st[6]) / st[9];
  float k1 = (coord[(size_t)g * 3 + 1] - st[7]) / st[10];
  float k2 = (coord[(size_t)g * 3 + 2] - st[8]) / st[11];
  float key = k0 + 2.17f * k1;
  key = key + 3.31f * k2;
  keys[g] = ((u64)__float_as_uint(key) << 32) | (unsigned)(g & (LPC - 1));
}

// ---------------- bitonic sort (per-cloud, u64 packed key|idx), 1024 threads ----------------
__global__ __launch_bounds__(1024) void sort_local_kernel(u64* __restrict__ keys) {
  __shared__ u64 s[4096];
  const int base = blockIdx.x * 4096;
  const int t = threadIdx.x;
  for (int i = t; i < 4096; i += 1024) s[i] = keys[base + i];
  __syncthreads();
  for (int k = 2; k <= 4096; k <<= 1) {
    for (int j = k >> 1; j > 0; j >>= 1) {
      for (int p = t; p < 2048; p += 1024) {
        int i = ((p & ~(j - 1)) << 1) | (p & (j - 1));
        int l = i | j;
        bool asc = (((base + i) & (LPC - 1)) & k) == 0;
        u64 a = s[i], bb = s[l];
        if (asc ? (a > bb) : (a < bb)) { s[i] = bb; s[l] = a; }
      }
      __syncthreads();
    }
  }
  for (int i = t; i < 4096; i += 1024) keys[base + i] = s[i];
}

__global__ __launch_bounds__(256) void sort_global_kernel(u64* __restrict__ keys, int k, int j) {
  int p = blockIdx.x * 256 + threadIdx.x;
  int i = ((p & ~(j - 1)) << 1) | (p & (j - 1));
  int l = i | j;
  bool asc = ((i & (LPC - 1)) & k) == 0;
  u64 a = keys[i], b = keys[l];
  if (asc ? (a > b) : (a < b)) { keys[i] = b; keys[l] = a; }
}

__global__ __launch_bounds__(1024) void sort_finish_kernel(u64* __restrict__ keys, int k) {
  __shared__ u64 s[4096];
  const int base = blockIdx.x * 4096;
  const int t = threadIdx.x;
  for (int i = t; i < 4096; i += 1024) s[i] = keys[base + i];
  __syncthreads();
  for (int j = 2048; j > 0; j >>= 1) {
    for (int p = t; p < 2048; p += 1024) {
      int i = ((p & ~(j - 1)) << 1) | (p & (j - 1));
      int l = i | j;
      bool asc = (((base + i) & (LPC - 1)) & k) == 0;
      u64 a = s[i], bb = s[l];
      if (asc ? (a > bb) : (a < bb)) { s[i] = bb; s[l] = a; }
    }
    __syncthreads();
  }
  for (int i = t; i < 4096; i += 1024) keys[base + i] = s[i];
}

// ---------------- order + rank from sorted keys ----------------
__global__ __launch_bounds__(256) void rank_kernel(const u64* __restrict__ keys,
                                                   int* __restrict__ order,
                                                   int* __restrict__ rank) {
  const int g = blockIdx.x * 256 + threadIdx.x;
  const int src = (int)(unsigned)(keys[g] & 0xffffffffULL) + (g & ~(LPC - 1));
  order[g] = src;
  rank[src] = g;
}

// ---------------- weight transpose + fp32->bf16: dst[C][R] = src[R][C] ----------------
__global__ __launch_bounds__(256) void wtrans_kernel(const float* __restrict__ src,
                                                     u16* __restrict__ dst, int R, int C) {
  __shared__ float t[32][33];
  const int bx = blockIdx.x * 32, by = blockIdx.y * 32;
  const int lc = threadIdx.x & 31, lr = threadIdx.x >> 5;  // 8 rows per pass
  for (int i = 0; i < 32; i += 8) t[lr + i][lc] = src[(size_t)(by + lr + i) * C + bx + lc];
  __syncthreads();
  for (int i = 0; i < 32; i += 8)
    dst[(size_t)(bx + lr + i) * R + by + lc] = f2bf(t[lc][lr + i]);
}

// ---------------- H = relu(scs @ pw1 + pb1), bf16 [N][64] ----------------
__global__ __launch_bounds__(256) void h_kernel(const float* __restrict__ coord,
                                                const float* __restrict__ stats,
                                                const float* __restrict__ pw1,
                                                const float* __restrict__ pb1,
                                                u16* __restrict__ H) {
  const int idx = blockIdx.x * 256 + threadIdx.x;
  const int row = idx >> 6, j = idx & 63;
  const int c = row >> 15;
  const float* st = stats + c * 16;
  float s0 = (coord[(size_t)row * 3 + 0] - st[0]) / st[3];
  float s1 = (coord[(size_t)row * 3 + 1] - st[1]) / st[4];
  float s2 = (coord[(size_t)row * 3 + 2] - st[2]) / st[5];
  float h = pb1[j] + s0 * pw1[j] + s1 * pw1[64 + j] + s2 * pw1[128 + j];
  H[idx] = f2bf(fmaxf(h, 0.f));
}

// ---------------- wave-per-row: xs[rank[row]] = LN(feats + pe) (fp32) ----------------
__global__ __launch_bounds__(256) void add_ln_kernel(const float* __restrict__ feats,
                                                     const u16* __restrict__ pe,
                                                     const int* __restrict__ rank,
                                                     const float* __restrict__ g,
                                                     const float* __restrict__ b,
                                                     float* __restrict__ xs) {
  const int row = blockIdx.x * 4 + (threadIdx.x >> 6);
  const int lane = threadIdx.x & 63;
  float4 f = *(const float4*)(feats + (size_t)row * 256 + lane * 4);
  ushort4 p = *(const ushort4*)(pe + (size_t)row * 256 + lane * 4);
  float v0 = f.x + bf2f(p.x), v1 = f.y + bf2f(p.y);
  float v2 = f.z + bf2f(p.z), v3 = f.w + bf2f(p.w);
  float s = v0 + v1 + v2 + v3;
#pragma unroll
  for (int o = 32; o > 0; o >>= 1) s += __shfl_xor(s, o);
  float mean = s * (1.f / 256.f);
  float d0 = v0 - mean, d1 = v1 - mean, d2 = v2 - mean, d3 = v3 - mean;
  float ss = d0 * d0 + d1 * d1 + d2 * d2 + d3 * d3;
#pragma unroll
  for (int o = 32; o > 0; o >>= 1) ss += __shfl_xor(ss, o);
  float inv = 1.f / sqrtf(ss * (1.f / 256.f) + LN_EPS);
  float4 gv = *(const float4*)(g + lane * 4);
  float4 bv = *(const float4*)(b + lane * 4);
  int dst = rank[row];
  float4 o4;
  o4.x = d0 * inv * gv.x + bv.x; o4.y = d1 * inv * gv.y + bv.y;
  o4.z = d2 * inv * gv.z + bv.z; o4.w = d3 * inv * gv.w + bv.w;
  *(float4*)(xs + (size_t)dst * 256 + lane * 4) = o4;
}

// ---------------- wave-per-row LN: fp32 in -> bf16 out ----------------
__global__ __launch_bounds__(256) void ln_bf16_kernel(const float* __restrict__ in,
                                                      const float* __restrict__ g,
                                                      const float* __restrict__ b,
                                                      u16* __restrict__ out) {
  const int row = blockIdx.x * 4 + (threadIdx.x >> 6);
  const int lane = threadIdx.x & 63;
  float4 v = *(const float4*)(in + (size_t)row * 256 + lane * 4);
  float s = v.x + v.y + v.z + v.w;
#pragma unroll
  for (int o = 32; o > 0; o >>= 1) s += __shfl_xor(s, o);
  float mean = s * (1.f / 256.f);
  float d0 = v.x - mean, d1 = v.y - mean, d2 = v.z - mean, d3 = v.w - mean;
  float ss = d0 * d0 + d1 * d1 + d2 * d2 + d3 * d3;
#pragma unroll
  for (int o = 32; o > 0; o >>= 1) ss += __shfl_xor(ss, o);
  float inv = 1.f / sqrtf(ss * (1.f / 256.f) + LN_EPS);
  float4 gv = *(const float4*)(g + lane * 4);
  float4 bv = *(const float4*)(b + lane * 4);
  ushort4 o4;
  o4.x = f2bf(d0 * inv * gv.x + bv.x); o4.y = f2bf(d1 * inv * gv.y + bv.y);
  o4.z = f2bf(d2 * inv * gv.z + bv.z); o4.w = f2bf(d3 * inv * gv.w + bv.w);
  *(ushort4*)(out + (size_t)row * 256 + lane * 4) = o4;
}

// ---------------- MFMA GEMM (m97 structure): C[M x Ko] = act(A@Wt^T + bias) ----------------
// MODE: 0 fp32 store, 1 fp32 resid +=, 2 bf16 store
template <int K, int ACT, int MODE, bool EXTRA>
__global__ __launch_bounds__(256, 4) void mfma_gemm(const u16* __restrict__ A,
                                                    const u16* __restrict__ Wt,
                                                    const float* __restrict__ bias,
                                                    const float* __restrict__ extra,
                                                    void* __restrict__ Cout, int Ko) {
  __shared__ __align__(16) u16 Al[128 * 32];
  __shared__ __align__(16) u16 Bl[128 * 32];
  const int tid = threadIdx.x;
  const int lane = tid & 63, wave = tid >> 6;
  const int wr = wave >> 1, wc = wave & 1;
  const int l15 = lane & 15, l4 = lane >> 4;
  const size_t row0 = (size_t)blockIdx.y * 128;
  const int col0 = blockIdx.x * 128;
  const int q0 = wave * 64 + lane;
  const int q1 = q0 + 256;
  const u16* gA0 = A + (row0 + (q0 >> 2)) * K + (q0 & 3) * 8;
  const u16* gA1 = A + (row0 + (q1 >> 2)) * K + (q1 & 3) * 8;
  const u16* gB0 = Wt + (size_t)(col0 + (q0 >> 2)) * K + (q0 & 3) * 8;
  const u16* gB1 = Wt + (size_t)(col0 + (q1 >> 2)) * K + (q1 & 3) * 8;
  u16* lA0 = Al + wave * 512;
  u16* lA1 = Al + 2048 + wave * 512;
  u16* lB0 = Bl + wave * 512;
  u16* lB1 = Bl + 2048 + wave * 512;
  f32x4 acc[4][4];
#pragma unroll
  for (int i = 0; i < 4; i++)
#pragma unroll
    for (int j = 0; j < 4; j++) acc[i][j] = f32x4{0.f, 0.f, 0.f, 0.f};
#pragma unroll 1
  for (int k0 = 0; k0 < K; k0 += 32) {
    gload_lds16(gA0 + k0, lA0);
    gload_lds16(gA1 + k0, lA1);
    gload_lds16(gB0 + k0, lB0);
    gload_lds16(gB1 + k0, lB1);
    __syncthreads();
    bf16x8 af[4], bfr[4];
#pragma unroll
    for (int rb = 0; rb < 4; rb++)
      af[rb] = *(const bf16x8*)&Al[(wr * 64 + rb * 16 + l15) * 32 + l4 * 8];
#pragma unroll
    for (int cb = 0; cb < 4; cb++)
      bfr[cb] = *(const bf16x8*)&Bl[(wc * 64 + cb * 16 + l15) * 32 + l4 * 8];
#pragma unroll
    for (int rb = 0; rb < 4; rb++)
#pragma unroll
      for (int cb = 0; cb < 4; cb++)
        acc[rb][cb] = __builtin_amdgcn_mfma_f32_16x16x32_bf16(af[rb], bfr[cb], acc[rb][cb], 0, 0, 0);
    __syncthreads();
  }
#pragma unroll
  for (int rb = 0; rb < 4; rb++)
#pragma unroll
    for (int cb = 0; cb < 4; cb++)
#pragma unroll
      for (int r = 0; r < 4; r++) {
        size_t row = row0 + wr * 64 + rb * 16 + l4 * 4 + r;
        int col = col0 + wc * 64 + cb * 16 + l15;
        float v = acc[rb][cb][r] + bias[col];
        if (EXTRA) v += extra[((int)(row >> 15)) * 256 + col];
        if (ACT == 1) v = fmaxf(v, 0.f);
        else if (ACT == 2) v = 0.5f * v * (1.f + erff(v * 0.70710678118654752440f));
        else if (ACT == 3) v = 1.f / (1.f + __expf(-v));
        size_t o = row * (size_t)Ko + col;
        if (MODE == 0) ((float*)Cout)[o] = v;
        else if (MODE == 1) ((float*)Cout)[o] += v;
        else ((u16*)Cout)[o] = f2bf(v);
      }
}

// ---------------- full-row MFMA GEMM: 64 rows x 256 cols per block, resid += on xs -------
// EPI 1: row-LN -> hout bf16 (g/b params). EPI 2: scatter t -> hout[order[row]*256+col].
template <int K, int EPI>
__global__ __launch_bounds__(256, 3) void mfma_row_gemm(const u16* __restrict__ A,
                                                        const u16* __restrict__ Wt,
                                                        const float* __restrict__ bias,
                                                        float* __restrict__ xs,
                                                        u16* __restrict__ hout,
                                                        const int* __restrict__ order,
                                                        const float* __restrict__ g,
                                                        const float* __restrict__ b) {
  __shared__ __align__(16) u16 Al[64 * 32];
  __shared__ __align__(16) u16 Bl[256 * 32];
  __shared__ float reds[2][4][64];
  const int tid = threadIdx.x;
  const int lane = tid & 63, wave = tid >> 6;
  const int l15 = lane & 15, l4 = lane >> 4;
  const size_t row0 = (size_t)blockIdx.x * 64;
  const u16* gA = A + (row0 + (tid >> 2)) * K + (tid & 3) * 8;
  u16* lA = Al + wave * 512;
  const u16* gB[4];
  u16* lB[4];
#pragma unroll
  for (int s = 0; s < 4; s++) {
    int q = s * 256 + tid;
    gB[s] = Wt + (size_t)(q >> 2) * K + (q & 3) * 8;
    lB[s] = Bl + s * 2048 + wave * 512;
  }
  f32x4 acc[4][4];
#pragma unroll
  for (int i = 0; i < 4; i++)
#pragma unroll
    for (int j = 0; j < 4; j++) acc[i][j] = f32x4{0.f, 0.f, 0.f, 0.f};
#pragma unroll 1
  for (int k0 = 0; k0 < K; k0 += 32) {
    gload_lds16(gA + k0, lA);
#pragma unroll
    for (int s = 0; s < 4; s++) gload_lds16(gB[s] + k0, lB[s]);
    __syncthreads();
    bf16x8 af[4], bfr[4];
#pragma unroll
    for (int rb = 0; rb < 4; rb++)
      af[rb] = *(const bf16x8*)&Al[(rb * 16 + l15) * 32 + l4 * 8];
#pragma unroll
    for (int cb = 0; cb < 4; cb++)
      bfr[cb] = *(const bf16x8*)&Bl[(wave * 64 + cb * 16 + l15) * 32 + l4 * 8];
#pragma unroll
    for (int rb = 0; rb < 4; rb++)
#pragma unroll
      for (int cb = 0; cb < 4; cb++)
        acc[rb][cb] = __builtin_amdgcn_mfma_f32_16x16x32_bf16(af[rb], bfr[cb], acc[rb][cb], 0, 0, 0);
    __syncthreads();
  }
  // epilogue: t = xs + v + bias; xs = t (keep t in acc)
#pragma unroll
  for (int rb = 0; rb < 4; rb++)
#pragma unroll
    for (int cb = 0; cb < 4; cb++)
#pragma unroll
      for (int r = 0; r < 4; r++) {
        size_t row = row0 + rb * 16 + l4 * 4 + r;
        int col = wave * 64 + cb * 16 + l15;
        size_t o = row * 256 + col;
        float t = xs[o] + acc[rb][cb][r] + bias[col];
        xs[o] = t;
        acc[rb][cb][r] = t;
      }
  if (EPI == 1) {
    float ps[4][4];
#pragma unroll
    for (int rb = 0; rb < 4; rb++)
#pragma unroll
      for (int r = 0; r < 4; r++) {
        float v = acc[rb][0][r] + acc[rb][1][r] + acc[rb][2][r] + acc[rb][3][r];
#pragma unroll
        for (int oo = 1; oo < 16; oo <<= 1) v += __shfl_xor(v, oo);
        ps[rb][r] = v;
      }
    if (l15 == 0)
#pragma unroll
      for (int rb = 0; rb < 4; rb++)
#pragma unroll
        for (int r = 0; r < 4; r++) reds[0][wave][rb * 16 + l4 * 4 + r] = ps[rb][r];
    __syncthreads();
    float mean[4][4];
#pragma unroll
    for (int rb = 0; rb < 4; rb++)
#pragma unroll
      for (int r = 0; r < 4; r++) {
        int ri = rb * 16 + l4 * 4 + r;
        mean[rb][r] = (reds[0][0][ri] + reds[0][1][ri] + reds[0][2][ri] + reds[0][3][ri]) *
                      (1.f / 256.f);
      }
#pragma unroll
    for (int rb = 0; rb < 4; rb++)
#pragma unroll
      for (int r = 0; r < 4; r++) {
        float d0 = acc[rb][0][r] - mean[rb][r], d1 = acc[rb][1][r] - mean[rb][r];
        float d2 = acc[rb][2][r] - mean[rb][r], d3 = acc[rb][3][r] - mean[rb][r];
        float v = d0 * d0 + d1 * d1 + d2 * d2 + d3 * d3;
#pragma unroll
        for (int oo = 1; oo < 16; oo <<= 1) v += __shfl_xor(v, oo);
        ps[rb][r] = v;
      }
    if (l15 == 0)
#pragma unroll
      for (int rb = 0; rb < 4; rb++)
#pragma unroll
        for (int r = 0; r < 4; r++) reds[1][wave][rb * 16 + l4 * 4 + r] = ps[rb][r];
    __syncthreads();
#pragma unroll
    for (int rb = 0; rb < 4; rb++)
#pragma unroll
      for (int r = 0; r < 4; r++) {
        int ri = rb * 16 + l4 * 4 + r;
        float var = (reds[1][0][ri] + reds[1][1][ri] + reds[1][2][ri] + reds[1][3][ri]) *
                    (1.f / 256.f);
        float inv = 1.f / sqrtf(var + LN_EPS);
        size_t row = row0 + ri;
#pragma unroll
        for (int cb = 0; cb < 4; cb++) {
          int col = wave * 64 + cb * 16 + l15;
          hout[row * 256 + col] =
              f2bf((acc[rb][cb][r] - mean[rb][r]) * inv * g[col] + b[col]);
        }
      }
  } else {
#pragma unroll
    for (int rb = 0; rb < 4; rb++)
#pragma unroll
      for (int r = 0; r < 4; r++) {
        size_t row = row0 + rb * 16 + l4 * 4 + r;
        size_t dst = (size_t)order[row];
#pragma unroll
        for (int cb = 0; cb < 4; cb++) {
          int col = wave * 64 + cb * 16 + l15;
          hout[dst * 256 + col] = f2bf(acc[rb][cb][r]);
        }
      }
  }
}

// ---------------- fully-fused tail: 32 rows/block -------------------------------------
// g1 = relu(bf16(feats)@ggw1T + ggt + b1g) -> LDS; u1 = relu(xobf@fw1T + fgt + b1f) -> LDS;
// out = feats + sigmoid(g1@ggw2T + b2g) * (u1@fw2T + b2f)
__global__ __launch_bounds__(256, 3) void tail_kernel(
    const float* __restrict__ feats, const u16* __restrict__ xobf,
    const u16* __restrict__ ggw1T, const u16* __restrict__ fw1T,
    const u16* __restrict__ ggw2T, const u16* __restrict__ fw2T,
    const float* __restrict__ ggt, const float* __restrict__ fgt,
    const float* __restrict__ b1g, const float* __restrict__ b1f,
    const float* __restrict__ b2g, const float* __restrict__ b2f,
    float* __restrict__ out) {
  __shared__ __align__(16) u16 g1l[32 * 264];   // [row][col], stride 264 (528B, 16B-aligned)
  __shared__ __align__(16) u16 u1l[32 * 264];
  __shared__ __align__(16) u16 Bst[256 * 32];   // weight chunk, reused per phase
  __shared__ __align__(16) u16 Ast[32 * 32];    // A chunk, reused
  const int tid = threadIdx.x;
  const int lane = tid & 63, wave = tid >> 6;
  const int l15 = lane & 15, l4 = lane >> 4;
  const size_t row0 = (size_t)blockIdx.x * 32;
  const int cloud = (int)(row0 >> 15);
  f32x4 acc[2][4];
  // ---- phase A1: g1 (A = bf16(feats), B = ggw1T) ----
#pragma unroll
  for (int i = 0; i < 2; i++)
#pragma unroll
    for (int j = 0; j < 4; j++) acc[i][j] = f32x4{0.f, 0.f, 0.f, 0.f};
#pragma unroll 1
  for (int k0 = 0; k0 < 256; k0 += 32) {
#pragma unroll
    for (int s = 0; s < 4; s++) {
      int q = s * 256 + tid;
      gload_lds16(ggw1T + (size_t)(q >> 2) * 256 + k0 + (q & 3) * 8,
                  Bst + s * 2048 + wave * 512);
    }
    {
      int r = tid >> 3, c4 = (tid & 7) * 4;
      float4 v = *(const float4*)(feats + (row0 + r) * 256 + k0 + c4);
      ushort4 o4; o4.x = f2bf(v.x); o4.y = f2bf(v.y); o4.z = f2bf(v.z); o4.w = f2bf(v.w);
      *(ushort4*)&Ast[r * 32 + c4] = o4;
    }
    __syncthreads();
    bf16x8 af[2];
#pragma unroll
    for (int rb = 0; rb < 2; rb++)
      af[rb] = *(const bf16x8*)&Ast[(rb * 16 + l15) * 32 + l4 * 8];
#pragma unroll
    for (int cb = 0; cb < 4; cb++) {
      bf16x8 bf = *(const bf16x8*)&Bst[(wave * 64 + cb * 16 + l15) * 32 + l4 * 8];
#pragma unroll
      for (int rb = 0; rb < 2; rb++)
        acc[rb][cb] = __builtin_amdgcn_mfma_f32_16x16x32_bf16(af[rb], bf, acc[rb][cb], 0, 0, 0);
    }
    __syncthreads();
  }
#pragma unroll
  for (int rb = 0; rb < 2; rb++)
#pragma unroll
    for (int cb = 0; cb < 4; cb++)
#pragma unroll
      for (int r = 0; r < 4; r++) {
        int row = rb * 16 + l4 * 4 + r;
        int col = wave * 64 + cb * 16 + l15;
        float v = acc[rb][cb][r] + b1g[col] + ggt[cloud * 256 + col];
        g1l[row * 264 + col] = f2bf(fmaxf(v, 0.f));
      }
  // ---- phase A2: u1 (A = xobf, B = fw1T) ----
#pragma unroll
  for (int i = 0; i < 2; i++)
#pragma unroll
    for (int j = 0; j < 4; j++) acc[i][j] = f32x4{0.f, 0.f, 0.f, 0.f};
#pragma unroll 1
  for (int k0 = 0; k0 < 256; k0 += 32) {
    __syncthreads();  // previous phase readers done before restaging Bst/Ast
#pragma unroll
    for (int s = 0; s < 4; s++) {
      int q = s * 256 + tid;
      gload_lds16(fw1T + (size_t)(q >> 2) * 256 + k0 + (q & 3) * 8,
                  Bst + s * 2048 + wave * 512);
    }
    if (tid < 128) {  // 32 rows x 32 k = 2 KB, waves 0-1
      int q = tid;
      gload_lds16(xobf + (row0 + (q >> 2)) * 256 + k0 + (q & 3) * 8, Ast + wave * 512);
    }
    __syncthreads();
    bf16x8 af[2];
#pragma unroll
    for (int rb = 0; rb < 2; rb++)
      af[rb] = *(const bf16x8*)&Ast[(rb * 16 + l15) * 32 + l4 * 8];
#pragma unroll
    for (int cb = 0; cb < 4; cb++) {
      bf16x8 bf = *(const bf16x8*)&Bst[(wave * 64 + cb * 16 + l15) * 32 + l4 * 8];
#pragma unroll
      for (int rb = 0; rb < 2; rb++)
        acc[rb][cb] = __builtin_amdgcn_mfma_f32_16x16x32_bf16(af[rb], bf, acc[rb][cb], 0, 0, 0);
    }
  }
#pragma unroll
  for (int rb = 0; rb < 2; rb++)
#pragma unroll
    for (int cb = 0; cb < 4; cb++)
#pragma unroll
      for (int r = 0; r < 4; r++) {
        int row = rb * 16 + l4 * 4 + r;
        int col = wave * 64 + cb * 16 + l15;
        float v = acc[rb][cb][r] + b1f[col] + fgt[cloud * 256 + col];
        u1l[row * 264 + col] = f2bf(fmaxf(v, 0.f));
      }
  // ---- phase B1: gate_arg = g1 @ ggw2T ----
#pragma unroll
  for (int i = 0; i < 2; i++)
#pragma unroll
    for (int j = 0; j < 4; j++) acc[i][j] = f32x4{0.f, 0.f, 0.f, 0.f};
#pragma unroll 1
  for (int k0 = 0; k0 < 256; k0 += 32) {
    __syncthreads();
#pragma unroll
    for (int s = 0; s < 4; s++) {
      int q = s * 256 + tid;
      gload_lds16(ggw2T + (size_t)(q >> 2) * 256 + k0 + (q & 3) * 8,
                  Bst + s * 2048 + wave * 512);
    }
    __syncthreads();
    bf16x8 af[2];
#pragma unroll
    for (int rb = 0; rb < 2; rb++)
      af[rb] = *(const bf16x8*)&g1l[(rb * 16 + l15) * 264 + k0 + l4 * 8];
#pragma unroll
    for (int cb = 0; cb < 4; cb++) {
      bf16x8 bf = *(const bf16x8*)&Bst[(wave * 64 + cb * 16 + l15) * 32 + l4 * 8];
#pragma unroll
      for (int rb = 0; rb < 2; rb++)
        acc[rb][cb] = __builtin_amdgcn_mfma_f32_16x16x32_bf16(af[rb], bf, acc[rb][cb], 0, 0, 0);
    }
  }
  float sg[2][4][4];
#pragma unroll
  for (int rb = 0; rb < 2; rb++)
#pragma unroll
    for (int cb = 0; cb < 4; cb++)
#pragma unroll
      for (int r = 0; r < 4; r++) {
        int col = wave * 64 + cb * 16 + l15;
        sg[rb][cb][r] = 1.f / (1.f + __expf(-(acc[rb][cb][r] + b2g[col])));
      }
  // ---- phase B2: fused = u1 @ fw2T; out = feats + sg * (fused + b2f) ----
#pragma unroll
  for (int i = 0; i < 2; i++)
#pragma unroll
    for (int j = 0; j < 4; j++) acc[i][j] = f32x4{0.f, 0.f, 0.f, 0.f};
#pragma unroll 1
  for (int k0 = 0; k0 < 256; k0 += 32) {
    __syncthreads();
#pragma unroll
    for (int s = 0; s < 4; s++) {
      int q = s * 256 + tid;
      gload_lds16(fw2T + (size_t)(q >> 2) * 256 + k0 + (q & 3) * 8,
                  Bst + s * 2048 + wave * 512);
    }
    __syncthreads();
    bf16x8 af[2];
#pragma unroll
    for (int rb = 0; rb < 2; rb++)
      af[rb] = *(const bf16x8*)&u1l[(rb * 16 + l15) * 264 + k0 + l4 * 8];
#pragma unroll
    for (int cb = 0; cb < 4; cb++) {
      bf16x8 bf = *(const bf16x8*)&Bst[(wave * 64 + cb * 16 + l15) * 32 + l4 * 8];
#pragma unroll
      for (int rb = 0; rb < 2; rb++)
        acc[rb][cb] = __builtin_amdgcn_mfma_f32_16x16x32_bf16(af[rb], bf, acc[rb][cb], 0, 0, 0);
    }
  }
#pragma unroll
  for (int rb = 0; rb < 2; rb++)
#pragma unroll
    for (int cb = 0; cb < 4; cb++)
#pragma unroll
      for (int r = 0; r < 4; r++) {
        size_t row = row0 + rb * 16 + l4 * 4 + r;
        int col = wave * 64 + cb * 16 + l15;
        size_t o = row * 256 + col;
        out[o] = feats[o] + sg[rb][cb][r] * (acc[rb][cb][r] + b2f[col]);
      }
}

// ---------------- MFMA attention: one (window, head) per block, 4 waves x 64 queries ----
__global__ __launch_bounds__(256, 3) void attn_mfma_kernel(const u16* __restrict__ qkv,
                                                           u16* __restrict__ ao) {
  __shared__ __align__(16) u16 VT[32 * 264];       // V^T [d][k], padded stride 264
  __shared__ __align__(16) u16 Pl[4][16 * 264];    // per-wave P [q][k]
  const int w = blockIdx.x, h = blockIdx.y;
  const int tid = threadIdx.x;
  const int lane = tid & 63, wave = tid >> 6;
  const int l15 = lane & 15, l4 = lane >> 4;
  const size_t base = (size_t)w * PATCH;
  {
    const u16* vrow = qkv + (base + tid) * 768 + 512 + h * HDIM;
#pragma unroll
    for (int d4 = 0; d4 < 8; d4++) {
      ushort4 v4 = *(const ushort4*)(vrow + d4 * 4);
      VT[(d4 * 4 + 0) * 264 + tid] = v4.x;
      VT[(d4 * 4 + 1) * 264 + tid] = v4.y;
      VT[(d4 * 4 + 2) * 264 + tid] = v4.z;
      VT[(d4 * 4 + 3) * 264 + tid] = v4.w;
    }
  }
  __syncthreads();
  u16* Pw = &Pl[wave][0];
  const float scale = 0.17677669529663687f;  // 1/sqrt(32)
  const f32x4 zero = {0.f, 0.f, 0.f, 0.f};
  for (int qt = 0; qt < 4; qt++) {
    const int qbase = wave * 64 + qt * 16;
    bf16x8 qf = *(const bf16x8*)(qkv + (base + qbase + l15) * 768 + h * HDIM + l4 * 8);
    f32x4 s[16];
#pragma unroll
    for (int kt = 0; kt < 16; kt++) {
      bf16x8 kf = *(const bf16x8*)(qkv + (base + kt * 16 + l15) * 768 + 256 + h * HDIM + l4 * 8);
      s[kt] = __builtin_amdgcn_mfma_f32_16x16x32_bf16(kf, qf, zero, 0, 0, 0);
    }
    float m = -1e30f;
#pragma unroll
    for (int kt = 0; kt < 16; kt++)
#pragma unroll
      for (int r = 0; r < 4; r++) { s[kt][r] *= scale; m = fmaxf(m, s[kt][r]); }
    m = fmaxf(m, __shfl_xor(m, 16));
    m = fmaxf(m, __shfl_xor(m, 32));
    float lsum = 0.f;
#pragma unroll
    for (int kt = 0; kt < 16; kt++) {
      float p0 = __expf(s[kt][0] - m), p1 = __expf(s[kt][1] - m);
      float p2 = __expf(s[kt][2] - m), p3 = __expf(s[kt][3] - m);
      lsum += (p0 + p1) + (p2 + p3);
      ushort4 pw4;
      pw4.x = f2bf(p0); pw4.y = f2bf(p1); pw4.z = f2bf(p2); pw4.w = f2bf(p3);
      *(ushort4*)&Pw[l15 * 264 + kt * 16 + l4 * 4] = pw4;
    }
    lsum += __shfl_xor(lsum, 16);
    lsum += __shfl_xor(lsum, 32);
    f32x4 o0 = zero, o1 = zero;
#pragma unroll
    for (int kc = 0; kc < 8; kc++) {
      bf16x8 pf = *(const bf16x8*)&Pw[l15 * 264 + kc * 32 + l4 * 8];
      bf16x8 va = *(const bf16x8*)&VT[l15 * 264 + kc * 32 + l4 * 8];
      bf16x8 vb = *(const bf16x8*)&VT[(16 + l15) * 264 + kc * 32 + l4 * 8];
      o0 = __builtin_amdgcn_mfma_f32_16x16x32_bf16(va, pf, o0, 0, 0, 0);
      o1 = __builtin_amdgcn_mfma_f32_16x16x32_bf16(vb, pf, o1, 0, 0, 0);
    }
    float inv = 1.f / lsum;
    u16* op = ao + (base + qbase + l15) * D_DIM + h * HDIM;
    ushort4 w0, w1;
    w0.x = f2bf(o0[0] * inv); w0.y = f2bf(o0[1] * inv);
    w0.z = f2bf(o0[2] * inv); w0.w = f2bf(o0[3] * inv);
    w1.x = f2bf(o1[0] * inv); w1.y = f2bf(o1[1] * inv);
    w1.z = f2bf(o1[2] * inv); w1.w = f2bf(o1[3] * inv);
    *(ushort4*)(op + l4 * 4) = w0;
    *(ushort4*)(op + 16 + l4 * 4) = w1;
  }
}

// ---------------- global-token mean from xs (permutation-invariant) ----------------
__global__ __launch_bounds__(256) void gt_partial_kernel(const float* __restrict__ xs,
                                                         float* __restrict__ part) {
  const int s = blockIdx.x, c = blockIdx.y;
  const int t = threadIdx.x;
  float acc = 0.f;
  const size_t base = (size_t)c * LPC + (size_t)s * 256;
  for (int r = 0; r < 256; r++) acc += xs[(base + r) * D_DIM + t];
  part[(size_t)(c * 128 + s) * D_DIM + t] = acc;
}

__global__ __launch_bounds__(256) void gt_reduce_kernel(const float* __restrict__ part,
                                                        float* __restrict__ gt) {
  const int c = blockIdx.x, t = threadIdx.x;
  float s = 0.f;
  for (int i = 0; i < 128; i++) s += part[(size_t)(c * 128 + i) * D_DIM + t];
  gt[c * D_DIM + t] = s * (1.f / (float)LPC);
}

// ---------------- per-cloud gt @ bottom-half weights (fp32) ----------------
__global__ __launch_bounds__(256) void pervec_kernel(const float* __restrict__ gt,
                                                     const float* __restrict__ ggw1,
                                                     const float* __restrict__ fw1,
                                                     float* __restrict__ ggt,
                                                     float* __restrict__ fgt) {
  const int c = blockIdx.x, which = blockIdx.y;
  const int t = threadIdx.x;
  const float* W = which ? fw1 : ggw1;
  float* o = which ? fgt : ggt;
  __shared__ float g[D_DIM];
  g[t] = gt[c * D_DIM + t];
  __syncthreads();
  float acc = 0.f;
#pragma unroll 8
  for (int k = 0; k < D_DIM; k++) acc += g[k] * W[(size_t)(256 + k) * D_DIM + t];
  o[c * D_DIM + t] = acc;
}

extern "C" void kernel_launch(void* const* d_in, const int* in_sizes, int n_in,
                              void* d_out, int out_size, void* d_ws, size_t ws_size,
                              hipStream_t stream) {
  const float* feats = (const float*)d_in[0];
  const float* coord = (const float*)d_in[1];
  const float* pe_w1 = (const float*)d_in[3];
  const float* pe_b1 = (const float*)d_in[4];
  const float* pe_w2 = (const float*)d_in[5];
  const float* pe_b2 = (const float*)d_in[6];
  const float* pre_g = (const float*)d_in[7];
  const float* pre_b = (const float*)d_in[8];
  const float* n1_g = (const float*)d_in[9];
  const float* n1_b = (const float*)d_in[10];
  const float* wqkv = (const float*)d_in[11];
  const float* bqkv = (const float*)d_in[12];
  const float* wo = (const float*)d_in[13];
  const float* bo = (const float*)d_in[14];
  const float* n2_g = (const float*)d_in[15];
  const float* n2_b = (const float*)d_in[16];
  const float* m_w1 = (const float*)d_in[17];
  const float* m_b1 = (const float*)d_in[18];
  const float* m_w2 = (const float*)d_in[19];
  const float* m_b2 = (const float*)d_in[20];
  const float* gg_w1 = (const float*)d_in[21];
  const float* gg_b1 = (const float*)d_in[22];
  const float* gg_w2 = (const float*)d_in[23];
  const float* gg_b2 = (const float*)d_in[24];
  const float* f_w1 = (const float*)d_in[25];
  const float* f_b1 = (const float*)d_in[26];
  const float* f_w2 = (const float*)d_in[27];
  const float* f_b2 = (const float*)d_in[28];
  float* out = (float*)d_out;

  // ---------------- workspace layout (~308 MiB) ----------------
  char* ws = (char*)d_ws;
  float* xs = (float*)(ws);                         // [0,128MiB) fp32 residual stream
  u16* hbuf = (u16*)(ws + 134217728);               // [128,192MiB) bf16 (pe / ln1 / LN2)
  u16* qkvchunk = (u16*)(ws + 201326592);           // [192..240MiB) chunk qkv (48 MiB)
  u16* aochunk = (u16*)(ws + 251658240);            // [240..256MiB) chunk attn out (16 MiB)
  u16* tbuf = (u16*)(ws + 268435456);               // [256..288MiB) chunk MLP mid (32 MiB)
  u16* Hbuf = (u16*)(ws + 268435456);               // [N][64] bf16 (16 MiB, pre-attn only)
  u16* xobf = (u16*)(ws + 201326592);               // post-attn: bf16 xo (64 MiB, reuses qkv region)
  size_t off = 301989888;
  u64* keybuf = (u64*)(ws + off); off += (size_t)NTOT * 8;
  int* orderbuf = (int*)(ws + off); off += (size_t)NTOT * 4;
  int* rankbuf = (int*)(ws + off); off += (size_t)NTOT * 4;
  float* statsbuf = (float*)(ws + off); off += 4096;
  float* gtpart = (float*)(ws + off); off += (size_t)NCLOUD * 128 * D_DIM * 4;
  float* gtbuf = (float*)(ws + off); off += 4096;
  float* ggtbuf = (float*)(ws + off); off += 4096;
  float* fgtbuf = (float*)(ws + off); off += 4096;
  u16* wqkvT = (u16*)(ws + off); off += 768 * 256 * 2;
  u16* woT = (u16*)(ws + off); off += 256 * 256 * 2;
  u16* mw1T = (u16*)(ws + off); off += 512 * 256 * 2;
  u16* mw2T = (u16*)(ws + off); off += 256 * 512 * 2;
  u16* ggw1T = (u16*)(ws + off); off += 256 * 256 * 2;
  u16* ggw2T = (u16*)(ws + off); off += 256 * 256 * 2;
  u16* fw1T = (u16*)(ws + off); off += 256 * 256 * 2;
  u16* fw2T = (u16*)(ws + off); off += 256 * 256 * 2;
  u16* pw2T = (u16*)(ws + off); off += 64 * 256 * 2;

  // 1. stats + keys + sort + order/rank
  stats_kernel<<<NCLOUD, 256, 0, stream>>>(coord, statsbuf);
  key_kernel<<<NTOT / 256, 256, 0, stream>>>(coord, statsbuf, keybuf);
  sort_local_kernel<<<NTOT / 4096, 1024, 0, stream>>>(keybuf);
  for (int k = 8192; k <= 32768; k <<= 1) {
    for (int j = k >> 1; j >= 4096; j >>= 1)
      sort_global_kernel<<<NTOT / 512, 256, 0, stream>>>(keybuf, k, j);
    sort_finish_kernel<<<NTOT / 4096, 1024, 0, stream>>>(keybuf, k);
  }
  rank_kernel<<<NTOT / 256, 256, 0, stream>>>(keybuf, orderbuf, rankbuf);
  // 2. weight convert+transpose (bf16)
  wtrans_kernel<<<dim3(24, 8), 256, 0, stream>>>(wqkv, wqkvT, 256, 768);
  wtrans_kernel<<<dim3(8, 8), 256, 0, stream>>>(wo, woT, 256, 256);
  wtrans_kernel<<<dim3(16, 8), 256, 0, stream>>>(m_w1, mw1T, 256, 512);
  wtrans_kernel<<<dim3(8, 16), 256, 0, stream>>>(m_w2, mw2T, 512, 256);
  wtrans_kernel<<<dim3(8, 8), 256, 0, stream>>>(gg_w1, ggw1T, 256, 256);  // top half
  wtrans_kernel<<<dim3(8, 8), 256, 0, stream>>>(gg_w2, ggw2T, 256, 256);
  wtrans_kernel<<<dim3(8, 8), 256, 0, stream>>>(f_w1, fw1T, 256, 256);    // top half
  wtrans_kernel<<<dim3(8, 8), 256, 0, stream>>>(f_w2, fw2T, 256, 256);
  wtrans_kernel<<<dim3(8, 2), 256, 0, stream>>>(pe_w2, pw2T, 64, 256);
  // 3. PE: H = relu(scs@pw1+b1); pe = H @ pw2 + b2 (MFMA, K=64) -> hbuf bf16
  h_kernel<<<NTOT * 64 / 256, 256, 0, stream>>>(coord, statsbuf, pe_w1, pe_b1, Hbuf);
  mfma_gemm<64, 0, 2, false><<<dim3(2, NTOT / 128), 256, 0, stream>>>(
      Hbuf, pw2T, pe_b2, nullptr, hbuf, 256);
  // 4. xs[rank] = LN_pre(feats+pe); then ln1 = LN1(xs) -> hbuf
  add_ln_kernel<<<NTOT / 4, 256, 0, stream>>>(feats, hbuf, rankbuf, pre_g, pre_b, xs);
  ln_bf16_kernel<<<NTOT / 4, 256, 0, stream>>>(xs, n1_g, n1_b, hbuf);
  // 5. attention block (chunked): xs += attn(ln1) @ wo + bo; proj also emits LN2 -> hbuf
  for (int ch = 0; ch < NCHUNK; ch++) {
    const size_t ro = (size_t)ch * CROWS;
    mfma_gemm<256, 0, 2, false><<<dim3(6, CROWS / 128), 256, 0, stream>>>(
        hbuf + ro * 256, wqkvT, bqkv, nullptr, qkvchunk, 768);
    attn_mfma_kernel<<<dim3(CROWS / PATCH, NHEAD), 256, 0, stream>>>(qkvchunk, aochunk);
    mfma_row_gemm<256, 1><<<CROWS / 64, 256, 0, stream>>>(
        aochunk, woT, bo, xs + ro * 256, hbuf + ro * 256, nullptr, n2_g, n2_b);
  }
  // 6. MLP block (chunked): xs += gelu(LN2@m_w1+b)@m_w2+b; MLP2 also scatters -> xobf
  for (int ch = 0; ch < NCHUNK; ch++) {
    const size_t ro = (size_t)ch * CROWS;
    mfma_gemm<256, 2, 2, false><<<dim3(MLPD / 128, CROWS / 128), 256, 0, stream>>>(
        hbuf + ro * 256, mw1T, m_b1, nullptr, tbuf, 512);
    mfma_row_gemm<512, 2><<<CROWS / 64, 256, 0, stream>>>(
        tbuf, mw2T, m_b2, xs + ro * 256, xobf, orderbuf + ro, nullptr, nullptr);
  }
  // 7. global token from xs (mean is permutation-invariant)
  gt_partial_kernel<<<dim3(128, NCLOUD), 256, 0, stream>>>(xs, gtpart);
  gt_reduce_kernel<<<NCLOUD, 256, 0, stream>>>(gtpart, gtbuf);
  pervec_kernel<<<dim3(NCLOUD, 2), 256, 0, stream>>>(gtbuf, gg_w1, f_w1, ggtbuf, fgtbuf);
  // 8. fully-fused tail: out = feats + sigmoid(relu(bf16(feats)@ggw1+ggt+b)@ggw2+b)
  //                              * (relu(xobf@fw1+fgt+b)@fw2+b)
  tail_kernel<<<NTOT / 32, 256, 0, stream>>>(feats, xobf, ggw1T, fw1T, ggw2T, fw2T,
                                             ggtbuf, fgtbuf, gg_b1, f_b1, gg_b2, f_b2, out);
  (void)in_sizes; (void)n_in; (void)out_size; (void)ws_size;
}